// Round 5
// baseline (1452.471 us; speedup 1.0000x reference)
//
#include <hip/hip_runtime.h>
#include <hip/hip_bf16.h>
#include <math.h>

// ---------------- types ----------------
typedef __bf16 bf16x8 __attribute__((ext_vector_type(8)));
typedef float f32x4 __attribute__((ext_vector_type(4)));

// ---------------- conversion kernels ----------------
__global__ void cvt_f32_bf16(const float* __restrict__ in, __bf16* __restrict__ out, long n) {
    long i = ((long)blockIdx.x * 256 + threadIdx.x) * 4;
    long stride = (long)gridDim.x * 1024;
    for (; i < n; i += stride) {
        float4 v = *(const float4*)(in + i);
        out[i + 0] = (__bf16)v.x;
        out[i + 1] = (__bf16)v.y;
        out[i + 2] = (__bf16)v.z;
        out[i + 3] = (__bf16)v.w;
    }
}

// transpose + convert: in f32 [M][N] (ldin) -> out bf16 [N][M] (ldout), batched over z
__global__ void transpose_cvt(const float* __restrict__ in, __bf16* __restrict__ out,
                              int ldin, int ldout, long inBS, long outBS) {
    __shared__ __bf16 tile[32][33];
    in  += (long)blockIdx.z * inBS;
    out += (long)blockIdx.z * outBS;
    int n0 = blockIdx.x * 32, m0 = blockIdx.y * 32;
    for (int i = threadIdx.y; i < 32; i += 8)
        tile[i][threadIdx.x] = (__bf16)in[(long)(m0 + i) * ldin + n0 + threadIdx.x];
    __syncthreads();
    for (int i = threadIdx.y; i < 32; i += 8)
        out[(long)(n0 + i) * ldout + m0 + threadIdx.x] = tile[threadIdx.x][i];
}

// bf16 transpose: in [rows][cols] -> out [cols][rows], batched over z
__global__ void transpose_bf16(const __bf16* __restrict__ in, __bf16* __restrict__ out,
                               int rows, int cols) {
    __shared__ __bf16 tile[32][33];
    in  += (long)blockIdx.z * rows * cols;
    out += (long)blockIdx.z * rows * cols;
    int c0 = blockIdx.x * 32, r0 = blockIdx.y * 32;
    for (int i = threadIdx.y; i < 32; i += 8)
        tile[i][threadIdx.x] = in[(long)(r0 + i) * cols + c0 + threadIdx.x];
    __syncthreads();
    for (int i = threadIdx.y; i < 32; i += 8)
        out[(long)(c0 + i) * rows + r0 + threadIdx.x] = tile[threadIdx.x][i];
}

// ---- frag_cvt: W f32 [K][N] -> bf16 MFMA-fragment chunks -------------------
// chunk c = nblk*(K/32) + kblk (nblk = n/16, kblk = k/32); within chunk:
// elem lane*8+e = W[kblk*32 + (lane>>4)*8 + e][nblk*16 + (lane&15)]
__global__ void frag_cvt(const float* __restrict__ in, __bf16* __restrict__ out,
                         int K, int N, long inBS, long outBS) {
    __shared__ float tile[32][65];
    in  += (long)blockIdx.z * inBS;
    out += (long)blockIdx.z * outBS;
    const int n0 = blockIdx.x * 64, k0 = blockIdx.y * 32;
    for (int r = threadIdx.x >> 6; r < 32; r += 4)
        tile[r][threadIdx.x & 63] = in[(long)(k0 + r) * N + n0 + (threadIdx.x & 63)];
    __syncthreads();
    const int cl = threadIdx.x >> 6, lane = threadIdx.x & 63;
    const int nl = cl * 16 + (lane & 15);
    const int kl = (lane >> 4) * 8;
    const long chunk = (long)((n0 >> 4) + cl) * (K >> 5) + (k0 >> 5);
    bf16x8 v;
#pragma unroll
    for (int e = 0; e < 8; e++) v[e] = (__bf16)tile[kl + e][nl];
    *(bf16x8*)(out + chunk * 512 + lane * 8) = v;
}

// ======= gemm_bdir: 256x128 tile, BK=32, A in LDS ring-3 (48KB), B direct =======
// C[M,N] = A[M,K] @ B^T, B in fragment layout. 512 thr, 8 waves (2M x 4N),
// per-wave C = 128x32. Counted vmcnt(4) per tile (never 0 mid-loop), one barrier
// per tile, 2 blocks/CU. OUT: 0 = f32, 1 = bf16
template<bool ROWB, bool COLB, bool GELUF, bool RES, int OUT>
__global__ __launch_bounds__(512, 4) void gemm_bdir(
    const __bf16* __restrict__ A, int lda,
    const __bf16* __restrict__ Bf,
    void* __restrict__ outp, int ldc,
    const float* __restrict__ rowBias,
    const float* __restrict__ colBias,
    const float* __restrict__ res, int ldres,
    int K)
{
    __shared__ __bf16 Asm[3 * 8192];      // 3 x 16KB ring of 256x32 A tiles

    const int tid = threadIdx.x, lane = tid & 63, wave = tid >> 6;
    const int l15 = lane & 15, l4 = lane >> 4;
    const int wm = wave >> 2, wn = wave & 3;

    // XCD swizzle: XCD owns contiguous N-panels x all M (B panels L2-resident)
    int bx, by;
    {
        int id = blockIdx.y * gridDim.x + blockIdx.x;
        int xcd = id & 7, local = id >> 3;
        int nx = gridDim.y >> 3;
        by = xcd * nx + local / gridDim.x;
        bx = local % gridDim.x;
    }
    const long m0 = (long)bx * 256, n0 = (long)by * 128;

    // A staging: per wave 2 loads x 16 rows (rows wave*32..+32); source pre-swizzled
    // so LDS[r][u16] = G[r][u ^ (r&3)] (4 x 16B units per 64B row) -> conflict-free reads.
    const __bf16* Abp = A + (m0 + wave * 32 + (lane >> 2)) * (long)lda
                          + (((lane & 3) ^ ((lane >> 2) & 3)) << 3);
    const int sdst = wave * 1024;         // elems: wave's 32 rows x 32 cols

    const int kb5 = K >> 5;               // chunks along K (BK=32 granularity)
    const int nblk0 = (int)(n0 >> 4) + wn * 2;
    const int aoff = (wm * 128 + l15) * 32 + ((l4 ^ (l15 & 3)) << 3);

    __bf16* pc = Asm;                     // current tile
    __bf16* pn = Asm + 8192;              // next tile
    __bf16* ps = Asm + 16384;             // stage target (t+2)

    f32x4 acc[8][2];
#pragma unroll
    for (int mi = 0; mi < 8; mi++) {
        acc[mi][0] = (f32x4){0.f, 0.f, 0.f, 0.f};
        acc[mi][1] = (f32x4){0.f, 0.f, 0.f, 0.f};
    }

    auto stage_to = [&](__bf16* dst, int t) {
        const __bf16* src = Abp + (long)t * 32;
#pragma unroll
        for (int j = 0; j < 2; j++)
            __builtin_amdgcn_global_load_lds(
                (const __attribute__((address_space(1))) unsigned int*)(src + (long)j * 16 * lda),
                (__attribute__((address_space(3))) unsigned int*)(dst + sdst + j * 512), 16, 0, 0);
    };
    auto bload = [&](int t, bf16x8 (&B)[2]) {
#pragma unroll
        for (int ni = 0; ni < 2; ni++)
            B[ni] = *(const bf16x8*)(Bf + ((long)(nblk0 + ni) * kb5 + t) * 512 + lane * 8);
    };
    auto iter = [&](int t, bf16x8 (&Bc)[2], bf16x8 (&Bn)[2],
                    bool do_stage, bool do_bload, bool w4) {
        if (w4) { asm volatile("s_waitcnt vmcnt(4)" ::: "memory"); }
        else    { asm volatile("s_waitcnt vmcnt(2)" ::: "memory"); }
        __builtin_amdgcn_s_barrier();
        __builtin_amdgcn_sched_barrier(0);
        if (do_stage) stage_to(ps, t + 2);
        if (do_bload) bload(t + 1, Bn);
        bf16x8 af[8];
#pragma unroll
        for (int mi = 0; mi < 8; mi++)
            af[mi] = *(const bf16x8*)(pc + aoff + mi * 512);
        __builtin_amdgcn_s_setprio(1);
#pragma unroll
        for (int mi = 0; mi < 8; mi++) {
            acc[mi][0] = __builtin_amdgcn_mfma_f32_16x16x32_bf16(af[mi], Bc[0], acc[mi][0], 0, 0, 0);
            acc[mi][1] = __builtin_amdgcn_mfma_f32_16x16x32_bf16(af[mi], Bc[1], acc[mi][1], 0, 0, 0);
        }
        __builtin_amdgcn_s_setprio(0);
        __bf16* tmp = pc; pc = pn; pn = ps; ps = tmp;
    };

    const int NT = K >> 5;                // >= 4, even
    bf16x8 Ba[2], Bb[2];
    stage_to(pc, 0);
    stage_to(pn, 1);
    bload(0, Ba);

    int t = 0;
    for (; t + 2 < NT; t += 2) {
        iter(t,     Ba, Bb, true, true, true);
        iter(t + 1, Bb, Ba, true, true, true);
    }
    iter(NT - 2, Ba, Bb, false, true,  true);
    iter(NT - 1, Bb, Ba, false, false, false);

    float* outf = (float*)outp;
    __bf16* outb = (__bf16*)outp;
#pragma unroll
    for (int mi = 0; mi < 8; mi++)
#pragma unroll
        for (int ni = 0; ni < 2; ni++) {
            long gmb = m0 + wm * 128 + mi * 16 + l4 * 4;
            long gc  = n0 + wn * 32 + ni * 16 + l15;
#pragma unroll
            for (int i = 0; i < 4; i++) {
                long gm = gmb + i;
                float v = acc[mi][ni][i];
                if (ROWB)  v += rowBias[gm];
                if (COLB)  v += colBias[gc];
                if (GELUF) v = 0.5f * v * (1.f + erff(v * 0.70710678118f));
                if (RES)   v += res[gm * (long)ldres + gc];
                if (OUT == 0) outf[gm * (long)ldc + gc] = v;
                else          outb[gm * (long)ldc + gc] = (__bf16)v;
            }
        }
}

// ========== gemm128_split: 128x128 tile split-K, writes f32 partials ==========
__global__ __launch_bounds__(256, 2) void gemm128_split(
    const __bf16* __restrict__ A, int lda, long aBS,
    const __bf16* __restrict__ Bt, int ldb, long bBS,
    float* __restrict__ P, long cBS, int ldc,
    int Ksplit, int S)
{
    __shared__ __bf16 Asm[128 * 64];
    __shared__ __bf16 Bsm[128 * 64];
    const int tid = threadIdx.x;
    const int lane = tid & 63, wave = tid >> 6;
    const int wm = wave >> 1, wn = wave & 1;
    const int l15 = lane & 15, l4 = lane >> 4;
    const long m0 = (long)blockIdx.x * 128, n0 = (long)blockIdx.y * 128;
    const long zb = blockIdx.z / S;
    const int  sp = blockIdx.z % S;
    A  += zb * aBS + (long)sp * Ksplit;
    Bt += zb * bBS + (long)sp * Ksplit;

    const int srow8 = lane >> 3;
    const int gunit = ((lane & 7) ^ srow8) << 3;
    const __bf16* Abase = A + (m0 + wave * 8 + srow8) * (long)lda + gunit;
    const __bf16* Bbase = Bt + (n0 + wave * 8 + srow8) * (long)ldb + gunit;
    __bf16* AsmW = Asm + wave * 8 * 64;
    __bf16* BsmW = Bsm + wave * 8 * 64;
    const int swz_r = l15 & 7;

    f32x4 acc[4][4];
#pragma unroll
    for (int mi = 0; mi < 4; mi++)
#pragma unroll
        for (int ni = 0; ni < 4; ni++) acc[mi][ni] = (f32x4){0.f, 0.f, 0.f, 0.f};

    for (int k0 = 0; k0 < Ksplit; k0 += 64) {
        __syncthreads();
#pragma unroll
        for (int p = 0; p < 4; p++) {
            __builtin_amdgcn_global_load_lds(
                (const __attribute__((address_space(1))) unsigned int*)(Abase + (long)p * 32 * lda + k0),
                (__attribute__((address_space(3))) unsigned int*)(AsmW + p * 32 * 64), 16, 0, 0);
            __builtin_amdgcn_global_load_lds(
                (const __attribute__((address_space(1))) unsigned int*)(Bbase + (long)p * 32 * ldb + k0),
                (__attribute__((address_space(3))) unsigned int*)(BsmW + p * 32 * 64), 16, 0, 0);
        }
        asm volatile("s_waitcnt vmcnt(0)" ::: "memory");
        __syncthreads();
#pragma unroll
        for (int ks = 0; ks < 2; ks++) {
            bf16x8 af[4], bfv[4];
#pragma unroll
            for (int mi = 0; mi < 4; mi++)
                af[mi] = *(const bf16x8*)(Asm + (wm * 64 + mi * 16 + l15) * 64 + (((ks * 4 + l4) ^ swz_r) << 3));
#pragma unroll
            for (int ni = 0; ni < 4; ni++)
                bfv[ni] = *(const bf16x8*)(Bsm + (wn * 64 + ni * 16 + l15) * 64 + (((ks * 4 + l4) ^ swz_r) << 3));
#pragma unroll
            for (int mi = 0; mi < 4; mi++)
#pragma unroll
                for (int ni = 0; ni < 4; ni++)
                    acc[mi][ni] = __builtin_amdgcn_mfma_f32_16x16x32_bf16(af[mi], bfv[ni], acc[mi][ni], 0, 0, 0);
        }
    }

    float* out = P + (long)blockIdx.z * cBS;
#pragma unroll
    for (int mi = 0; mi < 4; mi++)
#pragma unroll
        for (int ni = 0; ni < 4; ni++) {
            long gmb = m0 + wm * 64 + mi * 16 + l4 * 4;
            long gc  = n0 + wn * 64 + ni * 16 + l15;
#pragma unroll
            for (int i = 0; i < 4; i++)
                out[(gmb + i) * (long)ldc + gc] = acc[mi][ni][i];
        }
}

// ---------- reduce S f32 partials -> bf16 (+row bias, optional transposed write) ----------
template<bool BIAS, bool TRANS>
__global__ __launch_bounds__(256) void reduce_partials(
    const float* __restrict__ P, __bf16* __restrict__ out,
    const float* __restrict__ bias, int S, int M, int N, long pBS)
{
    int b = blockIdx.z;
    long idx = ((long)blockIdx.x * 256 + threadIdx.x) * 4;
    if (idx >= (long)M * N) return;
    const float* Pb = P + (long)b * S * pBS + idx;
    float4 a = *(const float4*)Pb;
    for (int s = 1; s < S; s++) {
        float4 v = *(const float4*)(Pb + (long)s * pBS);
        a.x += v.x; a.y += v.y; a.z += v.z; a.w += v.w;
    }
    int m = (int)(idx / N), n = (int)(idx % N);
    if (BIAS) { float bv = bias[m]; a.x += bv; a.y += bv; a.z += bv; a.w += bv; }
    float av[4] = {a.x, a.y, a.z, a.w};
    if (!TRANS) {
        __bf16* o = out + (long)b * M * N + idx;
        o[0] = (__bf16)av[0]; o[1] = (__bf16)av[1]; o[2] = (__bf16)av[2]; o[3] = (__bf16)av[3];
    } else {
#pragma unroll
        for (int j = 0; j < 4; j++)
            out[(long)b * M * N + (long)(n + j) * M + m] = (__bf16)av[j];
    }
}

// ---------------- fused Linformer attention ----------------
__global__ __launch_bounds__(256, 2) void attn_fused(
    const __bf16* __restrict__ Q, const __bf16* __restrict__ KP,
    const __bf16* __restrict__ VPt, __bf16* __restrict__ O)
{
    __shared__ __bf16 plds[4][4096];
    const int tid = threadIdx.x, lane = tid & 63, wave = tid >> 6;
    const int l15 = lane & 15, l4 = lane >> 4;
    const int h = blockIdx.y, b = blockIdx.z;
    const long row0 = (long)b * 4096 + (long)blockIdx.x * 64 + wave * 16;

    bf16x8 aq[2];
#pragma unroll
    for (int ks = 0; ks < 2; ks++)
        aq[ks] = *(const bf16x8*)(Q + (row0 + l15) * 1024 + h * 64 + ks * 32 + l4 * 8);

    f32x4 s[16];
#pragma unroll
    for (int f = 0; f < 16; f++) {
        f32x4 a = (f32x4){0.f, 0.f, 0.f, 0.f};
#pragma unroll
        for (int ks = 0; ks < 2; ks++) {
            bf16x8 bk = *(const bf16x8*)(KP + ((long)b * 256 + f * 16 + l15) * 1024 + h * 64 + ks * 32 + l4 * 8);
            a = __builtin_amdgcn_mfma_f32_16x16x32_bf16(aq[ks], bk, a, 0, 0, 0);
        }
        s[f] = a;
    }

    const float scale = 0.125f;
#pragma unroll
    for (int i = 0; i < 4; i++) {
        float m_ = -3.4e38f;
#pragma unroll
        for (int f = 0; f < 16; f++) { float v = s[f][i] * scale; s[f][i] = v; m_ = fmaxf(m_, v); }
#pragma unroll
        for (int msk = 1; msk < 16; msk <<= 1) m_ = fmaxf(m_, __shfl_xor(m_, msk));
        float su = 0.f;
#pragma unroll
        for (int f = 0; f < 16; f++) { float e = expf(s[f][i] - m_); s[f][i] = e; su += e; }
#pragma unroll
        for (int msk = 1; msk < 16; msk <<= 1) su += __shfl_xor(su, msk);
        float inv = 1.f / su;
#pragma unroll
        for (int f = 0; f < 16; f++) s[f][i] *= inv;
    }

    __bf16* pl = plds[wave];
#pragma unroll
    for (int f = 0; f < 16; f++)
#pragma unroll
        for (int i = 0; i < 4; i++) {
            int r = l4 * 4 + i, c = f * 16 + l15;
            int off = r * 256 + ((((c >> 3) ^ (r & 7)) << 3) | (c & 7));
            pl[off] = (__bf16)s[f][i];
        }

    f32x4 o[4];
#pragma unroll
    for (int f2 = 0; f2 < 4; f2++) o[f2] = (f32x4){0.f, 0.f, 0.f, 0.f};
#pragma unroll
    for (int ks = 0; ks < 8; ks++) {
        int kk = ks * 32 + l4 * 8;
        int off = l15 * 256 + (((kk >> 3) ^ (l15 & 7)) << 3);
        bf16x8 ap = *(const bf16x8*)(pl + off);
#pragma unroll
        for (int f2 = 0; f2 < 4; f2++) {
            bf16x8 bv = *(const bf16x8*)(VPt + ((long)b * 1024 + h * 64 + f2 * 16 + l15) * 256 + kk);
            o[f2] = __builtin_amdgcn_mfma_f32_16x16x32_bf16(ap, bv, o[f2], 0, 0, 0);
        }
    }
#pragma unroll
    for (int f2 = 0; f2 < 4; f2++)
#pragma unroll
        for (int i = 0; i < 4; i++)
            O[(row0 + l4 * 4 + i) * 1024 + h * 64 + f2 * 16 + l15] = (__bf16)o[f2][i];
}

// ---------------- LayerNorm (row=1024), writes f32 + bf16 ----------------
__global__ __launch_bounds__(256) void ln_kernel(const float* __restrict__ y,
    const float* __restrict__ g, const float* __restrict__ b,
    float* __restrict__ xout, __bf16* __restrict__ xb)
{
    const int row = blockIdx.x;
    const int t = threadIdx.x;
    const float4 v = ((const float4*)(y + (long)row * 1024))[t];
    float s  = v.x + v.y + v.z + v.w;
    float ss = v.x * v.x + v.y * v.y + v.z * v.z + v.w * v.w;
#pragma unroll
    for (int m = 1; m < 64; m <<= 1) { s += __shfl_xor(s, m); ss += __shfl_xor(ss, m); }
    __shared__ float red[2][4];
    const int wave = t >> 6, lane = t & 63;
    if (lane == 0) { red[0][wave] = s; red[1][wave] = ss; }
    __syncthreads();
    s  = red[0][0] + red[0][1] + red[0][2] + red[0][3];
    ss = red[1][0] + red[1][1] + red[1][2] + red[1][3];
    const float mu = s * (1.f / 1024.f);
    const float var = ss * (1.f / 1024.f) - mu * mu;
    const float rs = rsqrtf(var + 1e-5f);
    const float4 gv = ((const float4*)g)[t];
    const float4 bv = ((const float4*)b)[t];
    float o0 = (v.x - mu) * rs * gv.x + bv.x;
    float o1 = (v.y - mu) * rs * gv.y + bv.y;
    float o2 = (v.z - mu) * rs * gv.z + bv.z;
    float o3 = (v.w - mu) * rs * gv.w + bv.w;
    float4 ov; ov.x = o0; ov.y = o1; ov.z = o2; ov.w = o3;
    ((float4*)(xout + (long)row * 1024))[t] = ov;
    __bf16* xr = xb + (long)row * 1024 + t * 4;
    xr[0] = (__bf16)o0; xr[1] = (__bf16)o1; xr[2] = (__bf16)o2; xr[3] = (__bf16)o3;
}

// ---------------- host launch ----------------
extern "C" void kernel_launch(void* const* d_in, const int* in_sizes, int n_in,
                              void* d_out, int out_size, void* d_ws, size_t ws_size,
                              hipStream_t stream) {
    const float* x   = (const float*)d_in[0];
    const float* Wq  = (const float*)d_in[1];
    const float* Wk  = (const float*)d_in[2];
    const float* Wv  = (const float*)d_in[3];
    const float* Wo  = (const float*)d_in[4];
    const float* bo  = (const float*)d_in[5];
    const float* Ew  = (const float*)d_in[6];
    const float* Eb  = (const float*)d_in[7];
    const float* W1  = (const float*)d_in[8];
    const float* b1  = (const float*)d_in[9];
    const float* W2  = (const float*)d_in[10];
    const float* b2  = (const float*)d_in[11];
    const float* lng = (const float*)d_in[12];
    const float* lnb = (const float*)d_in[13];
    float* xout = (float*)d_out;

    char* base = (char*)d_ws;
    size_t off = 0;
    auto alloc = [&](size_t bytes) { void* p = base + off; off += (bytes + 255) & ~(size_t)255; return p; };
    __bf16* Wkt = (__bf16*)alloc(2ll * 1024 * 1024 * 2);
    __bf16* Wvt = (__bf16*)alloc(2ll * 1024 * 1024 * 2);
    __bf16* Wqf = (__bf16*)alloc(2ll * 1024 * 1024 * 2);   // fragment layouts
    __bf16* Wof = (__bf16*)alloc(2ll * 1024 * 1024 * 2);
    __bf16* W1f = (__bf16*)alloc(2ll * 1024 * 4096 * 2);
    __bf16* W2f = (__bf16*)alloc(2ll * 1024 * 4096 * 2);
    __bf16* Ewb = (__bf16*)alloc(256ll * 4096 * 2);
    __bf16* xb  = (__bf16*)alloc(8192ll * 1024 * 2);
    __bf16* xbT = (__bf16*)alloc(2ll * 1024 * 4096 * 2);
    float*  y   = (float*) alloc(8192ll * 1024 * 4);
    __bf16* xp  = (__bf16*)alloc(2ll * 256 * 1024 * 2);
    __bf16* KPb = (__bf16*)alloc(2ll * 256 * 1024 * 2);
    __bf16* VPt = (__bf16*)alloc(2ll * 1024 * 256 * 2);
    __bf16* big = (__bf16*)alloc(8192ll * 4096 * 2);   // 64 MB scratch region
    float*  xpP = (float*)big;                          // [16][256*1024] f32 = 16MB
    float*  kpP = (float*)((char*)big + (16ll << 20));  // [8][256*1024]  f32 =  8MB
    float*  vpP = (float*)((char*)big + (24ll << 20));  // [8][256*1024]  f32 =  8MB
    __bf16* Qb  = big;                                  // [8192][1024] (over xpP, dead)
    __bf16* Ob  = big + (16ll << 20);                   // [8192][1024] (over kpP/vpP, dead)
    __bf16* hbuf = big;                                 // [8192][4096] (FF stage)

    cvt_f32_bf16<<<2048, 256, 0, stream>>>(x, xb, 8388608);
    cvt_f32_bf16<<<1024, 256, 0, stream>>>(Ew, Ewb, 1048576);
    transpose_cvt<<<dim3(2, 32, 32),  dim3(32, 8), 0, stream>>>(Wk, Wkt, 64, 1024, 65536, 65536);
    transpose_cvt<<<dim3(2, 32, 32),  dim3(32, 8), 0, stream>>>(Wv, Wvt, 64, 1024, 65536, 65536);
    frag_cvt<<<dim3(1, 32, 32),  256, 0, stream>>>(Wq, Wqf, 1024, 64, 65536, 65536);
    frag_cvt<<<dim3(16, 32, 2),  256, 0, stream>>>(Wo, Wof, 1024, 1024, 1048576, 1048576);
    frag_cvt<<<dim3(64, 32, 2),  256, 0, stream>>>(W1, W1f, 1024, 4096, 4194304, 4194304);
    frag_cvt<<<dim3(16, 128, 2), 256, 0, stream>>>(W2, W2f, 4096, 1024, 4194304, 4194304);

    for (int l = 0; l < 2; l++) {
        const __bf16* Wkt_l = Wkt + (long)l * 1048576;
        const __bf16* Wvt_l = Wvt + (long)l * 1048576;
        const __bf16* Wqf_l = Wqf + (long)l * 1048576;
        const __bf16* Wof_l = Wof + (long)l * 1048576;
        const __bf16* W1f_l = W1f + (long)l * 4194304;
        const __bf16* W2f_l = W2f + (long)l * 4194304;
        const float* res = (l == 0) ? x : xout;

        // xbT[b] = xb[b]^T
        transpose_bf16<<<dim3(32, 128, 2), dim3(32, 8), 0, stream>>>(xb, xbT, 4096, 1024);
        // xp = Ew @ x  (split-K 8)
        gemm128_split<<<dim3(2, 8, 16), 256, 0, stream>>>(
            Ewb, 4096, 0, xbT, 4096, 4194304, xpP, 262144, 1024, 512, 8);
        reduce_partials<false, false><<<dim3(256, 1, 2), 256, 0, stream>>>(
            xpP, xp, nullptr, 8, 256, 1024, 262144);
        // KP = xp @ Wk^T + Eb  (split-K 4)
        gemm128_split<<<dim3(2, 8, 8), 256, 0, stream>>>(
            xp, 1024, 262144, Wkt_l, 1024, 0, kpP, 262144, 1024, 256, 4);
        reduce_partials<true, false><<<dim3(256, 1, 2), 256, 0, stream>>>(
            kpP, KPb, Eb, 4, 256, 1024, 262144);
        // VPt = (xp @ Wv^T + Eb)^T
        gemm128_split<<<dim3(2, 8, 8), 256, 0, stream>>>(
            xp, 1024, 262144, Wvt_l, 1024, 0, vpP, 262144, 1024, 256, 4);
        reduce_partials<true, true><<<dim3(256, 1, 2), 256, 0, stream>>>(
            vpP, VPt, Eb, 4, 256, 1024, 262144);
        // Q = xb @ Wq^T
        gemm_bdir<false, false, false, false, 1><<<dim3(32, 8), 512, 0, stream>>>(
            xb, 1024, Wqf_l, (void*)Qb, 1024, nullptr, nullptr, nullptr, 0, 1024);
        // attention
        attn_fused<<<dim3(64, 16, 2), 256, 0, stream>>>(Qb, KPb, VPt, Ob);
        // attn_out = O @ Wo^T + bo + residual
        gemm_bdir<false, true, false, true, 0><<<dim3(32, 8), 512, 0, stream>>>(
            Ob, 1024, Wof_l, (void*)y, 1024, nullptr, bo + l * 1024, res, 1024, 1024);
        ln_kernel<<<8192, 256, 0, stream>>>(y, lng + (2 * l + 0) * 1024, lnb + (2 * l + 0) * 1024, xout, xb);
        // h = gelu(x @ W1 + b1)
        gemm_bdir<false, true, true, false, 1><<<dim3(32, 32), 512, 0, stream>>>(
            xb, 1024, W1f_l, (void*)hbuf, 4096, nullptr, b1 + l * 4096, nullptr, 0, 1024);
        // ff = h @ W2 + b2 + residual
        gemm_bdir<false, true, false, true, 0><<<dim3(32, 8), 512, 0, stream>>>(
            hbuf, 4096, W2f_l, (void*)y, 1024, nullptr, b2 + l * 1024, xout, 1024, 4096);
        ln_kernel<<<8192, 256, 0, stream>>>(y, lng + (2 * l + 1) * 1024, lnb + (2 * l + 1) * 1024, xout, xb);
    }
}

// Round 6
// 907.412 us; speedup vs baseline: 1.6007x; 1.6007x over previous
//
#include <hip/hip_runtime.h>
#include <hip/hip_bf16.h>
#include <math.h>

// ---------------- types ----------------
typedef __bf16 bf16x8 __attribute__((ext_vector_type(8)));
typedef float f32x4 __attribute__((ext_vector_type(4)));

// ---------------- conversion kernels ----------------
__global__ void cvt_f32_bf16(const float* __restrict__ in, __bf16* __restrict__ out, long n) {
    long i = ((long)blockIdx.x * 256 + threadIdx.x) * 4;
    long stride = (long)gridDim.x * 1024;
    for (; i < n; i += stride) {
        float4 v = *(const float4*)(in + i);
        out[i + 0] = (__bf16)v.x;
        out[i + 1] = (__bf16)v.y;
        out[i + 2] = (__bf16)v.z;
        out[i + 3] = (__bf16)v.w;
    }
}

// transpose + convert: in f32 [M][N] (ldin) -> out bf16 [N][M] (ldout), batched over z
__global__ void transpose_cvt(const float* __restrict__ in, __bf16* __restrict__ out,
                              int ldin, int ldout, long inBS, long outBS) {
    __shared__ __bf16 tile[32][33];
    in  += (long)blockIdx.z * inBS;
    out += (long)blockIdx.z * outBS;
    int n0 = blockIdx.x * 32, m0 = blockIdx.y * 32;
    for (int i = threadIdx.y; i < 32; i += 8)
        tile[i][threadIdx.x] = (__bf16)in[(long)(m0 + i) * ldin + n0 + threadIdx.x];
    __syncthreads();
    for (int i = threadIdx.y; i < 32; i += 8)
        out[(long)(n0 + i) * ldout + m0 + threadIdx.x] = tile[threadIdx.x][i];
}

// bf16 transpose: in [rows][cols] -> out [cols][rows], batched over z
__global__ void transpose_bf16(const __bf16* __restrict__ in, __bf16* __restrict__ out,
                               int rows, int cols) {
    __shared__ __bf16 tile[32][33];
    in  += (long)blockIdx.z * rows * cols;
    out += (long)blockIdx.z * rows * cols;
    int c0 = blockIdx.x * 32, r0 = blockIdx.y * 32;
    for (int i = threadIdx.y; i < 32; i += 8)
        tile[i][threadIdx.x] = in[(long)(r0 + i) * cols + c0 + threadIdx.x];
    __syncthreads();
    for (int i = threadIdx.y; i < 32; i += 8)
        out[(long)(c0 + i) * rows + r0 + threadIdx.x] = tile[threadIdx.x][i];
}

// ============== gemm8p: 256x256 tile, BK=64, 8-phase counted-vmcnt schedule ==============
// C[M,N] = A[M,K] @ Bt[N,K]^T (+epilogue). 512 thr, 8 waves (2M x 4N), per-wave C 128x64.
// LDS 128KB (A,B double-buffered K-tiles). One stage (half-tile) per phase; vmcnt(4)
// only at end of phases 3 and 7 (never drains to 0 mid-loop). K % 128 == 0.
// OUT: 0 = f32, 1 = bf16
template<bool COLB, bool GELUF, bool RES, int OUT>
__global__ __launch_bounds__(512, 2) void gemm8p(
    const __bf16* __restrict__ A, int lda,
    const __bf16* __restrict__ Bt, int ldb,
    void* __restrict__ outp, int ldc,
    const float* __restrict__ colBias,
    const float* __restrict__ res, int ldres,
    int K)
{
    __shared__ __bf16 Asm[2][16384];   // [buf][256 rows x 64 cols]
    __shared__ __bf16 Bsm[2][16384];

    const int tid = threadIdx.x, lane = tid & 63, wave = tid >> 6;
    const int l15 = lane & 15, l4 = lane >> 4;
    const int wm = wave >> 2, wn = wave & 3;

    // 2D XCD swizzle: XCD -> (4 M-groups x 2 N-groups); inside: 8 bx x (gy/2) by
    int bx, by;
    {
        int id = blockIdx.y * gridDim.x + blockIdx.x;
        int xcd = id & 7, j = id >> 3;
        bx = (xcd & 3) * 8 + (j & 7);
        by = (xcd >> 2) * (gridDim.y >> 1) + (j >> 3);
    }
    const long m0 = (long)bx * 256, n0 = (long)by * 256;

    // staging geometry: wave stages 16 rows/half (2 gloads x 8 rows); source pre-swizzled
    // so LDS[r][u16] = G[r][u ^ (r&7)] -> proven conflict-free ds_read_b128 (round 2).
    const int srow = wave * 16 + (lane >> 3);           // row within 128-row half
    const int scol = ((lane & 7) ^ (lane >> 3)) << 3;   // swizzled elem col
    const __bf16* Abp = A + (m0 + srow) * (long)lda + scol;
    const __bf16* Bbp = Bt + (n0 + srow) * (long)ldb + scol;

    const int NT = K >> 6;

    auto stageA = [&](int half, int tau) {
        const __bf16* s = Abp + (long)half * 128 * lda + (long)tau * 64;
        __bf16* d = &Asm[tau & 1][(half * 128 + wave * 16) * 64];
#pragma unroll
        for (int j = 0; j < 2; j++)
            __builtin_amdgcn_global_load_lds(
                (const __attribute__((address_space(1))) unsigned int*)(s + (long)j * 8 * lda),
                (__attribute__((address_space(3))) unsigned int*)(d + j * 512), 16, 0, 0);
    };
    auto stageB = [&](int half, int tau) {
        const __bf16* s = Bbp + (long)half * 128 * ldb + (long)tau * 64;
        __bf16* d = &Bsm[tau & 1][(half * 128 + wave * 16) * 64];
#pragma unroll
        for (int j = 0; j < 2; j++)
            __builtin_amdgcn_global_load_lds(
                (const __attribute__((address_space(1))) unsigned int*)(s + (long)j * 8 * ldb),
                (__attribute__((address_space(3))) unsigned int*)(d + j * 512), 16, 0, 0);
    };
    auto ldA = [&](int buf, int mi, int kk) -> bf16x8 {
        return *(const bf16x8*)&Asm[buf][(wm * 128 + mi * 16 + l15) * 64 + (((kk * 4 + l4) ^ (l15 & 7)) << 3)];
    };
    auto ldB = [&](int buf, int ni, int kk) -> bf16x8 {
        return *(const bf16x8*)&Bsm[buf][(wn * 64 + ni * 16 + l15) * 64 + (((kk * 4 + l4) ^ (l15 & 7)) << 3)];
    };

    f32x4 acc[8][4];
#pragma unroll
    for (int mi = 0; mi < 8; mi++)
#pragma unroll
        for (int ni = 0; ni < 4; ni++) acc[mi][ni] = (f32x4){0.f, 0.f, 0.f, 0.f};

    // prologue: tile0 (A+B) + B(1); retire tile0, keep B(1) in flight (4 loads)
    stageB(0, 0); stageB(1, 0); stageA(0, 0); stageA(1, 0);
    if (NT > 1) { stageB(0, 1); stageB(1, 1); }
    __builtin_amdgcn_sched_barrier(0);
    asm volatile("s_waitcnt vmcnt(4)" ::: "memory");
    __builtin_amdgcn_sched_barrier(0);
    __builtin_amdgcn_s_barrier();

    bf16x8 Breg[2][4];
    const int NI = K >> 7;
    for (int it = 0; it < NI; ++it) {
        const int T = it << 1;
        const bool last = (it == NI - 1);
#pragma unroll
        for (int p = 0; p < 8; ++p) {
            const int cb = p >> 2;      // compute buffer / K-tile parity (T even)
            const int q = p & 3;        // mi-pair quadrant
            if (q == 0) {
#pragma unroll
                for (int kk = 0; kk < 2; kk++)
#pragma unroll
                    for (int ni = 0; ni < 4; ni++)
                        Breg[kk][ni] = ldB(cb, ni, kk);
            }
            bf16x8 a00 = ldA(cb, 2 * q, 0),     a01 = ldA(cb, 2 * q, 1);
            bf16x8 a10 = ldA(cb, 2 * q + 1, 0), a11 = ldA(cb, 2 * q + 1, 1);
            // one half-tile stage per phase (region free per the phase schedule)
            if      (p == 0) { stageA(0, T + 1); }
            else if (p == 1) { stageA(1, T + 1); }
            else if (p == 2) { if (T + 2 < NT) stageB(0, T + 2); }
            else if (p == 3) { if (T + 2 < NT) stageB(1, T + 2); }
            else if (p == 4) { if (T + 2 < NT) stageA(0, T + 2); }
            else if (p == 5) { if (T + 2 < NT) stageA(1, T + 2); }
            else if (p == 6) { if (T + 3 < NT) stageB(0, T + 3); }
            else             { if (T + 3 < NT) stageB(1, T + 3); }
            __builtin_amdgcn_sched_barrier(0);
            __builtin_amdgcn_s_barrier();
            __builtin_amdgcn_s_setprio(1);
#pragma unroll
            for (int ni = 0; ni < 4; ni++) {
                acc[2 * q][ni]     = __builtin_amdgcn_mfma_f32_16x16x32_bf16(a00, Breg[0][ni], acc[2 * q][ni], 0, 0, 0);
                acc[2 * q + 1][ni] = __builtin_amdgcn_mfma_f32_16x16x32_bf16(a10, Breg[0][ni], acc[2 * q + 1][ni], 0, 0, 0);
            }
#pragma unroll
            for (int ni = 0; ni < 4; ni++) {
                acc[2 * q][ni]     = __builtin_amdgcn_mfma_f32_16x16x32_bf16(a01, Breg[1][ni], acc[2 * q][ni], 0, 0, 0);
                acc[2 * q + 1][ni] = __builtin_amdgcn_mfma_f32_16x16x32_bf16(a11, Breg[1][ni], acc[2 * q + 1][ni], 0, 0, 0);
            }
            __builtin_amdgcn_s_setprio(0);
            if (p == 3) {
                if (last) { asm volatile("s_waitcnt vmcnt(0)" ::: "memory"); }
                else      { asm volatile("s_waitcnt vmcnt(4)" ::: "memory"); }
            } else if (p == 7 && !last) {
                asm volatile("s_waitcnt vmcnt(4)" ::: "memory");
            }
            __builtin_amdgcn_sched_barrier(0);
            __builtin_amdgcn_s_barrier();
        }
    }

    float* outf = (float*)outp;
    __bf16* outb = (__bf16*)outp;
#pragma unroll
    for (int mi = 0; mi < 8; mi++)
#pragma unroll
        for (int ni = 0; ni < 4; ni++) {
            long gmb = m0 + wm * 128 + mi * 16 + l4 * 4;
            long gc  = n0 + wn * 64 + ni * 16 + l15;
#pragma unroll
            for (int i = 0; i < 4; i++) {
                long gm = gmb + i;
                float v = acc[mi][ni][i];
                if (COLB)  v += colBias[gc];
                if (GELUF) v = 0.5f * v * (1.f + erff(v * 0.70710678118f));
                if (RES)   v += res[gm * (long)ldres + gc];
                if (OUT == 0) outf[gm * (long)ldc + gc] = v;
                else          outb[gm * (long)ldc + gc] = (__bf16)v;
            }
        }
}

// ---------------- GEMM (round-2 proven): C = A @ Bt^T, 128^2 tile ----------------
// OUT: 0 = f32 normal, 1 = bf16 normal, 2 = bf16 transposed
template<bool ROWB, bool COLB, bool GELUF, bool RES, int OUT>
__global__ __launch_bounds__(256, 2) void gemm_bf16(
    const __bf16* __restrict__ A, int lda, long aBS,
    const __bf16* __restrict__ Bt, int ldb, long bBS,
    void* __restrict__ outp, int ldc, long cBS,
    const float* __restrict__ rowBias,
    const float* __restrict__ colBias,
    const float* __restrict__ res, int ldres,
    int K)
{
    __shared__ __bf16 Asm[128 * 64];
    __shared__ __bf16 Bsm[128 * 64];
    const int tid = threadIdx.x;
    const int lane = tid & 63, wave = tid >> 6;
    const int wm = wave >> 1, wn = wave & 1;
    const int l15 = lane & 15, l4 = lane >> 4;

    int bx = blockIdx.x, by = blockIdx.y;
    {
        int nwg = gridDim.x * gridDim.y;
        if ((nwg & 7) == 0) {
            int id = by * gridDim.x + bx;
            int cpx = nwg >> 3;
            int swz = (id & 7) * cpx + (id >> 3);
            bx = swz % gridDim.x;
            by = swz / gridDim.x;
        }
    }
    const long m0 = (long)bx * 128, n0 = (long)by * 128;
    A  += (long)blockIdx.z * aBS;
    Bt += (long)blockIdx.z * bBS;

    const int srow8 = lane >> 3;
    const int gunit = ((lane & 7) ^ srow8) << 3;
    const __bf16* Abase = A  + (m0 + wave * 8 + srow8) * (long)lda + gunit;
    const __bf16* Bbase = Bt + (n0 + wave * 8 + srow8) * (long)ldb + gunit;
    __bf16* AsmW = Asm + wave * 8 * 64;
    __bf16* BsmW = Bsm + wave * 8 * 64;
    const int swz_r = l15 & 7;

    f32x4 acc[4][4];
#pragma unroll
    for (int mi = 0; mi < 4; mi++)
#pragma unroll
        for (int ni = 0; ni < 4; ni++) acc[mi][ni] = (f32x4){0.f, 0.f, 0.f, 0.f};

    for (int k0 = 0; k0 < K; k0 += 64) {
        __syncthreads();
#pragma unroll
        for (int p = 0; p < 4; p++) {
            __builtin_amdgcn_global_load_lds(
                (const __attribute__((address_space(1))) unsigned int*)(Abase + (long)p * 32 * lda + k0),
                (__attribute__((address_space(3))) unsigned int*)(AsmW + p * 32 * 64), 16, 0, 0);
            __builtin_amdgcn_global_load_lds(
                (const __attribute__((address_space(1))) unsigned int*)(Bbase + (long)p * 32 * ldb + k0),
                (__attribute__((address_space(3))) unsigned int*)(BsmW + p * 32 * 64), 16, 0, 0);
        }
        asm volatile("s_waitcnt vmcnt(0)" ::: "memory");
        __syncthreads();
#pragma unroll
        for (int ks = 0; ks < 2; ks++) {
            bf16x8 af[4], bfv[4];
#pragma unroll
            for (int mi = 0; mi < 4; mi++)
                af[mi] = *(const bf16x8*)(Asm + (wm * 64 + mi * 16 + l15) * 64 + (((ks * 4 + l4) ^ swz_r) << 3));
#pragma unroll
            for (int ni = 0; ni < 4; ni++)
                bfv[ni] = *(const bf16x8*)(Bsm + (wn * 64 + ni * 16 + l15) * 64 + (((ks * 4 + l4) ^ swz_r) << 3));
#pragma unroll
            for (int mi = 0; mi < 4; mi++)
#pragma unroll
                for (int ni = 0; ni < 4; ni++)
                    acc[mi][ni] = __builtin_amdgcn_mfma_f32_16x16x32_bf16(af[mi], bfv[ni], acc[mi][ni], 0, 0, 0);
        }
    }

    float* outf = (float*)outp;
    __bf16* outb = (__bf16*)outp;
    const long cOff = (long)blockIdx.z * cBS;
#pragma unroll
    for (int mi = 0; mi < 4; mi++)
#pragma unroll
        for (int ni = 0; ni < 4; ni++) {
            long gmb = m0 + wm * 64 + mi * 16 + l4 * 4;
            long gc  = n0 + wn * 64 + ni * 16 + l15;
#pragma unroll
            for (int i = 0; i < 4; i++) {
                long gm = gmb + i;
                float v = acc[mi][ni][i];
                if (ROWB)  v += rowBias[gm];
                if (COLB)  v += colBias[gc];
                if (GELUF) v = 0.5f * v * (1.f + erff(v * 0.70710678118f));
                if (RES)   v += res[gm * (long)ldres + gc];
                if (OUT == 0)      outf[cOff + gm * (long)ldc + gc] = v;
                else if (OUT == 1) outb[cOff + gm * (long)ldc + gc] = (__bf16)v;
                else               outb[cOff + gc * (long)ldc + gm] = (__bf16)v;
            }
        }
}

// ========== gemm128_split: 128x128 tile split-K, writes f32 partials ==========
__global__ __launch_bounds__(256, 2) void gemm128_split(
    const __bf16* __restrict__ A, int lda, long aBS,
    const __bf16* __restrict__ Bt, int ldb, long bBS,
    float* __restrict__ P, long cBS, int ldc,
    int Ksplit, int S)
{
    __shared__ __bf16 Asm[128 * 64];
    __shared__ __bf16 Bsm[128 * 64];
    const int tid = threadIdx.x;
    const int lane = tid & 63, wave = tid >> 6;
    const int wm = wave >> 1, wn = wave & 1;
    const int l15 = lane & 15, l4 = lane >> 4;
    const long m0 = (long)blockIdx.x * 128, n0 = (long)blockIdx.y * 128;
    const long zb = blockIdx.z / S;
    const int  sp = blockIdx.z % S;
    A  += zb * aBS + (long)sp * Ksplit;
    Bt += zb * bBS + (long)sp * Ksplit;

    const int srow8 = lane >> 3;
    const int gunit = ((lane & 7) ^ srow8) << 3;
    const __bf16* Abase = A + (m0 + wave * 8 + srow8) * (long)lda + gunit;
    const __bf16* Bbase = Bt + (n0 + wave * 8 + srow8) * (long)ldb + gunit;
    __bf16* AsmW = Asm + wave * 8 * 64;
    __bf16* BsmW = Bsm + wave * 8 * 64;
    const int swz_r = l15 & 7;

    f32x4 acc[4][4];
#pragma unroll
    for (int mi = 0; mi < 4; mi++)
#pragma unroll
        for (int ni = 0; ni < 4; ni++) acc[mi][ni] = (f32x4){0.f, 0.f, 0.f, 0.f};

    for (int k0 = 0; k0 < Ksplit; k0 += 64) {
        __syncthreads();
#pragma unroll
        for (int p = 0; p < 4; p++) {
            __builtin_amdgcn_global_load_lds(
                (const __attribute__((address_space(1))) unsigned int*)(Abase + (long)p * 32 * lda + k0),
                (__attribute__((address_space(3))) unsigned int*)(AsmW + p * 32 * 64), 16, 0, 0);
            __builtin_amdgcn_global_load_lds(
                (const __attribute__((address_space(1))) unsigned int*)(Bbase + (long)p * 32 * ldb + k0),
                (__attribute__((address_space(3))) unsigned int*)(BsmW + p * 32 * 64), 16, 0, 0);
        }
        asm volatile("s_waitcnt vmcnt(0)" ::: "memory");
        __syncthreads();
#pragma unroll
        for (int ks = 0; ks < 2; ks++) {
            bf16x8 af[4], bfv[4];
#pragma unroll
            for (int mi = 0; mi < 4; mi++)
                af[mi] = *(const bf16x8*)(Asm + (wm * 64 + mi * 16 + l15) * 64 + (((ks * 4 + l4) ^ swz_r) << 3));
#pragma unroll
            for (int ni = 0; ni < 4; ni++)
                bfv[ni] = *(const bf16x8*)(Bsm + (wn * 64 + ni * 16 + l15) * 64 + (((ks * 4 + l4) ^ swz_r) << 3));
#pragma unroll
            for (int mi = 0; mi < 4; mi++)
#pragma unroll
                for (int ni = 0; ni < 4; ni++)
                    acc[mi][ni] = __builtin_amdgcn_mfma_f32_16x16x32_bf16(af[mi], bfv[ni], acc[mi][ni], 0, 0, 0);
        }
    }

    float* out = P + (long)blockIdx.z * cBS;
#pragma unroll
    for (int mi = 0; mi < 4; mi++)
#pragma unroll
        for (int ni = 0; ni < 4; ni++) {
            long gmb = m0 + wm * 64 + mi * 16 + l4 * 4;
            long gc  = n0 + wn * 64 + ni * 16 + l15;
#pragma unroll
            for (int i = 0; i < 4; i++)
                out[(gmb + i) * (long)ldc + gc] = acc[mi][ni][i];
        }
}

// ---------- reduce S f32 partials -> bf16 (+row bias, optional transposed write) ----------
template<bool BIAS, bool TRANS>
__global__ __launch_bounds__(256) void reduce_partials(
    const float* __restrict__ P, __bf16* __restrict__ out,
    const float* __restrict__ bias, int S, int M, int N, long pBS)
{
    int b = blockIdx.z;
    long idx = ((long)blockIdx.x * 256 + threadIdx.x) * 4;
    if (idx >= (long)M * N) return;
    const float* Pb = P + (long)b * S * pBS + idx;
    float4 a = *(const float4*)Pb;
    for (int s = 1; s < S; s++) {
        float4 v = *(const float4*)(Pb + (long)s * pBS);
        a.x += v.x; a.y += v.y; a.z += v.z; a.w += v.w;
    }
    int m = (int)(idx / N), n = (int)(idx % N);
    if (BIAS) { float bv = bias[m]; a.x += bv; a.y += bv; a.z += bv; a.w += bv; }
    float av[4] = {a.x, a.y, a.z, a.w};
    if (!TRANS) {
        __bf16* o = out + (long)b * M * N + idx;
        o[0] = (__bf16)av[0]; o[1] = (__bf16)av[1]; o[2] = (__bf16)av[2]; o[3] = (__bf16)av[3];
    } else {
#pragma unroll
        for (int j = 0; j < 4; j++)
            out[(long)b * M * N + (long)(n + j) * M + m] = (__bf16)av[j];
    }
}

// ---------------- fused Linformer attention ----------------
__global__ __launch_bounds__(256, 2) void attn_fused(
    const __bf16* __restrict__ Q, const __bf16* __restrict__ KP,
    const __bf16* __restrict__ VPt, __bf16* __restrict__ O)
{
    __shared__ __bf16 plds[4][4096];
    const int tid = threadIdx.x, lane = tid & 63, wave = tid >> 6;
    const int l15 = lane & 15, l4 = lane >> 4;
    const int h = blockIdx.y, b = blockIdx.z;
    const long row0 = (long)b * 4096 + (long)blockIdx.x * 64 + wave * 16;

    bf16x8 aq[2];
#pragma unroll
    for (int ks = 0; ks < 2; ks++)
        aq[ks] = *(const bf16x8*)(Q + (row0 + l15) * 1024 + h * 64 + ks * 32 + l4 * 8);

    f32x4 s[16];
#pragma unroll
    for (int f = 0; f < 16; f++) {
        f32x4 a = (f32x4){0.f, 0.f, 0.f, 0.f};
#pragma unroll
        for (int ks = 0; ks < 2; ks++) {
            bf16x8 bk = *(const bf16x8*)(KP + ((long)b * 256 + f * 16 + l15) * 1024 + h * 64 + ks * 32 + l4 * 8);
            a = __builtin_amdgcn_mfma_f32_16x16x32_bf16(aq[ks], bk, a, 0, 0, 0);
        }
        s[f] = a;
    }

    const float scale = 0.125f;
#pragma unroll
    for (int i = 0; i < 4; i++) {
        float m_ = -3.4e38f;
#pragma unroll
        for (int f = 0; f < 16; f++) { float v = s[f][i] * scale; s[f][i] = v; m_ = fmaxf(m_, v); }
#pragma unroll
        for (int msk = 1; msk < 16; msk <<= 1) m_ = fmaxf(m_, __shfl_xor(m_, msk));
        float su = 0.f;
#pragma unroll
        for (int f = 0; f < 16; f++) { float e = expf(s[f][i] - m_); s[f][i] = e; su += e; }
#pragma unroll
        for (int msk = 1; msk < 16; msk <<= 1) su += __shfl_xor(su, msk);
        float inv = 1.f / su;
#pragma unroll
        for (int f = 0; f < 16; f++) s[f][i] *= inv;
    }

    __bf16* pl = plds[wave];
#pragma unroll
    for (int f = 0; f < 16; f++)
#pragma unroll
        for (int i = 0; i < 4; i++) {
            int r = l4 * 4 + i, c = f * 16 + l15;
            int off = r * 256 + ((((c >> 3) ^ (r & 7)) << 3) | (c & 7));
            pl[off] = (__bf16)s[f][i];
        }

    f32x4 o[4];
#pragma unroll
    for (int f2 = 0; f2 < 4; f2++) o[f2] = (f32x4){0.f, 0.f, 0.f, 0.f};
#pragma unroll
    for (int ks = 0; ks < 8; ks++) {
        int kk = ks * 32 + l4 * 8;
        int off = l15 * 256 + (((kk >> 3) ^ (l15 & 7)) << 3);
        bf16x8 ap = *(const bf16x8*)(pl + off);
#pragma unroll
        for (int f2 = 0; f2 < 4; f2++) {
            bf16x8 bv = *(const bf16x8*)(VPt + ((long)b * 1024 + h * 64 + f2 * 16 + l15) * 256 + kk);
            o[f2] = __builtin_amdgcn_mfma_f32_16x16x32_bf16(ap, bv, o[f2], 0, 0, 0);
        }
    }
#pragma unroll
    for (int f2 = 0; f2 < 4; f2++)
#pragma unroll
        for (int i = 0; i < 4; i++)
            O[(row0 + l4 * 4 + i) * 1024 + h * 64 + f2 * 16 + l15] = (__bf16)o[f2][i];
}

// ---------------- LayerNorm (row=1024), writes f32 + bf16 ----------------
__global__ __launch_bounds__(256) void ln_kernel(const float* __restrict__ y,
    const float* __restrict__ g, const float* __restrict__ b,
    float* __restrict__ xout, __bf16* __restrict__ xb)
{
    const int row = blockIdx.x;
    const int t = threadIdx.x;
    const float4 v = ((const float4*)(y + (long)row * 1024))[t];
    float s  = v.x + v.y + v.z + v.w;
    float ss = v.x * v.x + v.y * v.y + v.z * v.z + v.w * v.w;
#pragma unroll
    for (int m = 1; m < 64; m <<= 1) { s += __shfl_xor(s, m); ss += __shfl_xor(ss, m); }
    __shared__ float red[2][4];
    const int wave = t >> 6, lane = t & 63;
    if (lane == 0) { red[0][wave] = s; red[1][wave] = ss; }
    __syncthreads();
    s  = red[0][0] + red[0][1] + red[0][2] + red[0][3];
    ss = red[1][0] + red[1][1] + red[1][2] + red[1][3];
    const float mu = s * (1.f / 1024.f);
    const float var = ss * (1.f / 1024.f) - mu * mu;
    const float rs = rsqrtf(var + 1e-5f);
    const float4 gv = ((const float4*)g)[t];
    const float4 bv = ((const float4*)b)[t];
    float o0 = (v.x - mu) * rs * gv.x + bv.x;
    float o1 = (v.y - mu) * rs * gv.y + bv.y;
    float o2 = (v.z - mu) * rs * gv.z + bv.z;
    float o3 = (v.w - mu) * rs * gv.w + bv.w;
    float4 ov; ov.x = o0; ov.y = o1; ov.z = o2; ov.w = o3;
    ((float4*)(xout + (long)row * 1024))[t] = ov;
    __bf16* xr = xb + (long)row * 1024 + t * 4;
    xr[0] = (__bf16)o0; xr[1] = (__bf16)o1; xr[2] = (__bf16)o2; xr[3] = (__bf16)o3;
}

// ---------------- host launch ----------------
extern "C" void kernel_launch(void* const* d_in, const int* in_sizes, int n_in,
                              void* d_out, int out_size, void* d_ws, size_t ws_size,
                              hipStream_t stream) {
    const float* x   = (const float*)d_in[0];
    const float* Wq  = (const float*)d_in[1];
    const float* Wk  = (const float*)d_in[2];
    const float* Wv  = (const float*)d_in[3];
    const float* Wo  = (const float*)d_in[4];
    const float* bo  = (const float*)d_in[5];
    const float* Ew  = (const float*)d_in[6];
    const float* Eb  = (const float*)d_in[7];
    const float* W1  = (const float*)d_in[8];
    const float* b1  = (const float*)d_in[9];
    const float* W2  = (const float*)d_in[10];
    const float* b2  = (const float*)d_in[11];
    const float* lng = (const float*)d_in[12];
    const float* lnb = (const float*)d_in[13];
    float* xout = (float*)d_out;

    char* base = (char*)d_ws;
    size_t off = 0;
    auto alloc = [&](size_t bytes) { void* p = base + off; off += (bytes + 255) & ~(size_t)255; return p; };
    __bf16* Wqt = (__bf16*)alloc(2ll * 1024 * 1024 * 2);
    __bf16* Wkt = (__bf16*)alloc(2ll * 1024 * 1024 * 2);
    __bf16* Wvt = (__bf16*)alloc(2ll * 1024 * 1024 * 2);
    __bf16* Wot = (__bf16*)alloc(2ll * 1024 * 1024 * 2);
    __bf16* W1t = (__bf16*)alloc(2ll * 1024 * 4096 * 2);
    __bf16* W2t = (__bf16*)alloc(2ll * 1024 * 4096 * 2);
    __bf16* Ewb = (__bf16*)alloc(256ll * 4096 * 2);
    __bf16* xb  = (__bf16*)alloc(8192ll * 1024 * 2);
    __bf16* xbT = (__bf16*)alloc(2ll * 1024 * 4096 * 2);
    float*  y   = (float*) alloc(8192ll * 1024 * 4);
    __bf16* xp  = (__bf16*)alloc(2ll * 256 * 1024 * 2);
    __bf16* KPb = (__bf16*)alloc(2ll * 256 * 1024 * 2);
    __bf16* VPt = (__bf16*)alloc(2ll * 1024 * 256 * 2);
    __bf16* big = (__bf16*)alloc(8192ll * 4096 * 2);   // 64 MB scratch region
    float*  xpP = (float*)big;                          // [16][256*1024] f32 = 16MB
    float*  kpP = (float*)((char*)big + (16ll << 20));  // [8][256*1024]  f32 =  8MB
    float*  vpP = (float*)((char*)big + (24ll << 20));  // [8][256*1024]  f32 =  8MB
    __bf16* Qb  = big;                                  // [8192][1024] (over xpP, dead)
    __bf16* Ob  = big + (16ll << 20);                   // [8192][1024] (over kpP/vpP, dead)
    __bf16* hbuf = big;                                 // [8192][4096] (FF stage)

    cvt_f32_bf16<<<2048, 256, 0, stream>>>(x, xb, 8388608);
    cvt_f32_bf16<<<1024, 256, 0, stream>>>(Ew, Ewb, 1048576);
    transpose_cvt<<<dim3(2, 32, 32),  dim3(32, 8), 0, stream>>>(Wq, Wqt, 64, 1024, 65536, 65536);
    transpose_cvt<<<dim3(2, 32, 32),  dim3(32, 8), 0, stream>>>(Wk, Wkt, 64, 1024, 65536, 65536);
    transpose_cvt<<<dim3(2, 32, 32),  dim3(32, 8), 0, stream>>>(Wv, Wvt, 64, 1024, 65536, 65536);
    transpose_cvt<<<dim3(32, 32, 2),  dim3(32, 8), 0, stream>>>(Wo, Wot, 1024, 1024, 1048576, 1048576);
    transpose_cvt<<<dim3(128, 32, 2), dim3(32, 8), 0, stream>>>(W1, W1t, 4096, 1024, 4194304, 4194304);
    transpose_cvt<<<dim3(32, 128, 2), dim3(32, 8), 0, stream>>>(W2, W2t, 1024, 4096, 4194304, 4194304);

    for (int l = 0; l < 2; l++) {
        const __bf16* Wqt_l = Wqt + (long)l * 1048576;
        const __bf16* Wkt_l = Wkt + (long)l * 1048576;
        const __bf16* Wvt_l = Wvt + (long)l * 1048576;
        const __bf16* Wot_l = Wot + (long)l * 1048576;
        const __bf16* W1t_l = W1t + (long)l * 4194304;
        const __bf16* W2t_l = W2t + (long)l * 4194304;
        const float* res = (l == 0) ? x : xout;

        // xbT[b] = xb[b]^T
        transpose_bf16<<<dim3(32, 128, 2), dim3(32, 8), 0, stream>>>(xb, xbT, 4096, 1024);
        // xp = Ew @ x  (split-K 8)
        gemm128_split<<<dim3(2, 8, 16), 256, 0, stream>>>(
            Ewb, 4096, 0, xbT, 4096, 4194304, xpP, 262144, 1024, 512, 8);
        reduce_partials<false, false><<<dim3(256, 1, 2), 256, 0, stream>>>(
            xpP, xp, nullptr, 8, 256, 1024, 262144);
        // KP = xp @ Wk^T + Eb  (split-K 4)
        gemm128_split<<<dim3(2, 8, 8), 256, 0, stream>>>(
            xp, 1024, 262144, Wkt_l, 1024, 0, kpP, 262144, 1024, 256, 4);
        reduce_partials<true, false><<<dim3(256, 1, 2), 256, 0, stream>>>(
            kpP, KPb, Eb, 4, 256, 1024, 262144);
        // VPt = (xp @ Wv^T + Eb)^T
        gemm128_split<<<dim3(2, 8, 8), 256, 0, stream>>>(
            xp, 1024, 262144, Wvt_l, 1024, 0, vpP, 262144, 1024, 256, 4);
        reduce_partials<true, true><<<dim3(256, 1, 2), 256, 0, stream>>>(
            vpP, VPt, Eb, 4, 256, 1024, 262144);
        // Q = xb @ Wq^T (round-2 kernel, proven)
        gemm_bf16<false, false, false, false, 1><<<dim3(64, 8, 1), 256, 0, stream>>>(
            xb, 1024, 0, Wqt_l, 1024, 0, (void*)Qb, 1024, 0, nullptr, nullptr, nullptr, 0, 1024);
        // attention
        attn_fused<<<dim3(64, 16, 2), 256, 0, stream>>>(Qb, KPb, VPt, Ob);
        // attn_out = O @ Wo^T + bo + residual  (round-2 kernel)
        gemm_bf16<false, true, false, true, 0><<<dim3(64, 8, 1), 256, 0, stream>>>(
            Ob, 1024, 0, Wot_l, 1024, 0, (void*)y, 1024, 0,
            nullptr, bo + l * 1024, res, 1024, 1024);
        ln_kernel<<<8192, 256, 0, stream>>>(y, lng + (2 * l + 0) * 1024, lnb + (2 * l + 0) * 1024, xout, xb);
        // h = gelu(x @ W1 + b1)  -- 8-phase kernel, grid 32x16 = 512 blocks
        gemm8p<true, true, false, 1><<<dim3(32, 16), 512, 0, stream>>>(
            xb, 1024, W1t_l, 1024, (void*)hbuf, 4096, b1 + l * 4096, nullptr, 0, 1024);
        // ff = h @ W2 + b2 + residual  -- 8-phase kernel, grid 32x4 = 128 blocks
        gemm8p<true, false, true, 0><<<dim3(32, 4), 512, 0, stream>>>(
            hbuf, 4096, W2t_l, 4096, (void*)y, 1024, b2 + l * 1024, xout, 1024, 4096);
        ln_kernel<<<8192, 256, 0, stream>>>(y, lng + (2 * l + 1) * 1024, lnb + (2 * l + 1) * 1024, xout, xb);
    }
}

// Round 7
// 813.284 us; speedup vs baseline: 1.7859x; 1.1157x over previous
//
#include <hip/hip_runtime.h>
#include <hip/hip_bf16.h>
#include <math.h>

// ---------------- types ----------------
typedef __bf16 bf16x8 __attribute__((ext_vector_type(8)));
typedef float f32x4 __attribute__((ext_vector_type(4)));

// ---------------- conversion kernels ----------------
__global__ void cvt_f32_bf16(const float* __restrict__ in, __bf16* __restrict__ out, long n) {
    long i = ((long)blockIdx.x * 256 + threadIdx.x) * 4;
    long stride = (long)gridDim.x * 1024;
    for (; i < n; i += stride) {
        float4 v = *(const float4*)(in + i);
        out[i + 0] = (__bf16)v.x;
        out[i + 1] = (__bf16)v.y;
        out[i + 2] = (__bf16)v.z;
        out[i + 3] = (__bf16)v.w;
    }
}

// transpose + convert: in f32 [M][N] (ldin) -> out bf16 [N][M] (ldout), batched over z
__global__ void transpose_cvt(const float* __restrict__ in, __bf16* __restrict__ out,
                              int ldin, int ldout, long inBS, long outBS) {
    __shared__ __bf16 tile[32][33];
    in  += (long)blockIdx.z * inBS;
    out += (long)blockIdx.z * outBS;
    int n0 = blockIdx.x * 32, m0 = blockIdx.y * 32;
    for (int i = threadIdx.y; i < 32; i += 8)
        tile[i][threadIdx.x] = (__bf16)in[(long)(m0 + i) * ldin + n0 + threadIdx.x];
    __syncthreads();
    for (int i = threadIdx.y; i < 32; i += 8)
        out[(long)(n0 + i) * ldout + m0 + threadIdx.x] = tile[threadIdx.x][i];
}

// bf16 transpose: in [rows][cols] -> out [cols][rows], batched over z
__global__ void transpose_bf16(const __bf16* __restrict__ in, __bf16* __restrict__ out,
                               int rows, int cols) {
    __shared__ __bf16 tile[32][33];
    in  += (long)blockIdx.z * rows * cols;
    out += (long)blockIdx.z * rows * cols;
    int c0 = blockIdx.x * 32, r0 = blockIdx.y * 32;
    for (int i = threadIdx.y; i < 32; i += 8)
        tile[i][threadIdx.x] = in[(long)(r0 + i) * cols + c0 + threadIdx.x];
    __syncthreads();
    for (int i = threadIdx.y; i < 32; i += 8)
        out[(long)(c0 + i) * rows + r0 + threadIdx.x] = tile[threadIdx.x][i];
}

// ---------------- GEMM (R2 proven structure + 8x8 patch swizzle) ----------------
// C[M,N] = A[M,K] @ Bt[N,K]^T (+epilogue). 128^2 tile, BK=64, 4 waves.
// OUT: 0 = f32 normal, 1 = bf16 normal, 2 = bf16 transposed
template<bool ROWB, bool COLB, bool GELUF, bool RES, int OUT>
__global__ __launch_bounds__(256, 2) void gemm_bf16(
    const __bf16* __restrict__ A, int lda, long aBS,
    const __bf16* __restrict__ Bt, int ldb, long bBS,
    void* __restrict__ outp, int ldc, long cBS,
    const float* __restrict__ rowBias,
    const float* __restrict__ colBias,
    const float* __restrict__ res, int ldres,
    int K)
{
    __shared__ __bf16 Asm[128 * 64];
    __shared__ __bf16 Bsm[128 * 64];
    const int tid = threadIdx.x;
    const int lane = tid & 63, wave = tid >> 6;
    const int wm = wave >> 1, wn = wave & 1;
    const int l15 = lane & 15, l4 = lane >> 4;

    // Block swizzle. Preferred: 8x8 patch per XCD (working set = 2MB A + 2MB B = L2).
    // Assumes HW round-robin dispatch: xcd = id & 7 (perf heuristic only).
    int bx = blockIdx.x, by = blockIdx.y;
    {
        int gx = gridDim.x, gy = gridDim.y;
        int nb = gx * gy;
        if ((gx & 7) == 0 && (gy & 7) == 0 && (nb & 511) == 0) {
            int id = by * gx + bx;
            int xcd = id & 7, local = id >> 3;
            int t = local >> 6, within = local & 63;
            int ppx = gx >> 3;            // patch grid width
            int ppc = nb >> 9;            // patches per XCD
            int pid = xcd * ppc + t;
            int pgy = pid / ppx, pgx = pid % ppx;
            bx = pgx * 8 + (within & 7);
            by = pgy * 8 + (within >> 3);
        } else if ((nb & 7) == 0) {
            int id = by * gx + bx;
            int cpx = nb >> 3;
            int swz = (id & 7) * cpx + (id >> 3);
            bx = swz % gx;
            by = swz / gx;
        }
    }
    const long m0 = (long)bx * 128, n0 = (long)by * 128;
    A  += (long)blockIdx.z * aBS;
    Bt += (long)blockIdx.z * bBS;

    // staging: pre-swizzled global source so LDS[r][u16] = G[r][u ^ (r&7)]
    const int srow8 = lane >> 3;
    const int gunit = ((lane & 7) ^ srow8) << 3;
    const __bf16* Abase = A  + (m0 + wave * 8 + srow8) * (long)lda + gunit;
    const __bf16* Bbase = Bt + (n0 + wave * 8 + srow8) * (long)ldb + gunit;
    __bf16* AsmW = Asm + wave * 8 * 64;
    __bf16* BsmW = Bsm + wave * 8 * 64;
    const int swz_r = l15 & 7;

    f32x4 acc[4][4];
#pragma unroll
    for (int mi = 0; mi < 4; mi++)
#pragma unroll
        for (int ni = 0; ni < 4; ni++) acc[mi][ni] = (f32x4){0.f, 0.f, 0.f, 0.f};

    for (int k0 = 0; k0 < K; k0 += 64) {
        __syncthreads();
#pragma unroll
        for (int p = 0; p < 4; p++) {
            __builtin_amdgcn_global_load_lds(
                (const __attribute__((address_space(1))) unsigned int*)(Abase + (long)p * 32 * lda + k0),
                (__attribute__((address_space(3))) unsigned int*)(AsmW + p * 32 * 64), 16, 0, 0);
            __builtin_amdgcn_global_load_lds(
                (const __attribute__((address_space(1))) unsigned int*)(Bbase + (long)p * 32 * ldb + k0),
                (__attribute__((address_space(3))) unsigned int*)(BsmW + p * 32 * 64), 16, 0, 0);
        }
        asm volatile("s_waitcnt vmcnt(0)" ::: "memory");
        __syncthreads();
#pragma unroll
        for (int ks = 0; ks < 2; ks++) {
            bf16x8 af[4], bfv[4];
#pragma unroll
            for (int mi = 0; mi < 4; mi++)
                af[mi] = *(const bf16x8*)(Asm + (wm * 64 + mi * 16 + l15) * 64 + (((ks * 4 + l4) ^ swz_r) << 3));
#pragma unroll
            for (int ni = 0; ni < 4; ni++)
                bfv[ni] = *(const bf16x8*)(Bsm + (wn * 64 + ni * 16 + l15) * 64 + (((ks * 4 + l4) ^ swz_r) << 3));
#pragma unroll
            for (int mi = 0; mi < 4; mi++)
#pragma unroll
                for (int ni = 0; ni < 4; ni++)
                    acc[mi][ni] = __builtin_amdgcn_mfma_f32_16x16x32_bf16(af[mi], bfv[ni], acc[mi][ni], 0, 0, 0);
        }
    }

    float* outf = (float*)outp;
    __bf16* outb = (__bf16*)outp;
    const long cOff = (long)blockIdx.z * cBS;
#pragma unroll
    for (int mi = 0; mi < 4; mi++)
#pragma unroll
        for (int ni = 0; ni < 4; ni++) {
            long gmb = m0 + wm * 64 + mi * 16 + l4 * 4;
            long gc  = n0 + wn * 64 + ni * 16 + l15;
#pragma unroll
            for (int i = 0; i < 4; i++) {
                long gm = gmb + i;
                float v = acc[mi][ni][i];
                if (ROWB)  v += rowBias[gm];
                if (COLB)  v += colBias[gc];
                if (GELUF) v = 0.5f * v * (1.f + erff(v * 0.70710678118f));
                if (RES)   v += res[gm * (long)ldres + gc];
                if (OUT == 0)      outf[cOff + gm * (long)ldc + gc] = v;
                else if (OUT == 1) outb[cOff + gm * (long)ldc + gc] = (__bf16)v;
                else               outb[cOff + gc * (long)ldc + gm] = (__bf16)v;
            }
        }
}

// ========== gemm128_split: 128x128 tile split-K, writes f32 partials ==========
__global__ __launch_bounds__(256, 2) void gemm128_split(
    const __bf16* __restrict__ A, int lda, long aBS,
    const __bf16* __restrict__ Bt, int ldb, long bBS,
    float* __restrict__ P, long cBS, int ldc,
    int Ksplit, int S)
{
    __shared__ __bf16 Asm[128 * 64];
    __shared__ __bf16 Bsm[128 * 64];
    const int tid = threadIdx.x;
    const int lane = tid & 63, wave = tid >> 6;
    const int wm = wave >> 1, wn = wave & 1;
    const int l15 = lane & 15, l4 = lane >> 4;
    const long m0 = (long)blockIdx.x * 128, n0 = (long)blockIdx.y * 128;
    const long zb = blockIdx.z / S;
    const int  sp = blockIdx.z % S;
    A  += zb * aBS + (long)sp * Ksplit;
    Bt += zb * bBS + (long)sp * Ksplit;

    const int srow8 = lane >> 3;
    const int gunit = ((lane & 7) ^ srow8) << 3;
    const __bf16* Abase = A + (m0 + wave * 8 + srow8) * (long)lda + gunit;
    const __bf16* Bbase = Bt + (n0 + wave * 8 + srow8) * (long)ldb + gunit;
    __bf16* AsmW = Asm + wave * 8 * 64;
    __bf16* BsmW = Bsm + wave * 8 * 64;
    const int swz_r = l15 & 7;

    f32x4 acc[4][4];
#pragma unroll
    for (int mi = 0; mi < 4; mi++)
#pragma unroll
        for (int ni = 0; ni < 4; ni++) acc[mi][ni] = (f32x4){0.f, 0.f, 0.f, 0.f};

    for (int k0 = 0; k0 < Ksplit; k0 += 64) {
        __syncthreads();
#pragma unroll
        for (int p = 0; p < 4; p++) {
            __builtin_amdgcn_global_load_lds(
                (const __attribute__((address_space(1))) unsigned int*)(Abase + (long)p * 32 * lda + k0),
                (__attribute__((address_space(3))) unsigned int*)(AsmW + p * 32 * 64), 16, 0, 0);
            __builtin_amdgcn_global_load_lds(
                (const __attribute__((address_space(1))) unsigned int*)(Bbase + (long)p * 32 * ldb + k0),
                (__attribute__((address_space(3))) unsigned int*)(BsmW + p * 32 * 64), 16, 0, 0);
        }
        asm volatile("s_waitcnt vmcnt(0)" ::: "memory");
        __syncthreads();
#pragma unroll
        for (int ks = 0; ks < 2; ks++) {
            bf16x8 af[4], bfv[4];
#pragma unroll
            for (int mi = 0; mi < 4; mi++)
                af[mi] = *(const bf16x8*)(Asm + (wm * 64 + mi * 16 + l15) * 64 + (((ks * 4 + l4) ^ swz_r) << 3));
#pragma unroll
            for (int ni = 0; ni < 4; ni++)
                bfv[ni] = *(const bf16x8*)(Bsm + (wn * 64 + ni * 16 + l15) * 64 + (((ks * 4 + l4) ^ swz_r) << 3));
#pragma unroll
            for (int mi = 0; mi < 4; mi++)
#pragma unroll
                for (int ni = 0; ni < 4; ni++)
                    acc[mi][ni] = __builtin_amdgcn_mfma_f32_16x16x32_bf16(af[mi], bfv[ni], acc[mi][ni], 0, 0, 0);
        }
    }

    float* out = P + (long)blockIdx.z * cBS;
#pragma unroll
    for (int mi = 0; mi < 4; mi++)
#pragma unroll
        for (int ni = 0; ni < 4; ni++) {
            long gmb = m0 + wm * 64 + mi * 16 + l4 * 4;
            long gc  = n0 + wn * 64 + ni * 16 + l15;
#pragma unroll
            for (int i = 0; i < 4; i++)
                out[(gmb + i) * (long)ldc + gc] = acc[mi][ni][i];
        }
}

// ---------- reduce S f32 partials -> bf16 (+row bias, optional transposed write) ----------
template<bool BIAS, bool TRANS>
__global__ __launch_bounds__(256) void reduce_partials(
    const float* __restrict__ P, __bf16* __restrict__ out,
    const float* __restrict__ bias, int S, int M, int N, long pBS)
{
    int b = blockIdx.z;
    long idx = ((long)blockIdx.x * 256 + threadIdx.x) * 4;
    if (idx >= (long)M * N) return;
    const float* Pb = P + (long)b * S * pBS + idx;
    float4 a = *(const float4*)Pb;
    for (int s = 1; s < S; s++) {
        float4 v = *(const float4*)(Pb + (long)s * pBS);
        a.x += v.x; a.y += v.y; a.z += v.z; a.w += v.w;
    }
    int m = (int)(idx / N), n = (int)(idx % N);
    if (BIAS) { float bv = bias[m]; a.x += bv; a.y += bv; a.z += bv; a.w += bv; }
    float av[4] = {a.x, a.y, a.z, a.w};
    if (!TRANS) {
        __bf16* o = out + (long)b * M * N + idx;
        o[0] = (__bf16)av[0]; o[1] = (__bf16)av[1]; o[2] = (__bf16)av[2]; o[3] = (__bf16)av[3];
    } else {
#pragma unroll
        for (int j = 0; j < 4; j++)
            out[(long)b * M * N + (long)(n + j) * M + m] = (__bf16)av[j];
    }
}

// ---------------- fused Linformer attention ----------------
__global__ __launch_bounds__(256, 2) void attn_fused(
    const __bf16* __restrict__ Q, const __bf16* __restrict__ KP,
    const __bf16* __restrict__ VPt, __bf16* __restrict__ O)
{
    __shared__ __bf16 plds[4][4096];
    const int tid = threadIdx.x, lane = tid & 63, wave = tid >> 6;
    const int l15 = lane & 15, l4 = lane >> 4;
    const int h = blockIdx.y, b = blockIdx.z;
    const long row0 = (long)b * 4096 + (long)blockIdx.x * 64 + wave * 16;

    bf16x8 aq[2];
#pragma unroll
    for (int ks = 0; ks < 2; ks++)
        aq[ks] = *(const bf16x8*)(Q + (row0 + l15) * 1024 + h * 64 + ks * 32 + l4 * 8);

    f32x4 s[16];
#pragma unroll
    for (int f = 0; f < 16; f++) {
        f32x4 a = (f32x4){0.f, 0.f, 0.f, 0.f};
#pragma unroll
        for (int ks = 0; ks < 2; ks++) {
            bf16x8 bk = *(const bf16x8*)(KP + ((long)b * 256 + f * 16 + l15) * 1024 + h * 64 + ks * 32 + l4 * 8);
            a = __builtin_amdgcn_mfma_f32_16x16x32_bf16(aq[ks], bk, a, 0, 0, 0);
        }
        s[f] = a;
    }

    const float scale = 0.125f;
#pragma unroll
    for (int i = 0; i < 4; i++) {
        float m_ = -3.4e38f;
#pragma unroll
        for (int f = 0; f < 16; f++) { float v = s[f][i] * scale; s[f][i] = v; m_ = fmaxf(m_, v); }
#pragma unroll
        for (int msk = 1; msk < 16; msk <<= 1) m_ = fmaxf(m_, __shfl_xor(m_, msk));
        float su = 0.f;
#pragma unroll
        for (int f = 0; f < 16; f++) { float e = expf(s[f][i] - m_); s[f][i] = e; su += e; }
#pragma unroll
        for (int msk = 1; msk < 16; msk <<= 1) su += __shfl_xor(su, msk);
        float inv = 1.f / su;
#pragma unroll
        for (int f = 0; f < 16; f++) s[f][i] *= inv;
    }

    __bf16* pl = plds[wave];
#pragma unroll
    for (int f = 0; f < 16; f++)
#pragma unroll
        for (int i = 0; i < 4; i++) {
            int r = l4 * 4 + i, c = f * 16 + l15;
            int off = r * 256 + ((((c >> 3) ^ (r & 7)) << 3) | (c & 7));
            pl[off] = (__bf16)s[f][i];
        }

    f32x4 o[4];
#pragma unroll
    for (int f2 = 0; f2 < 4; f2++) o[f2] = (f32x4){0.f, 0.f, 0.f, 0.f};
#pragma unroll
    for (int ks = 0; ks < 8; ks++) {
        int kk = ks * 32 + l4 * 8;
        int off = l15 * 256 + (((kk >> 3) ^ (l15 & 7)) << 3);
        bf16x8 ap = *(const bf16x8*)(pl + off);
#pragma unroll
        for (int f2 = 0; f2 < 4; f2++) {
            bf16x8 bv = *(const bf16x8*)(VPt + ((long)b * 1024 + h * 64 + f2 * 16 + l15) * 256 + kk);
            o[f2] = __builtin_amdgcn_mfma_f32_16x16x32_bf16(ap, bv, o[f2], 0, 0, 0);
        }
    }
#pragma unroll
    for (int f2 = 0; f2 < 4; f2++)
#pragma unroll
        for (int i = 0; i < 4; i++)
            O[(row0 + l4 * 4 + i) * 1024 + h * 64 + f2 * 16 + l15] = (__bf16)o[f2][i];
}

// ---------------- LayerNorm (row=1024), writes f32 + bf16 ----------------
__global__ __launch_bounds__(256) void ln_kernel(const float* __restrict__ y,
    const float* __restrict__ g, const float* __restrict__ b,
    float* __restrict__ xout, __bf16* __restrict__ xb)
{
    const int row = blockIdx.x;
    const int t = threadIdx.x;
    const float4 v = ((const float4*)(y + (long)row * 1024))[t];
    float s  = v.x + v.y + v.z + v.w;
    float ss = v.x * v.x + v.y * v.y + v.z * v.z + v.w * v.w;
#pragma unroll
    for (int m = 1; m < 64; m <<= 1) { s += __shfl_xor(s, m); ss += __shfl_xor(ss, m); }
    __shared__ float red[2][4];
    const int wave = t >> 6, lane = t & 63;
    if (lane == 0) { red[0][wave] = s; red[1][wave] = ss; }
    __syncthreads();
    s  = red[0][0] + red[0][1] + red[0][2] + red[0][3];
    ss = red[1][0] + red[1][1] + red[1][2] + red[1][3];
    const float mu = s * (1.f / 1024.f);
    const float var = ss * (1.f / 1024.f) - mu * mu;
    const float rs = rsqrtf(var + 1e-5f);
    const float4 gv = ((const float4*)g)[t];
    const float4 bv = ((const float4*)b)[t];
    float o0 = (v.x - mu) * rs * gv.x + bv.x;
    float o1 = (v.y - mu) * rs * gv.y + bv.y;
    float o2 = (v.z - mu) * rs * gv.z + bv.z;
    float o3 = (v.w - mu) * rs * gv.w + bv.w;
    float4 ov; ov.x = o0; ov.y = o1; ov.z = o2; ov.w = o3;
    ((float4*)(xout + (long)row * 1024))[t] = ov;
    __bf16* xr = xb + (long)row * 1024 + t * 4;
    xr[0] = (__bf16)o0; xr[1] = (__bf16)o1; xr[2] = (__bf16)o2; xr[3] = (__bf16)o3;
}

// ---------------- host launch ----------------
extern "C" void kernel_launch(void* const* d_in, const int* in_sizes, int n_in,
                              void* d_out, int out_size, void* d_ws, size_t ws_size,
                              hipStream_t stream) {
    const float* x   = (const float*)d_in[0];
    const float* Wq  = (const float*)d_in[1];
    const float* Wk  = (const float*)d_in[2];
    const float* Wv  = (const float*)d_in[3];
    const float* Wo  = (const float*)d_in[4];
    const float* bo  = (const float*)d_in[5];
    const float* Ew  = (const float*)d_in[6];
    const float* Eb  = (const float*)d_in[7];
    const float* W1  = (const float*)d_in[8];
    const float* b1  = (const float*)d_in[9];
    const float* W2  = (const float*)d_in[10];
    const float* b2  = (const float*)d_in[11];
    const float* lng = (const float*)d_in[12];
    const float* lnb = (const float*)d_in[13];
    float* xout = (float*)d_out;

    char* base = (char*)d_ws;
    size_t off = 0;
    auto alloc = [&](size_t bytes) { void* p = base + off; off += (bytes + 255) & ~(size_t)255; return p; };
    __bf16* Wqt = (__bf16*)alloc(2ll * 1024 * 1024 * 2);
    __bf16* Wkt = (__bf16*)alloc(2ll * 1024 * 1024 * 2);
    __bf16* Wvt = (__bf16*)alloc(2ll * 1024 * 1024 * 2);
    __bf16* Wot = (__bf16*)alloc(2ll * 1024 * 1024 * 2);
    __bf16* W1t = (__bf16*)alloc(2ll * 1024 * 4096 * 2);
    __bf16* W2t = (__bf16*)alloc(2ll * 1024 * 4096 * 2);
    __bf16* Ewb = (__bf16*)alloc(256ll * 4096 * 2);
    __bf16* xb  = (__bf16*)alloc(8192ll * 1024 * 2);
    __bf16* xbT = (__bf16*)alloc(2ll * 1024 * 4096 * 2);
    float*  y   = (float*) alloc(8192ll * 1024 * 4);
    __bf16* xp  = (__bf16*)alloc(2ll * 256 * 1024 * 2);
    __bf16* KPb = (__bf16*)alloc(2ll * 256 * 1024 * 2);
    __bf16* VPt = (__bf16*)alloc(2ll * 1024 * 256 * 2);
    __bf16* big = (__bf16*)alloc(8192ll * 4096 * 2);   // 64 MB scratch region
    float*  xpP = (float*)big;                          // [16][256*1024] f32 = 16MB
    float*  kpP = (float*)((char*)big + (16ll << 20));  // [8][256*1024]  f32 =  8MB
    float*  vpP = (float*)((char*)big + (24ll << 20));  // [8][256*1024]  f32 =  8MB
    __bf16* Qb  = big;                                  // [8192][1024] (over xpP, dead)
    __bf16* Ob  = big + (16ll << 20);                   // [8192][1024] (over kpP/vpP, dead)
    __bf16* hbuf = big;                                 // [8192][4096] (FF stage)

    cvt_f32_bf16<<<2048, 256, 0, stream>>>(x, xb, 8388608);
    cvt_f32_bf16<<<1024, 256, 0, stream>>>(Ew, Ewb, 1048576);
    transpose_cvt<<<dim3(2, 32, 32),  dim3(32, 8), 0, stream>>>(Wq, Wqt, 64, 1024, 65536, 65536);
    transpose_cvt<<<dim3(2, 32, 32),  dim3(32, 8), 0, stream>>>(Wk, Wkt, 64, 1024, 65536, 65536);
    transpose_cvt<<<dim3(2, 32, 32),  dim3(32, 8), 0, stream>>>(Wv, Wvt, 64, 1024, 65536, 65536);
    transpose_cvt<<<dim3(32, 32, 2),  dim3(32, 8), 0, stream>>>(Wo, Wot, 1024, 1024, 1048576, 1048576);
    transpose_cvt<<<dim3(128, 32, 2), dim3(32, 8), 0, stream>>>(W1, W1t, 4096, 1024, 4194304, 4194304);
    transpose_cvt<<<dim3(32, 128, 2), dim3(32, 8), 0, stream>>>(W2, W2t, 1024, 4096, 4194304, 4194304);

    for (int l = 0; l < 2; l++) {
        const __bf16* Wqt_l = Wqt + (long)l * 1048576;
        const __bf16* Wkt_l = Wkt + (long)l * 1048576;
        const __bf16* Wvt_l = Wvt + (long)l * 1048576;
        const __bf16* Wot_l = Wot + (long)l * 1048576;
        const __bf16* W1t_l = W1t + (long)l * 4194304;
        const __bf16* W2t_l = W2t + (long)l * 4194304;
        const float* res = (l == 0) ? x : xout;

        // xbT[b] = xb[b]^T
        transpose_bf16<<<dim3(32, 128, 2), dim3(32, 8), 0, stream>>>(xb, xbT, 4096, 1024);
        // xp = Ew @ x  (split-K 8)
        gemm128_split<<<dim3(2, 8, 16), 256, 0, stream>>>(
            Ewb, 4096, 0, xbT, 4096, 4194304, xpP, 262144, 1024, 512, 8);
        reduce_partials<false, false><<<dim3(256, 1, 2), 256, 0, stream>>>(
            xpP, xp, nullptr, 8, 256, 1024, 262144);
        // KP = xp @ Wk^T + Eb  (split-K 4)
        gemm128_split<<<dim3(2, 8, 8), 256, 0, stream>>>(
            xp, 1024, 262144, Wkt_l, 1024, 0, kpP, 262144, 1024, 256, 4);
        reduce_partials<true, false><<<dim3(256, 1, 2), 256, 0, stream>>>(
            kpP, KPb, Eb, 4, 256, 1024, 262144);
        // VPt = (xp @ Wv^T + Eb)^T
        gemm128_split<<<dim3(2, 8, 8), 256, 0, stream>>>(
            xp, 1024, 262144, Wvt_l, 1024, 0, vpP, 262144, 1024, 256, 4);
        reduce_partials<true, true><<<dim3(256, 1, 2), 256, 0, stream>>>(
            vpP, VPt, Eb, 4, 256, 1024, 262144);
        // Q = xb @ Wq^T
        gemm_bf16<false, false, false, false, 1><<<dim3(64, 8, 1), 256, 0, stream>>>(
            xb, 1024, 0, Wqt_l, 1024, 0, (void*)Qb, 1024, 0, nullptr, nullptr, nullptr, 0, 1024);
        // attention
        attn_fused<<<dim3(64, 16, 2), 256, 0, stream>>>(Qb, KPb, VPt, Ob);
        // attn_out = O @ Wo^T + bo + residual
        gemm_bf16<false, true, false, true, 0><<<dim3(64, 8, 1), 256, 0, stream>>>(
            Ob, 1024, 0, Wot_l, 1024, 0, (void*)y, 1024, 0,
            nullptr, bo + l * 1024, res, 1024, 1024);
        ln_kernel<<<8192, 256, 0, stream>>>(y, lng + (2 * l + 0) * 1024, lnb + (2 * l + 0) * 1024, xout, xb);
        // h = gelu(x @ W1 + b1)
        gemm_bf16<false, true, true, false, 1><<<dim3(64, 32, 1), 256, 0, stream>>>(
            xb, 1024, 0, W1t_l, 1024, 0, (void*)hbuf, 4096, 0,
            nullptr, b1 + l * 4096, nullptr, 0, 1024);
        // ff = h @ W2 + b2 + residual
        gemm_bf16<false, true, false, true, 0><<<dim3(64, 8, 1), 256, 0, stream>>>(
            hbuf, 4096, 0, W2t_l, 4096, 0, (void*)y, 1024, 0,
            nullptr, b2 + l * 1024, xout, 1024, 4096);
        ln_kernel<<<8192, 256, 0, stream>>>(y, lng + (2 * l + 1) * 1024, lnb + (2 * l + 1) * 1024, xout, xb);
    }
}

// Round 8
// 809.753 us; speedup vs baseline: 1.7937x; 1.0044x over previous
//
#include <hip/hip_runtime.h>
#include <hip/hip_bf16.h>
#include <math.h>

// ---------------- types ----------------
typedef __bf16 bf16x8 __attribute__((ext_vector_type(8)));
typedef float f32x4 __attribute__((ext_vector_type(4)));

// ---------------- conversion kernels ----------------
__global__ void cvt_f32_bf16(const float* __restrict__ in, __bf16* __restrict__ out, long n) {
    long i = ((long)blockIdx.x * 256 + threadIdx.x) * 4;
    long stride = (long)gridDim.x * 1024;
    for (; i < n; i += stride) {
        float4 v = *(const float4*)(in + i);
        out[i + 0] = (__bf16)v.x;
        out[i + 1] = (__bf16)v.y;
        out[i + 2] = (__bf16)v.z;
        out[i + 3] = (__bf16)v.w;
    }
}

// transpose + convert: in f32 [M][N] (ldin) -> out bf16 [N][M] (ldout), batched over z
__global__ void transpose_cvt(const float* __restrict__ in, __bf16* __restrict__ out,
                              int ldin, int ldout, long inBS, long outBS) {
    __shared__ __bf16 tile[32][33];
    in  += (long)blockIdx.z * inBS;
    out += (long)blockIdx.z * outBS;
    int n0 = blockIdx.x * 32, m0 = blockIdx.y * 32;
    for (int i = threadIdx.y; i < 32; i += 8)
        tile[i][threadIdx.x] = (__bf16)in[(long)(m0 + i) * ldin + n0 + threadIdx.x];
    __syncthreads();
    for (int i = threadIdx.y; i < 32; i += 8)
        out[(long)(n0 + i) * ldout + m0 + threadIdx.x] = tile[threadIdx.x][i];
}

// bf16 transpose: in [rows][cols] -> out [cols][rows], batched over z
__global__ void transpose_bf16(const __bf16* __restrict__ in, __bf16* __restrict__ out,
                               int rows, int cols) {
    __shared__ __bf16 tile[32][33];
    in  += (long)blockIdx.z * rows * cols;
    out += (long)blockIdx.z * rows * cols;
    int c0 = blockIdx.x * 32, r0 = blockIdx.y * 32;
    for (int i = threadIdx.y; i < 32; i += 8)
        tile[i][threadIdx.x] = in[(long)(r0 + i) * cols + c0 + threadIdx.x];
    __syncthreads();
    for (int i = threadIdx.y; i < 32; i += 8)
        out[(long)(c0 + i) * rows + r0 + threadIdx.x] = tile[threadIdx.x][i];
}

// ============== gemm8p: 256x256 tile, BK=64, 8-phase counted-vmcnt schedule ==============
// Stage table per iter (computes tiles T buf0 / T+1 buf1):
//   p0: A0(T+1)  p1: A1(T+1)  p2: B0(T+2)  p3: B1(T+2)
//   p4: A0(T+2)  p5: A1(T+2)  p6: B0(T+3)  p7: B1(T+3)
// vmcnt(4) at end of p3 and p7 (never 0 mid-loop). L2 residency via 4x4-block patch
// per XCD (A 2MB + B 2MB = 4MB = L2) -- the prerequisite R6 was missing.
template<bool COLB, bool GELUF, bool RES, int OUT>
__global__ __launch_bounds__(512, 2) void gemm8p(
    const __bf16* __restrict__ A, int lda,
    const __bf16* __restrict__ Bt, int ldb,
    void* __restrict__ outp, int ldc,
    const float* __restrict__ colBias,
    const float* __restrict__ res, int ldres,
    int K)
{
    __shared__ __bf16 Asm[2][16384];
    __shared__ __bf16 Bsm[2][16384];

    const int tid = threadIdx.x, lane = tid & 63, wave = tid >> 6;
    const int l15 = lane & 15, l4 = lane >> 4;
    const int wm = wave >> 2, wn = wave & 3;

    // 4x4-patch XCD swizzle (gx%4==0, gy%4==0, nb%128==0)
    int bx = blockIdx.x, by = blockIdx.y;
    {
        int gx = gridDim.x, gy = gridDim.y, nb = gx * gy;
        if ((gx & 3) == 0 && (gy & 3) == 0 && (nb & 127) == 0) {
            int id = by * gx + bx;
            int xcd = id & 7, local = id >> 3;
            int ppc = nb >> 7;                 // patches per XCD
            int t = local >> 4, within = local & 15;
            int pid = xcd * ppc + t;
            int ppx = gx >> 2;
            int pgy = pid / ppx, pgx = pid % ppx;
            bx = pgx * 4 + (within & 3);
            by = pgy * 4 + (within >> 2);
        }
    }
    const long m0 = (long)bx * 256, n0 = (long)by * 256;

    // staging: half-tile = 128 rows x 64 cols; 8 waves x 2 loads; source pre-swizzled
    const int srw = lane >> 3;
    const int scol = ((lane & 7) ^ srw) << 3;
    const __bf16* Abp = A  + (m0 + wave * 16 + srw) * (long)lda + scol;
    const __bf16* Bbp = Bt + (n0 + wave * 16 + srw) * (long)ldb + scol;

    auto stA = [&](int buf, int half, int tau) {
        const __bf16* s = Abp + (long)half * 128 * lda + (long)tau * 64;
        __bf16* d = &Asm[buf][(half * 128 + wave * 16) * 64];
#pragma unroll
        for (int j = 0; j < 2; j++)
            __builtin_amdgcn_global_load_lds(
                (const __attribute__((address_space(1))) unsigned int*)(s + (long)j * 8 * lda),
                (__attribute__((address_space(3))) unsigned int*)(d + j * 512), 16, 0, 0);
    };
    auto stB = [&](int buf, int half, int tau) {
        const __bf16* s = Bbp + (long)half * 128 * ldb + (long)tau * 64;
        __bf16* d = &Bsm[buf][(half * 128 + wave * 16) * 64];
#pragma unroll
        for (int j = 0; j < 2; j++)
            __builtin_amdgcn_global_load_lds(
                (const __attribute__((address_space(1))) unsigned int*)(s + (long)j * 8 * ldb),
                (__attribute__((address_space(3))) unsigned int*)(d + j * 512), 16, 0, 0);
    };
    auto ldAf = [&](int buf, int mi, int kk) -> bf16x8 {
        return *(const bf16x8*)&Asm[buf][(wm * 128 + mi * 16 + l15) * 64 + (((kk * 4 + l4) ^ (l15 & 7)) << 3)];
    };
    auto ldBf = [&](int buf, int ni, int kk) -> bf16x8 {
        return *(const bf16x8*)&Bsm[buf][(wn * 64 + ni * 16 + l15) * 64 + (((kk * 4 + l4) ^ (l15 & 7)) << 3)];
    };

    f32x4 acc[8][4];
#pragma unroll
    for (int mi = 0; mi < 8; mi++)
#pragma unroll
        for (int ni = 0; ni < 4; ni++) acc[mi][ni] = (f32x4){0.f, 0.f, 0.f, 0.f};

    const int NT = K >> 6, NI = K >> 7;
    // prologue: tile0 A+B, tile1 B; retire tile0 (8 loads), keep B(1) (4) in flight
    stB(0, 0, 0); stB(0, 1, 0); stA(0, 0, 0); stA(0, 1, 0);
    stB(1, 0, 1); stB(1, 1, 1);
    __builtin_amdgcn_sched_barrier(0);
    asm volatile("s_waitcnt vmcnt(4)" ::: "memory");
    __builtin_amdgcn_sched_barrier(0);
    __builtin_amdgcn_s_barrier();

    bf16x8 Breg[2][4];
    for (int it = 0; it < NI; ++it) {
        const int T = it << 1;
        const bool last = (it == NI - 1);
#pragma unroll
        for (int p = 0; p < 8; ++p) {
            const int buf = p >> 2;
            const int q = p & 3;
            if (q == 0) {
#pragma unroll
                for (int kk = 0; kk < 2; kk++)
#pragma unroll
                    for (int ni = 0; ni < 4; ni++)
                        Breg[kk][ni] = ldBf(buf, ni, kk);
            }
            bf16x8 a00 = ldAf(buf, 2 * q, 0),     a01 = ldAf(buf, 2 * q, 1);
            bf16x8 a10 = ldAf(buf, 2 * q + 1, 0), a11 = ldAf(buf, 2 * q + 1, 1);
            if      (p == 0) { stA(1, 0, T + 1); }
            else if (p == 1) { stA(1, 1, T + 1); }
            else if (p == 2) { if (!last) stB(0, 0, T + 2); }
            else if (p == 3) { if (!last) stB(0, 1, T + 2); }
            else if (p == 4) { if (!last) stA(0, 0, T + 2); }
            else if (p == 5) { if (!last) stA(0, 1, T + 2); }
            else if (p == 6) { if (!last) stB(1, 0, T + 3); }
            else             { if (!last) stB(1, 1, T + 3); }
            __builtin_amdgcn_sched_barrier(0);
            __builtin_amdgcn_s_barrier();
            asm volatile("s_waitcnt lgkmcnt(0)" ::: "memory");
            __builtin_amdgcn_sched_barrier(0);
            __builtin_amdgcn_s_setprio(1);
#pragma unroll
            for (int ni = 0; ni < 4; ni++) {
                acc[2 * q][ni]     = __builtin_amdgcn_mfma_f32_16x16x32_bf16(a00, Breg[0][ni], acc[2 * q][ni], 0, 0, 0);
                acc[2 * q + 1][ni] = __builtin_amdgcn_mfma_f32_16x16x32_bf16(a10, Breg[0][ni], acc[2 * q + 1][ni], 0, 0, 0);
            }
#pragma unroll
            for (int ni = 0; ni < 4; ni++) {
                acc[2 * q][ni]     = __builtin_amdgcn_mfma_f32_16x16x32_bf16(a01, Breg[1][ni], acc[2 * q][ni], 0, 0, 0);
                acc[2 * q + 1][ni] = __builtin_amdgcn_mfma_f32_16x16x32_bf16(a11, Breg[1][ni], acc[2 * q + 1][ni], 0, 0, 0);
            }
            __builtin_amdgcn_s_setprio(0);
            if (p == 3) {
                if (last) { asm volatile("s_waitcnt vmcnt(0)" ::: "memory"); }
                else      { asm volatile("s_waitcnt vmcnt(4)" ::: "memory"); }
            } else if (p == 7 && !last) {
                asm volatile("s_waitcnt vmcnt(4)" ::: "memory");
            }
            __builtin_amdgcn_sched_barrier(0);
            __builtin_amdgcn_s_barrier();
        }
    }

    float* outf = (float*)outp;
    __bf16* outb = (__bf16*)outp;
#pragma unroll
    for (int mi = 0; mi < 8; mi++)
#pragma unroll
        for (int ni = 0; ni < 4; ni++) {
            long gmb = m0 + wm * 128 + mi * 16 + l4 * 4;
            long gc  = n0 + wn * 64 + ni * 16 + l15;
#pragma unroll
            for (int i = 0; i < 4; i++) {
                long gm = gmb + i;
                float v = acc[mi][ni][i];
                if (COLB)  v += colBias[gc];
                if (GELUF) v = 0.5f * v * (1.f + erff(v * 0.70710678118f));
                if (RES)   v += res[gm * (long)ldres + gc];
                if (OUT == 0) outf[gm * (long)ldc + gc] = v;
                else          outb[gm * (long)ldc + gc] = (__bf16)v;
            }
        }
}

// ---------------- GEMM (R7: proven structure + 8x8 patch swizzle) ----------------
template<bool ROWB, bool COLB, bool GELUF, bool RES, int OUT>
__global__ __launch_bounds__(256, 2) void gemm_bf16(
    const __bf16* __restrict__ A, int lda, long aBS,
    const __bf16* __restrict__ Bt, int ldb, long bBS,
    void* __restrict__ outp, int ldc, long cBS,
    const float* __restrict__ rowBias,
    const float* __restrict__ colBias,
    const float* __restrict__ res, int ldres,
    int K)
{
    __shared__ __bf16 Asm[128 * 64];
    __shared__ __bf16 Bsm[128 * 64];
    const int tid = threadIdx.x;
    const int lane = tid & 63, wave = tid >> 6;
    const int wm = wave >> 1, wn = wave & 1;
    const int l15 = lane & 15, l4 = lane >> 4;

    int bx = blockIdx.x, by = blockIdx.y;
    {
        int gx = gridDim.x, gy = gridDim.y;
        int nb = gx * gy;
        if ((gx & 7) == 0 && (gy & 7) == 0 && (nb & 511) == 0) {
            int id = by * gx + bx;
            int xcd = id & 7, local = id >> 3;
            int t = local >> 6, within = local & 63;
            int ppx = gx >> 3;
            int ppc = nb >> 9;
            int pid = xcd * ppc + t;
            int pgy = pid / ppx, pgx = pid % ppx;
            bx = pgx * 8 + (within & 7);
            by = pgy * 8 + (within >> 3);
        } else if ((nb & 7) == 0) {
            int id = by * gx + bx;
            int cpx = nb >> 3;
            int swz = (id & 7) * cpx + (id >> 3);
            bx = swz % gx;
            by = swz / gx;
        }
    }
    const long m0 = (long)bx * 128, n0 = (long)by * 128;
    A  += (long)blockIdx.z * aBS;
    Bt += (long)blockIdx.z * bBS;

    const int srow8 = lane >> 3;
    const int gunit = ((lane & 7) ^ srow8) << 3;
    const __bf16* Abase = A  + (m0 + wave * 8 + srow8) * (long)lda + gunit;
    const __bf16* Bbase = Bt + (n0 + wave * 8 + srow8) * (long)ldb + gunit;
    __bf16* AsmW = Asm + wave * 8 * 64;
    __bf16* BsmW = Bsm + wave * 8 * 64;
    const int swz_r = l15 & 7;

    f32x4 acc[4][4];
#pragma unroll
    for (int mi = 0; mi < 4; mi++)
#pragma unroll
        for (int ni = 0; ni < 4; ni++) acc[mi][ni] = (f32x4){0.f, 0.f, 0.f, 0.f};

    for (int k0 = 0; k0 < K; k0 += 64) {
        __syncthreads();
#pragma unroll
        for (int p = 0; p < 4; p++) {
            __builtin_amdgcn_global_load_lds(
                (const __attribute__((address_space(1))) unsigned int*)(Abase + (long)p * 32 * lda + k0),
                (__attribute__((address_space(3))) unsigned int*)(AsmW + p * 32 * 64), 16, 0, 0);
            __builtin_amdgcn_global_load_lds(
                (const __attribute__((address_space(1))) unsigned int*)(Bbase + (long)p * 32 * ldb + k0),
                (__attribute__((address_space(3))) unsigned int*)(BsmW + p * 32 * 64), 16, 0, 0);
        }
        asm volatile("s_waitcnt vmcnt(0)" ::: "memory");
        __syncthreads();
#pragma unroll
        for (int ks = 0; ks < 2; ks++) {
            bf16x8 af[4], bfv[4];
#pragma unroll
            for (int mi = 0; mi < 4; mi++)
                af[mi] = *(const bf16x8*)(Asm + (wm * 64 + mi * 16 + l15) * 64 + (((ks * 4 + l4) ^ swz_r) << 3));
#pragma unroll
            for (int ni = 0; ni < 4; ni++)
                bfv[ni] = *(const bf16x8*)(Bsm + (wn * 64 + ni * 16 + l15) * 64 + (((ks * 4 + l4) ^ swz_r) << 3));
#pragma unroll
            for (int mi = 0; mi < 4; mi++)
#pragma unroll
                for (int ni = 0; ni < 4; ni++)
                    acc[mi][ni] = __builtin_amdgcn_mfma_f32_16x16x32_bf16(af[mi], bfv[ni], acc[mi][ni], 0, 0, 0);
        }
    }

    float* outf = (float*)outp;
    __bf16* outb = (__bf16*)outp;
    const long cOff = (long)blockIdx.z * cBS;
#pragma unroll
    for (int mi = 0; mi < 4; mi++)
#pragma unroll
        for (int ni = 0; ni < 4; ni++) {
            long gmb = m0 + wm * 64 + mi * 16 + l4 * 4;
            long gc  = n0 + wn * 64 + ni * 16 + l15;
#pragma unroll
            for (int i = 0; i < 4; i++) {
                long gm = gmb + i;
                float v = acc[mi][ni][i];
                if (ROWB)  v += rowBias[gm];
                if (COLB)  v += colBias[gc];
                if (GELUF) v = 0.5f * v * (1.f + erff(v * 0.70710678118f));
                if (RES)   v += res[gm * (long)ldres + gc];
                if (OUT == 0)      outf[cOff + gm * (long)ldc + gc] = v;
                else if (OUT == 1) outb[cOff + gm * (long)ldc + gc] = (__bf16)v;
                else               outb[cOff + gc * (long)ldc + gm] = (__bf16)v;
            }
        }
}

// ========== gemm128_split: 128x128 tile split-K, writes f32 partials ==========
__global__ __launch_bounds__(256, 2) void gemm128_split(
    const __bf16* __restrict__ A, int lda, long aBS,
    const __bf16* __restrict__ Bt, int ldb, long bBS,
    float* __restrict__ P, long cBS, int ldc,
    int Ksplit, int S)
{
    __shared__ __bf16 Asm[128 * 64];
    __shared__ __bf16 Bsm[128 * 64];
    const int tid = threadIdx.x;
    const int lane = tid & 63, wave = tid >> 6;
    const int wm = wave >> 1, wn = wave & 1;
    const int l15 = lane & 15, l4 = lane >> 4;
    const long m0 = (long)blockIdx.x * 128, n0 = (long)blockIdx.y * 128;
    const long zb = blockIdx.z / S;
    const int  sp = blockIdx.z % S;
    A  += zb * aBS + (long)sp * Ksplit;
    Bt += zb * bBS + (long)sp * Ksplit;

    const int srow8 = lane >> 3;
    const int gunit = ((lane & 7) ^ srow8) << 3;
    const __bf16* Abase = A + (m0 + wave * 8 + srow8) * (long)lda + gunit;
    const __bf16* Bbase = Bt + (n0 + wave * 8 + srow8) * (long)ldb + gunit;
    __bf16* AsmW = Asm + wave * 8 * 64;
    __bf16* BsmW = Bsm + wave * 8 * 64;
    const int swz_r = l15 & 7;

    f32x4 acc[4][4];
#pragma unroll
    for (int mi = 0; mi < 4; mi++)
#pragma unroll
        for (int ni = 0; ni < 4; ni++) acc[mi][ni] = (f32x4){0.f, 0.f, 0.f, 0.f};

    for (int k0 = 0; k0 < Ksplit; k0 += 64) {
        __syncthreads();
#pragma unroll
        for (int p = 0; p < 4; p++) {
            __builtin_amdgcn_global_load_lds(
                (const __attribute__((address_space(1))) unsigned int*)(Abase + (long)p * 32 * lda + k0),
                (__attribute__((address_space(3))) unsigned int*)(AsmW + p * 32 * 64), 16, 0, 0);
            __builtin_amdgcn_global_load_lds(
                (const __attribute__((address_space(1))) unsigned int*)(Bbase + (long)p * 32 * ldb + k0),
                (__attribute__((address_space(3))) unsigned int*)(BsmW + p * 32 * 64), 16, 0, 0);
        }
        asm volatile("s_waitcnt vmcnt(0)" ::: "memory");
        __syncthreads();
#pragma unroll
        for (int ks = 0; ks < 2; ks++) {
            bf16x8 af[4], bfv[4];
#pragma unroll
            for (int mi = 0; mi < 4; mi++)
                af[mi] = *(const bf16x8*)(Asm + (wm * 64 + mi * 16 + l15) * 64 + (((ks * 4 + l4) ^ swz_r) << 3));
#pragma unroll
            for (int ni = 0; ni < 4; ni++)
                bfv[ni] = *(const bf16x8*)(Bsm + (wn * 64 + ni * 16 + l15) * 64 + (((ks * 4 + l4) ^ swz_r) << 3));
#pragma unroll
            for (int mi = 0; mi < 4; mi++)
#pragma unroll
                for (int ni = 0; ni < 4; ni++)
                    acc[mi][ni] = __builtin_amdgcn_mfma_f32_16x16x32_bf16(af[mi], bfv[ni], acc[mi][ni], 0, 0, 0);
        }
    }

    float* out = P + (long)blockIdx.z * cBS;
#pragma unroll
    for (int mi = 0; mi < 4; mi++)
#pragma unroll
        for (int ni = 0; ni < 4; ni++) {
            long gmb = m0 + wm * 64 + mi * 16 + l4 * 4;
            long gc  = n0 + wn * 64 + ni * 16 + l15;
#pragma unroll
            for (int i = 0; i < 4; i++)
                out[(gmb + i) * (long)ldc + gc] = acc[mi][ni][i];
        }
}

// ---------- reduce S f32 partials -> bf16 (+row bias, optional transposed write) ----------
template<bool BIAS, bool TRANS>
__global__ __launch_bounds__(256) void reduce_partials(
    const float* __restrict__ P, __bf16* __restrict__ out,
    const float* __restrict__ bias, int S, int M, int N, long pBS)
{
    int b = blockIdx.z;
    long idx = ((long)blockIdx.x * 256 + threadIdx.x) * 4;
    if (idx >= (long)M * N) return;
    const float* Pb = P + (long)b * S * pBS + idx;
    float4 a = *(const float4*)Pb;
    for (int s = 1; s < S; s++) {
        float4 v = *(const float4*)(Pb + (long)s * pBS);
        a.x += v.x; a.y += v.y; a.z += v.z; a.w += v.w;
    }
    int m = (int)(idx / N), n = (int)(idx % N);
    if (BIAS) { float bv = bias[m]; a.x += bv; a.y += bv; a.z += bv; a.w += bv; }
    float av[4] = {a.x, a.y, a.z, a.w};
    if (!TRANS) {
        __bf16* o = out + (long)b * M * N + idx;
        o[0] = (__bf16)av[0]; o[1] = (__bf16)av[1]; o[2] = (__bf16)av[2]; o[3] = (__bf16)av[3];
    } else {
#pragma unroll
        for (int j = 0; j < 4; j++)
            out[(long)b * M * N + (long)(n + j) * M + m] = (__bf16)av[j];
    }
}

// ---------------- fused Linformer attention ----------------
__global__ __launch_bounds__(256, 2) void attn_fused(
    const __bf16* __restrict__ Q, const __bf16* __restrict__ KP,
    const __bf16* __restrict__ VPt, __bf16* __restrict__ O)
{
    __shared__ __bf16 plds[4][4096];
    const int tid = threadIdx.x, lane = tid & 63, wave = tid >> 6;
    const int l15 = lane & 15, l4 = lane >> 4;
    const int h = blockIdx.y, b = blockIdx.z;
    const long row0 = (long)b * 4096 + (long)blockIdx.x * 64 + wave * 16;

    bf16x8 aq[2];
#pragma unroll
    for (int ks = 0; ks < 2; ks++)
        aq[ks] = *(const bf16x8*)(Q + (row0 + l15) * 1024 + h * 64 + ks * 32 + l4 * 8);

    f32x4 s[16];
#pragma unroll
    for (int f = 0; f < 16; f++) {
        f32x4 a = (f32x4){0.f, 0.f, 0.f, 0.f};
#pragma unroll
        for (int ks = 0; ks < 2; ks++) {
            bf16x8 bk = *(const bf16x8*)(KP + ((long)b * 256 + f * 16 + l15) * 1024 + h * 64 + ks * 32 + l4 * 8);
            a = __builtin_amdgcn_mfma_f32_16x16x32_bf16(aq[ks], bk, a, 0, 0, 0);
        }
        s[f] = a;
    }

    const float scale = 0.125f;
#pragma unroll
    for (int i = 0; i < 4; i++) {
        float m_ = -3.4e38f;
#pragma unroll
        for (int f = 0; f < 16; f++) { float v = s[f][i] * scale; s[f][i] = v; m_ = fmaxf(m_, v); }
#pragma unroll
        for (int msk = 1; msk < 16; msk <<= 1) m_ = fmaxf(m_, __shfl_xor(m_, msk));
        float su = 0.f;
#pragma unroll
        for (int f = 0; f < 16; f++) { float e = expf(s[f][i] - m_); s[f][i] = e; su += e; }
#pragma unroll
        for (int msk = 1; msk < 16; msk <<= 1) su += __shfl_xor(su, msk);
        float inv = 1.f / su;
#pragma unroll
        for (int f = 0; f < 16; f++) s[f][i] *= inv;
    }

    __bf16* pl = plds[wave];
#pragma unroll
    for (int f = 0; f < 16; f++)
#pragma unroll
        for (int i = 0; i < 4; i++) {
            int r = l4 * 4 + i, c = f * 16 + l15;
            int off = r * 256 + ((((c >> 3) ^ (r & 7)) << 3) | (c & 7));
            pl[off] = (__bf16)s[f][i];
        }

    f32x4 o[4];
#pragma unroll
    for (int f2 = 0; f2 < 4; f2++) o[f2] = (f32x4){0.f, 0.f, 0.f, 0.f};
#pragma unroll
    for (int ks = 0; ks < 8; ks++) {
        int kk = ks * 32 + l4 * 8;
        int off = l15 * 256 + (((kk >> 3) ^ (l15 & 7)) << 3);
        bf16x8 ap = *(const bf16x8*)(pl + off);
#pragma unroll
        for (int f2 = 0; f2 < 4; f2++) {
            bf16x8 bv = *(const bf16x8*)(VPt + ((long)b * 1024 + h * 64 + f2 * 16 + l15) * 256 + kk);
            o[f2] = __builtin_amdgcn_mfma_f32_16x16x32_bf16(ap, bv, o[f2], 0, 0, 0);
        }
    }
#pragma unroll
    for (int f2 = 0; f2 < 4; f2++)
#pragma unroll
        for (int i = 0; i < 4; i++)
            O[(row0 + l4 * 4 + i) * 1024 + h * 64 + f2 * 16 + l15] = (__bf16)o[f2][i];
}

// ---------------- LayerNorm (row=1024), writes f32 + bf16 ----------------
__global__ __launch_bounds__(256) void ln_kernel(const float* __restrict__ y,
    const float* __restrict__ g, const float* __restrict__ b,
    float* __restrict__ xout, __bf16* __restrict__ xb)
{
    const int row = blockIdx.x;
    const int t = threadIdx.x;
    const float4 v = ((const float4*)(y + (long)row * 1024))[t];
    float s  = v.x + v.y + v.z + v.w;
    float ss = v.x * v.x + v.y * v.y + v.z * v.z + v.w * v.w;
#pragma unroll
    for (int m = 1; m < 64; m <<= 1) { s += __shfl_xor(s, m); ss += __shfl_xor(ss, m); }
    __shared__ float red[2][4];
    const int wave = t >> 6, lane = t & 63;
    if (lane == 0) { red[0][wave] = s; red[1][wave] = ss; }
    __syncthreads();
    s  = red[0][0] + red[0][1] + red[0][2] + red[0][3];
    ss = red[1][0] + red[1][1] + red[1][2] + red[1][3];
    const float mu = s * (1.f / 1024.f);
    const float var = ss * (1.f / 1024.f) - mu * mu;
    const float rs = rsqrtf(var + 1e-5f);
    const float4 gv = ((const float4*)g)[t];
    const float4 bv = ((const float4*)b)[t];
    float o0 = (v.x - mu) * rs * gv.x + bv.x;
    float o1 = (v.y - mu) * rs * gv.y + bv.y;
    float o2 = (v.z - mu) * rs * gv.z + bv.z;
    float o3 = (v.w - mu) * rs * gv.w + bv.w;
    float4 ov; ov.x = o0; ov.y = o1; ov.z = o2; ov.w = o3;
    ((float4*)(xout + (long)row * 1024))[t] = ov;
    __bf16* xr = xb + (long)row * 1024 + t * 4;
    xr[0] = (__bf16)o0; xr[1] = (__bf16)o1; xr[2] = (__bf16)o2; xr[3] = (__bf16)o3;
}

// ---------------- host launch ----------------
extern "C" void kernel_launch(void* const* d_in, const int* in_sizes, int n_in,
                              void* d_out, int out_size, void* d_ws, size_t ws_size,
                              hipStream_t stream) {
    const float* x   = (const float*)d_in[0];
    const float* Wq  = (const float*)d_in[1];
    const float* Wk  = (const float*)d_in[2];
    const float* Wv  = (const float*)d_in[3];
    const float* Wo  = (const float*)d_in[4];
    const float* bo  = (const float*)d_in[5];
    const float* Ew  = (const float*)d_in[6];
    const float* Eb  = (const float*)d_in[7];
    const float* W1  = (const float*)d_in[8];
    const float* b1  = (const float*)d_in[9];
    const float* W2  = (const float*)d_in[10];
    const float* b2  = (const float*)d_in[11];
    const float* lng = (const float*)d_in[12];
    const float* lnb = (const float*)d_in[13];
    float* xout = (float*)d_out;

    char* base = (char*)d_ws;
    size_t off = 0;
    auto alloc = [&](size_t bytes) { void* p = base + off; off += (bytes + 255) & ~(size_t)255; return p; };
    __bf16* Wqt = (__bf16*)alloc(2ll * 1024 * 1024 * 2);
    __bf16* Wkt = (__bf16*)alloc(2ll * 1024 * 1024 * 2);
    __bf16* Wvt = (__bf16*)alloc(2ll * 1024 * 1024 * 2);
    __bf16* Wot = (__bf16*)alloc(2ll * 1024 * 1024 * 2);
    __bf16* W1t = (__bf16*)alloc(2ll * 1024 * 4096 * 2);
    __bf16* W2t = (__bf16*)alloc(2ll * 1024 * 4096 * 2);
    __bf16* Ewb = (__bf16*)alloc(256ll * 4096 * 2);
    __bf16* xb  = (__bf16*)alloc(8192ll * 1024 * 2);
    __bf16* xbT = (__bf16*)alloc(2ll * 1024 * 4096 * 2);
    float*  y   = (float*) alloc(8192ll * 1024 * 4);
    __bf16* xp  = (__bf16*)alloc(2ll * 256 * 1024 * 2);
    __bf16* KPb = (__bf16*)alloc(2ll * 256 * 1024 * 2);
    __bf16* VPt = (__bf16*)alloc(2ll * 1024 * 256 * 2);
    __bf16* big = (__bf16*)alloc(8192ll * 4096 * 2);   // 64 MB scratch region
    float*  xpP = (float*)big;                          // [16][256*1024] f32 = 16MB
    float*  kpP = (float*)((char*)big + (16ll << 20));  // [8][256*1024]  f32 =  8MB
    float*  vpP = (float*)((char*)big + (24ll << 20));  // [8][256*1024]  f32 =  8MB
    __bf16* Qb  = big;                                  // [8192][1024] (over xpP, dead)
    __bf16* Ob  = big + (16ll << 20);                   // [8192][1024] (over kpP/vpP, dead)
    __bf16* hbuf = big;                                 // [8192][4096] (FF stage)

    cvt_f32_bf16<<<2048, 256, 0, stream>>>(x, xb, 8388608);
    cvt_f32_bf16<<<1024, 256, 0, stream>>>(Ew, Ewb, 1048576);
    transpose_cvt<<<dim3(2, 32, 32),  dim3(32, 8), 0, stream>>>(Wq, Wqt, 64, 1024, 65536, 65536);
    transpose_cvt<<<dim3(2, 32, 32),  dim3(32, 8), 0, stream>>>(Wk, Wkt, 64, 1024, 65536, 65536);
    transpose_cvt<<<dim3(2, 32, 32),  dim3(32, 8), 0, stream>>>(Wv, Wvt, 64, 1024, 65536, 65536);
    transpose_cvt<<<dim3(32, 32, 2),  dim3(32, 8), 0, stream>>>(Wo, Wot, 1024, 1024, 1048576, 1048576);
    transpose_cvt<<<dim3(128, 32, 2), dim3(32, 8), 0, stream>>>(W1, W1t, 4096, 1024, 4194304, 4194304);
    transpose_cvt<<<dim3(32, 128, 2), dim3(32, 8), 0, stream>>>(W2, W2t, 1024, 4096, 4194304, 4194304);

    for (int l = 0; l < 2; l++) {
        const __bf16* Wqt_l = Wqt + (long)l * 1048576;
        const __bf16* Wkt_l = Wkt + (long)l * 1048576;
        const __bf16* Wvt_l = Wvt + (long)l * 1048576;
        const __bf16* Wot_l = Wot + (long)l * 1048576;
        const __bf16* W1t_l = W1t + (long)l * 4194304;
        const __bf16* W2t_l = W2t + (long)l * 4194304;
        const float* res = (l == 0) ? x : xout;

        // xbT[b] = xb[b]^T
        transpose_bf16<<<dim3(32, 128, 2), dim3(32, 8), 0, stream>>>(xb, xbT, 4096, 1024);
        // xp = Ew @ x  (split-K 8)
        gemm128_split<<<dim3(2, 8, 16), 256, 0, stream>>>(
            Ewb, 4096, 0, xbT, 4096, 4194304, xpP, 262144, 1024, 512, 8);
        reduce_partials<false, false><<<dim3(256, 1, 2), 256, 0, stream>>>(
            xpP, xp, nullptr, 8, 256, 1024, 262144);
        // KP = xp @ Wk^T + Eb  (split-K 4)
        gemm128_split<<<dim3(2, 8, 8), 256, 0, stream>>>(
            xp, 1024, 262144, Wkt_l, 1024, 0, kpP, 262144, 1024, 256, 4);
        reduce_partials<true, false><<<dim3(256, 1, 2), 256, 0, stream>>>(
            kpP, KPb, Eb, 4, 256, 1024, 262144);
        // VPt = (xp @ Wv^T + Eb)^T
        gemm128_split<<<dim3(2, 8, 8), 256, 0, stream>>>(
            xp, 1024, 262144, Wvt_l, 1024, 0, vpP, 262144, 1024, 256, 4);
        reduce_partials<true, true><<<dim3(256, 1, 2), 256, 0, stream>>>(
            vpP, VPt, Eb, 4, 256, 1024, 262144);
        // Q = xb @ Wq^T
        gemm_bf16<false, false, false, false, 1><<<dim3(64, 8, 1), 256, 0, stream>>>(
            xb, 1024, 0, Wqt_l, 1024, 0, (void*)Qb, 1024, 0, nullptr, nullptr, nullptr, 0, 1024);
        // attention
        attn_fused<<<dim3(64, 16, 2), 256, 0, stream>>>(Qb, KPb, VPt, Ob);
        // attn_out = O @ Wo^T + bo + residual
        gemm_bf16<false, true, false, true, 0><<<dim3(64, 8, 1), 256, 0, stream>>>(
            Ob, 1024, 0, Wot_l, 1024, 0, (void*)y, 1024, 0,
            nullptr, bo + l * 1024, res, 1024, 1024);
        ln_kernel<<<8192, 256, 0, stream>>>(y, lng + (2 * l + 0) * 1024, lnb + (2 * l + 0) * 1024, xout, xb);
        // h = gelu(x @ W1 + b1)  -- 8-phase 256^2, grid 32x16, 4x4 patch swizzle
        gemm8p<true, true, false, 1><<<dim3(32, 16), 512, 0, stream>>>(
            xb, 1024, W1t_l, 1024, (void*)hbuf, 4096, b1 + l * 4096, nullptr, 0, 1024);
        // ff = h @ W2 + b2 + residual  (R7 kernel)
        gemm_bf16<false, true, false, true, 0><<<dim3(64, 8, 1), 256, 0, stream>>>(
            hbuf, 4096, 0, W2t_l, 4096, 0, (void*)y, 1024, 0,
            nullptr, b2 + l * 1024, xout, 1024, 4096);
        ln_kernel<<<8192, 256, 0, stream>>>(y, lng + (2 * l + 1) * 1024, lnb + (2 * l + 1) * 1024, xout, xb);
    }
}

// Round 9
// 808.414 us; speedup vs baseline: 1.7967x; 1.0017x over previous
//
#include <hip/hip_runtime.h>
#include <hip/hip_bf16.h>
#include <math.h>

// ---------------- types ----------------
typedef __bf16 bf16x8 __attribute__((ext_vector_type(8)));
typedef __bf16 bf16x4 __attribute__((ext_vector_type(4)));
typedef float f32x4 __attribute__((ext_vector_type(4)));

// ---------------- conversion kernels ----------------
__global__ void cvt_f32_bf16(const float* __restrict__ in, __bf16* __restrict__ out, long n) {
    long i = ((long)blockIdx.x * 256 + threadIdx.x) * 4;
    long stride = (long)gridDim.x * 1024;
    for (; i < n; i += stride) {
        float4 v = *(const float4*)(in + i);
        out[i + 0] = (__bf16)v.x;
        out[i + 1] = (__bf16)v.y;
        out[i + 2] = (__bf16)v.z;
        out[i + 3] = (__bf16)v.w;
    }
}

// transpose + convert: in f32 [M][N] (ldin) -> out bf16 [N][M] (ldout), batched over z
__global__ void transpose_cvt(const float* __restrict__ in, __bf16* __restrict__ out,
                              int ldin, int ldout, long inBS, long outBS) {
    __shared__ __bf16 tile[32][33];
    in  += (long)blockIdx.z * inBS;
    out += (long)blockIdx.z * outBS;
    int n0 = blockIdx.x * 32, m0 = blockIdx.y * 32;
    for (int i = threadIdx.y; i < 32; i += 8)
        tile[i][threadIdx.x] = (__bf16)in[(long)(m0 + i) * ldin + n0 + threadIdx.x];
    __syncthreads();
    for (int i = threadIdx.y; i < 32; i += 8)
        out[(long)(n0 + i) * ldout + m0 + threadIdx.x] = tile[threadIdx.x][i];
}

// bf16 transpose: in [rows][cols] -> out [cols][rows], batched over z
__global__ void transpose_bf16(const __bf16* __restrict__ in, __bf16* __restrict__ out,
                               int rows, int cols) {
    __shared__ __bf16 tile[32][33];
    in  += (long)blockIdx.z * rows * cols;
    out += (long)blockIdx.z * rows * cols;
    int c0 = blockIdx.x * 32, r0 = blockIdx.y * 32;
    for (int i = threadIdx.y; i < 32; i += 8)
        tile[i][threadIdx.x] = in[(long)(r0 + i) * cols + c0 + threadIdx.x];
    __syncthreads();
    for (int i = threadIdx.y; i < 32; i += 8)
        out[(long)(c0 + i) * rows + r0 + threadIdx.x] = tile[threadIdx.x][i];
}

// ---------------- GEMM (proven structure + 8x8 patch swizzle) ----------------
// C[M,N] = A[M,K] @ Bt[N,K]^T (+epilogue). 128^2 tile, BK=64, 4 waves.
// OUT: 0 = f32 normal, 1 = bf16 normal, 2 = bf16 transposed
template<bool ROWB, bool COLB, bool GELUF, bool RES, int OUT>
__global__ __launch_bounds__(256, 2) void gemm_bf16(
    const __bf16* __restrict__ A, int lda, long aBS,
    const __bf16* __restrict__ Bt, int ldb, long bBS,
    void* __restrict__ outp, int ldc, long cBS,
    const float* __restrict__ rowBias,
    const float* __restrict__ colBias,
    const float* __restrict__ res, int ldres,
    int K)
{
    __shared__ __bf16 Asm[128 * 64];
    __shared__ __bf16 Bsm[128 * 64];
    const int tid = threadIdx.x;
    const int lane = tid & 63, wave = tid >> 6;
    const int wm = wave >> 1, wn = wave & 1;
    const int l15 = lane & 15, l4 = lane >> 4;

    // 8x8 patch per XCD (L2-resident panels); fallback 1D swizzle
    int bx = blockIdx.x, by = blockIdx.y;
    {
        int gx = gridDim.x, gy = gridDim.y;
        int nb = gx * gy;
        if ((gx & 7) == 0 && (gy & 7) == 0 && (nb & 511) == 0) {
            int id = by * gx + bx;
            int xcd = id & 7, local = id >> 3;
            int t = local >> 6, within = local & 63;
            int ppx = gx >> 3;
            int ppc = nb >> 9;
            int pid = xcd * ppc + t;
            int pgy = pid / ppx, pgx = pid % ppx;
            bx = pgx * 8 + (within & 7);
            by = pgy * 8 + (within >> 3);
        } else if ((nb & 7) == 0) {
            int id = by * gx + bx;
            int cpx = nb >> 3;
            int swz = (id & 7) * cpx + (id >> 3);
            bx = swz % gx;
            by = swz / gx;
        }
    }
    const long m0 = (long)bx * 128, n0 = (long)by * 128;
    A  += (long)blockIdx.z * aBS;
    Bt += (long)blockIdx.z * bBS;

    const int srow8 = lane >> 3;
    const int gunit = ((lane & 7) ^ srow8) << 3;
    const __bf16* Abase = A  + (m0 + wave * 8 + srow8) * (long)lda + gunit;
    const __bf16* Bbase = Bt + (n0 + wave * 8 + srow8) * (long)ldb + gunit;
    __bf16* AsmW = Asm + wave * 8 * 64;
    __bf16* BsmW = Bsm + wave * 8 * 64;
    const int swz_r = l15 & 7;

    f32x4 acc[4][4];
#pragma unroll
    for (int mi = 0; mi < 4; mi++)
#pragma unroll
        for (int ni = 0; ni < 4; ni++) acc[mi][ni] = (f32x4){0.f, 0.f, 0.f, 0.f};

    for (int k0 = 0; k0 < K; k0 += 64) {
        __syncthreads();
#pragma unroll
        for (int p = 0; p < 4; p++) {
            __builtin_amdgcn_global_load_lds(
                (const __attribute__((address_space(1))) unsigned int*)(Abase + (long)p * 32 * lda + k0),
                (__attribute__((address_space(3))) unsigned int*)(AsmW + p * 32 * 64), 16, 0, 0);
            __builtin_amdgcn_global_load_lds(
                (const __attribute__((address_space(1))) unsigned int*)(Bbase + (long)p * 32 * ldb + k0),
                (__attribute__((address_space(3))) unsigned int*)(BsmW + p * 32 * 64), 16, 0, 0);
        }
        asm volatile("s_waitcnt vmcnt(0)" ::: "memory");
        __syncthreads();
#pragma unroll
        for (int ks = 0; ks < 2; ks++) {
            bf16x8 af[4], bfv[4];
#pragma unroll
            for (int mi = 0; mi < 4; mi++)
                af[mi] = *(const bf16x8*)(Asm + (wm * 64 + mi * 16 + l15) * 64 + (((ks * 4 + l4) ^ swz_r) << 3));
#pragma unroll
            for (int ni = 0; ni < 4; ni++)
                bfv[ni] = *(const bf16x8*)(Bsm + (wn * 64 + ni * 16 + l15) * 64 + (((ks * 4 + l4) ^ swz_r) << 3));
#pragma unroll
            for (int mi = 0; mi < 4; mi++)
#pragma unroll
                for (int ni = 0; ni < 4; ni++)
                    acc[mi][ni] = __builtin_amdgcn_mfma_f32_16x16x32_bf16(af[mi], bfv[ni], acc[mi][ni], 0, 0, 0);
        }
    }

    float* outf = (float*)outp;
    __bf16* outb = (__bf16*)outp;
    const long cOff = (long)blockIdx.z * cBS;
#pragma unroll
    for (int mi = 0; mi < 4; mi++)
#pragma unroll
        for (int ni = 0; ni < 4; ni++) {
            long gmb = m0 + wm * 64 + mi * 16 + l4 * 4;
            long gc  = n0 + wn * 64 + ni * 16 + l15;
#pragma unroll
            for (int i = 0; i < 4; i++) {
                long gm = gmb + i;
                float v = acc[mi][ni][i];
                if (ROWB)  v += rowBias[gm];
                if (COLB)  v += colBias[gc];
                if (GELUF) v = 0.5f * v * (1.f + erff(v * 0.70710678118f));
                if (RES)   v += res[gm * (long)ldres + gc];
                if (OUT == 0)      outf[cOff + gm * (long)ldc + gc] = v;
                else if (OUT == 1) outb[cOff + gm * (long)ldc + gc] = (__bf16)v;
                else               outb[cOff + gc * (long)ldc + gm] = (__bf16)v;
            }
        }
}

// ========== gemm128_split: 128x128 tile split-K, writes f32 partials ==========
__global__ __launch_bounds__(256, 2) void gemm128_split(
    const __bf16* __restrict__ A, int lda, long aBS,
    const __bf16* __restrict__ Bt, int ldb, long bBS,
    float* __restrict__ P, long cBS, int ldc,
    int Ksplit, int S)
{
    __shared__ __bf16 Asm[128 * 64];
    __shared__ __bf16 Bsm[128 * 64];
    const int tid = threadIdx.x;
    const int lane = tid & 63, wave = tid >> 6;
    const int wm = wave >> 1, wn = wave & 1;
    const int l15 = lane & 15, l4 = lane >> 4;
    const long m0 = (long)blockIdx.x * 128, n0 = (long)blockIdx.y * 128;
    const long zb = blockIdx.z / S;
    const int  sp = blockIdx.z % S;
    A  += zb * aBS + (long)sp * Ksplit;
    Bt += zb * bBS + (long)sp * Ksplit;

    const int srow8 = lane >> 3;
    const int gunit = ((lane & 7) ^ srow8) << 3;
    const __bf16* Abase = A + (m0 + wave * 8 + srow8) * (long)lda + gunit;
    const __bf16* Bbase = Bt + (n0 + wave * 8 + srow8) * (long)ldb + gunit;
    __bf16* AsmW = Asm + wave * 8 * 64;
    __bf16* BsmW = Bsm + wave * 8 * 64;
    const int swz_r = l15 & 7;

    f32x4 acc[4][4];
#pragma unroll
    for (int mi = 0; mi < 4; mi++)
#pragma unroll
        for (int ni = 0; ni < 4; ni++) acc[mi][ni] = (f32x4){0.f, 0.f, 0.f, 0.f};

    for (int k0 = 0; k0 < Ksplit; k0 += 64) {
        __syncthreads();
#pragma unroll
        for (int p = 0; p < 4; p++) {
            __builtin_amdgcn_global_load_lds(
                (const __attribute__((address_space(1))) unsigned int*)(Abase + (long)p * 32 * lda + k0),
                (__attribute__((address_space(3))) unsigned int*)(AsmW + p * 32 * 64), 16, 0, 0);
            __builtin_amdgcn_global_load_lds(
                (const __attribute__((address_space(1))) unsigned int*)(Bbase + (long)p * 32 * ldb + k0),
                (__attribute__((address_space(3))) unsigned int*)(BsmW + p * 32 * 64), 16, 0, 0);
        }
        asm volatile("s_waitcnt vmcnt(0)" ::: "memory");
        __syncthreads();
#pragma unroll
        for (int ks = 0; ks < 2; ks++) {
            bf16x8 af[4], bfv[4];
#pragma unroll
            for (int mi = 0; mi < 4; mi++)
                af[mi] = *(const bf16x8*)(Asm + (wm * 64 + mi * 16 + l15) * 64 + (((ks * 4 + l4) ^ swz_r) << 3));
#pragma unroll
            for (int ni = 0; ni < 4; ni++)
                bfv[ni] = *(const bf16x8*)(Bsm + (wn * 64 + ni * 16 + l15) * 64 + (((ks * 4 + l4) ^ swz_r) << 3));
#pragma unroll
            for (int mi = 0; mi < 4; mi++)
#pragma unroll
                for (int ni = 0; ni < 4; ni++)
                    acc[mi][ni] = __builtin_amdgcn_mfma_f32_16x16x32_bf16(af[mi], bfv[ni], acc[mi][ni], 0, 0, 0);
        }
    }

    float* out = P + (long)blockIdx.z * cBS;
#pragma unroll
    for (int mi = 0; mi < 4; mi++)
#pragma unroll
        for (int ni = 0; ni < 4; ni++) {
            long gmb = m0 + wm * 64 + mi * 16 + l4 * 4;
            long gc  = n0 + wn * 64 + ni * 16 + l15;
#pragma unroll
            for (int i = 0; i < 4; i++)
                out[(gmb + i) * (long)ldc + gc] = acc[mi][ni][i];
        }
}

// ---------- reduce S f32 partials -> bf16 (xp path) ----------
__global__ __launch_bounds__(256) void reduce_partials(
    const float* __restrict__ P, __bf16* __restrict__ out, int S, long total, long pBS)
{
    int b = blockIdx.z;
    long idx = ((long)blockIdx.x * 256 + threadIdx.x) * 4;
    if (idx >= total) return;
    const float* Pb = P + (long)b * S * pBS + idx;
    float4 a = *(const float4*)Pb;
    for (int s = 1; s < S; s++) {
        float4 v = *(const float4*)(Pb + (long)s * pBS);
        a.x += v.x; a.y += v.y; a.z += v.z; a.w += v.w;
    }
    __bf16* o = out + (long)b * total + idx;
    o[0] = (__bf16)a.x; o[1] = (__bf16)a.y; o[2] = (__bf16)a.z; o[3] = (__bf16)a.w;
}

// ---------- merged KV reduce: partials [S][256][2048] -> KP bf16 + VPt bf16 ----------
__global__ __launch_bounds__(256) void reduce_kv(
    const float* __restrict__ P, __bf16* __restrict__ KP, __bf16* __restrict__ VPt,
    const float* __restrict__ Eb, int S)
{
    int b = blockIdx.z;
    long idx = ((long)blockIdx.x * 256 + threadIdx.x) * 4;   // over 256*2048
    const float* Pb = P + (long)b * S * 524288 + idx;
    float4 a = *(const float4*)Pb;
    for (int s = 1; s < S; s++) {
        float4 v = *(const float4*)(Pb + (long)s * 524288);
        a.x += v.x; a.y += v.y; a.z += v.z; a.w += v.w;
    }
    int m = (int)(idx >> 11), n = (int)(idx & 2047);
    float bv = Eb[m];
    float av[4] = {a.x + bv, a.y + bv, a.z + bv, a.w + bv};
    if (n < 1024) {
        __bf16* o = KP + (long)b * 262144 + (long)m * 1024 + n;
        o[0] = (__bf16)av[0]; o[1] = (__bf16)av[1]; o[2] = (__bf16)av[2]; o[3] = (__bf16)av[3];
    } else {
        int c = n - 1024;
#pragma unroll
        for (int j = 0; j < 4; j++)
            VPt[(long)b * 262144 + (long)(c + j) * 256 + m] = (__bf16)av[j];
    }
}

// ---------------- fused Linformer attention ----------------
__global__ __launch_bounds__(256, 2) void attn_fused(
    const __bf16* __restrict__ Q, const __bf16* __restrict__ KP,
    const __bf16* __restrict__ VPt, __bf16* __restrict__ O)
{
    __shared__ __bf16 plds[4][4096];
    const int tid = threadIdx.x, lane = tid & 63, wave = tid >> 6;
    const int l15 = lane & 15, l4 = lane >> 4;
    const int h = blockIdx.y, b = blockIdx.z;
    const long row0 = (long)b * 4096 + (long)blockIdx.x * 64 + wave * 16;

    bf16x8 aq[2];
#pragma unroll
    for (int ks = 0; ks < 2; ks++)
        aq[ks] = *(const bf16x8*)(Q + (row0 + l15) * 1024 + h * 64 + ks * 32 + l4 * 8);

    f32x4 s[16];
#pragma unroll
    for (int f = 0; f < 16; f++) {
        f32x4 a = (f32x4){0.f, 0.f, 0.f, 0.f};
#pragma unroll
        for (int ks = 0; ks < 2; ks++) {
            bf16x8 bk = *(const bf16x8*)(KP + ((long)b * 256 + f * 16 + l15) * 1024 + h * 64 + ks * 32 + l4 * 8);
            a = __builtin_amdgcn_mfma_f32_16x16x32_bf16(aq[ks], bk, a, 0, 0, 0);
        }
        s[f] = a;
    }

    const float scale = 0.125f;
#pragma unroll
    for (int i = 0; i < 4; i++) {
        float m_ = -3.4e38f;
#pragma unroll
        for (int f = 0; f < 16; f++) { float v = s[f][i] * scale; s[f][i] = v; m_ = fmaxf(m_, v); }
#pragma unroll
        for (int msk = 1; msk < 16; msk <<= 1) m_ = fmaxf(m_, __shfl_xor(m_, msk));
        float su = 0.f;
#pragma unroll
        for (int f = 0; f < 16; f++) { float e = expf(s[f][i] - m_); s[f][i] = e; su += e; }
#pragma unroll
        for (int msk = 1; msk < 16; msk <<= 1) su += __shfl_xor(su, msk);
        float inv = 1.f / su;
#pragma unroll
        for (int f = 0; f < 16; f++) s[f][i] *= inv;
    }

    __bf16* pl = plds[wave];
#pragma unroll
    for (int f = 0; f < 16; f++)
#pragma unroll
        for (int i = 0; i < 4; i++) {
            int r = l4 * 4 + i, c = f * 16 + l15;
            int off = r * 256 + ((((c >> 3) ^ (r & 7)) << 3) | (c & 7));
            pl[off] = (__bf16)s[f][i];
        }

    f32x4 o[4];
#pragma unroll
    for (int f2 = 0; f2 < 4; f2++) o[f2] = (f32x4){0.f, 0.f, 0.f, 0.f};
#pragma unroll
    for (int ks = 0; ks < 8; ks++) {
        int kk = ks * 32 + l4 * 8;
        int off = l15 * 256 + (((kk >> 3) ^ (l15 & 7)) << 3);
        bf16x8 ap = *(const bf16x8*)(pl + off);
#pragma unroll
        for (int f2 = 0; f2 < 4; f2++) {
            bf16x8 bv = *(const bf16x8*)(VPt + ((long)b * 1024 + h * 64 + f2 * 16 + l15) * 256 + kk);
            o[f2] = __builtin_amdgcn_mfma_f32_16x16x32_bf16(ap, bv, o[f2], 0, 0, 0);
        }
    }
#pragma unroll
    for (int f2 = 0; f2 < 4; f2++)
#pragma unroll
        for (int i = 0; i < 4; i++)
            O[(row0 + l4 * 4 + i) * 1024 + h * 64 + f2 * 16 + l15] = (__bf16)o[f2][i];
}

// ---------------- LayerNorm (row=1024), bf16 input, writes f32 + bf16 ----------------
__global__ __launch_bounds__(256) void ln_kernel(const __bf16* __restrict__ y,
    const float* __restrict__ g, const float* __restrict__ b,
    float* __restrict__ xout, __bf16* __restrict__ xb)
{
    const int row = blockIdx.x;
    const int t = threadIdx.x;
    bf16x4 yv = *(const bf16x4*)(y + (long)row * 1024 + t * 4);
    float v0 = (float)yv[0], v1 = (float)yv[1], v2 = (float)yv[2], v3 = (float)yv[3];
    float s  = v0 + v1 + v2 + v3;
    float ss = v0 * v0 + v1 * v1 + v2 * v2 + v3 * v3;
#pragma unroll
    for (int m = 1; m < 64; m <<= 1) { s += __shfl_xor(s, m); ss += __shfl_xor(ss, m); }
    __shared__ float red[2][4];
    const int wave = t >> 6, lane = t & 63;
    if (lane == 0) { red[0][wave] = s; red[1][wave] = ss; }
    __syncthreads();
    s  = red[0][0] + red[0][1] + red[0][2] + red[0][3];
    ss = red[1][0] + red[1][1] + red[1][2] + red[1][3];
    const float mu = s * (1.f / 1024.f);
    const float var = ss * (1.f / 1024.f) - mu * mu;
    const float rs = rsqrtf(var + 1e-5f);
    const float4 gv = ((const float4*)g)[t];
    const float4 bv = ((const float4*)b)[t];
    float o0 = (v0 - mu) * rs * gv.x + bv.x;
    float o1 = (v1 - mu) * rs * gv.y + bv.y;
    float o2 = (v2 - mu) * rs * gv.z + bv.z;
    float o3 = (v3 - mu) * rs * gv.w + bv.w;
    float4 ov; ov.x = o0; ov.y = o1; ov.z = o2; ov.w = o3;
    ((float4*)(xout + (long)row * 1024))[t] = ov;
    __bf16* xr = xb + (long)row * 1024 + t * 4;
    xr[0] = (__bf16)o0; xr[1] = (__bf16)o1; xr[2] = (__bf16)o2; xr[3] = (__bf16)o3;
}

// ---------------- host launch ----------------
extern "C" void kernel_launch(void* const* d_in, const int* in_sizes, int n_in,
                              void* d_out, int out_size, void* d_ws, size_t ws_size,
                              hipStream_t stream) {
    const float* x   = (const float*)d_in[0];
    const float* Wq  = (const float*)d_in[1];
    const float* Wk  = (const float*)d_in[2];
    const float* Wv  = (const float*)d_in[3];
    const float* Wo  = (const float*)d_in[4];
    const float* bo  = (const float*)d_in[5];
    const float* Ew  = (const float*)d_in[6];
    const float* Eb  = (const float*)d_in[7];
    const float* W1  = (const float*)d_in[8];
    const float* b1  = (const float*)d_in[9];
    const float* W2  = (const float*)d_in[10];
    const float* b2  = (const float*)d_in[11];
    const float* lng = (const float*)d_in[12];
    const float* lnb = (const float*)d_in[13];
    float* xout = (float*)d_out;

    char* base = (char*)d_ws;
    size_t off = 0;
    auto alloc = [&](size_t bytes) { void* p = base + off; off += (bytes + 255) & ~(size_t)255; return p; };
    __bf16* Wqt  = (__bf16*)alloc(2ll * 1024 * 1024 * 2);
    __bf16* WkVt = (__bf16*)alloc(2ll * 2048 * 1024 * 2);   // [l][2048][1024]: Wk rows 0..1023, Wv rows 1024..2047
    __bf16* Wot  = (__bf16*)alloc(2ll * 1024 * 1024 * 2);
    __bf16* W1t  = (__bf16*)alloc(2ll * 1024 * 4096 * 2);
    __bf16* W2t  = (__bf16*)alloc(2ll * 1024 * 4096 * 2);
    __bf16* Ewb  = (__bf16*)alloc(256ll * 4096 * 2);
    __bf16* xb   = (__bf16*)alloc(8192ll * 1024 * 2);
    __bf16* xbT  = (__bf16*)alloc(2ll * 1024 * 4096 * 2);
    __bf16* ybf  = (__bf16*)alloc(8192ll * 1024 * 2);
    __bf16* xp   = (__bf16*)alloc(2ll * 256 * 1024 * 2);
    __bf16* KPb  = (__bf16*)alloc(2ll * 256 * 1024 * 2);
    __bf16* VPt  = (__bf16*)alloc(2ll * 1024 * 256 * 2);
    __bf16* big  = (__bf16*)alloc(8192ll * 4096 * 2);   // 64 MB scratch region
    float*  xpP  = (float*)big;                          // [16][256*1024] f32 = 16MB
    float*  kvP  = (float*)((char*)big + (16ll << 20));  // [8][256*2048]  f32 = 16MB
    __bf16* Qb   = big;                                  // [8192][1024] (over xpP, dead)
    __bf16* Ob   = big + (32ll << 20);                   // [8192][1024] at +32MB
    __bf16* hbuf = big;                                  // [8192][4096] (FF stage)

    cvt_f32_bf16<<<2048, 256, 0, stream>>>(x, xb, 8388608);
    cvt_f32_bf16<<<1024, 256, 0, stream>>>(Ew, Ewb, 1048576);
    transpose_cvt<<<dim3(2, 32, 32),  dim3(32, 8), 0, stream>>>(Wq, Wqt, 64, 1024, 65536, 65536);
    // WkVt: per-layer concat of Wk^T and Wv^T
    transpose_cvt<<<dim3(2, 32, 16),  dim3(32, 8), 0, stream>>>(Wk,           WkVt,                     64, 1024, 65536, 65536);
    transpose_cvt<<<dim3(2, 32, 16),  dim3(32, 8), 0, stream>>>(Wk + 1048576, WkVt + 2097152,           64, 1024, 65536, 65536);
    transpose_cvt<<<dim3(2, 32, 16),  dim3(32, 8), 0, stream>>>(Wv,           WkVt + 1048576,           64, 1024, 65536, 65536);
    transpose_cvt<<<dim3(2, 32, 16),  dim3(32, 8), 0, stream>>>(Wv + 1048576, WkVt + 2097152 + 1048576, 64, 1024, 65536, 65536);
    transpose_cvt<<<dim3(32, 32, 2),  dim3(32, 8), 0, stream>>>(Wo, Wot, 1024, 1024, 1048576, 1048576);
    transpose_cvt<<<dim3(128, 32, 2), dim3(32, 8), 0, stream>>>(W1, W1t, 4096, 1024, 4194304, 4194304);
    transpose_cvt<<<dim3(32, 128, 2), dim3(32, 8), 0, stream>>>(W2, W2t, 1024, 4096, 4194304, 4194304);

    for (int l = 0; l < 2; l++) {
        const __bf16* Wqt_l  = Wqt  + (long)l * 1048576;
        const __bf16* WkVt_l = WkVt + (long)l * 2097152;
        const __bf16* Wot_l  = Wot  + (long)l * 1048576;
        const __bf16* W1t_l  = W1t  + (long)l * 4194304;
        const __bf16* W2t_l  = W2t  + (long)l * 4194304;
        const float* res = (l == 0) ? x : xout;

        // xbT[b] = xb[b]^T
        transpose_bf16<<<dim3(32, 128, 2), dim3(32, 8), 0, stream>>>(xb, xbT, 4096, 1024);
        // xp = Ew @ x  (split-K 8)
        gemm128_split<<<dim3(2, 8, 16), 256, 0, stream>>>(
            Ewb, 4096, 0, xbT, 4096, 4194304, xpP, 262144, 1024, 512, 8);
        reduce_partials<<<dim3(256, 1, 2), 256, 0, stream>>>(xpP, xp, 8, 262144, 262144);
        // [KP|VP] = xp @ [Wk|Wv]^T + Eb  (merged, split-K 4)
        gemm128_split<<<dim3(2, 16, 8), 256, 0, stream>>>(
            xp, 1024, 262144, WkVt_l, 1024, 0, kvP, 524288, 2048, 256, 4);
        reduce_kv<<<dim3(512, 1, 2), 256, 0, stream>>>(kvP, KPb, VPt, Eb, 4);
        // Q = xb @ Wq^T
        gemm_bf16<false, false, false, false, 1><<<dim3(64, 8, 1), 256, 0, stream>>>(
            xb, 1024, 0, Wqt_l, 1024, 0, (void*)Qb, 1024, 0, nullptr, nullptr, nullptr, 0, 1024);
        // attention
        attn_fused<<<dim3(64, 16, 2), 256, 0, stream>>>(Qb, KPb, VPt, Ob);
        // attn_out = O @ Wo^T + bo + residual -> ybf (bf16)
        gemm_bf16<false, true, false, true, 1><<<dim3(64, 8, 1), 256, 0, stream>>>(
            Ob, 1024, 0, Wot_l, 1024, 0, (void*)ybf, 1024, 0,
            nullptr, bo + l * 1024, res, 1024, 1024);
        ln_kernel<<<8192, 256, 0, stream>>>(ybf, lng + (2 * l + 0) * 1024, lnb + (2 * l + 0) * 1024, xout, xb);
        // h = gelu(x @ W1 + b1)
        gemm_bf16<false, true, true, false, 1><<<dim3(64, 32, 1), 256, 0, stream>>>(
            xb, 1024, 0, W1t_l, 1024, 0, (void*)hbuf, 4096, 0,
            nullptr, b1 + l * 4096, nullptr, 0, 1024);
        // ff = h @ W2 + b2 + residual -> ybf (bf16)
        gemm_bf16<false, true, false, true, 1><<<dim3(64, 8, 1), 256, 0, stream>>>(
            hbuf, 4096, 0, W2t_l, 4096, 0, (void*)ybf, 1024, 0,
            nullptr, b2 + l * 1024, xout, 1024, 4096);
        ln_kernel<<<8192, 256, 0, stream>>>(ybf, lng + (2 * l + 1) * 1024, lnb + (2 * l + 1) * 1024, xout, xb);
    }
}

// Round 10
// 773.903 us; speedup vs baseline: 1.8768x; 1.0446x over previous
//
#include <hip/hip_runtime.h>
#include <hip/hip_bf16.h>
#include <math.h>

// ---------------- types ----------------
typedef __bf16 bf16x8 __attribute__((ext_vector_type(8)));
typedef __bf16 bf16x4 __attribute__((ext_vector_type(4)));
typedef float f32x4 __attribute__((ext_vector_type(4)));

__device__ __forceinline__ float gelu_fast(float v) {
    // 0.5v(1+tanh(c(v+0.044715v^3))) == v * sigmoid(2c(v+0.044715v^3))
    float z = v * (1.f + 0.044715f * v * v);
    return v / (1.f + __expf(-1.5957691216f * z));
}

// ---------------- conversion kernels ----------------
__global__ void cvt_f32_bf16(const float* __restrict__ in, __bf16* __restrict__ out, long n) {
    long i = ((long)blockIdx.x * 256 + threadIdx.x) * 4;
    long stride = (long)gridDim.x * 1024;
    for (; i < n; i += stride) {
        float4 v = *(const float4*)(in + i);
        out[i + 0] = (__bf16)v.x;
        out[i + 1] = (__bf16)v.y;
        out[i + 2] = (__bf16)v.z;
        out[i + 3] = (__bf16)v.w;
    }
}

// transpose + convert: in f32 [M][N] (ldin) -> out bf16 [N][M] (ldout), batched over z
__global__ void transpose_cvt(const float* __restrict__ in, __bf16* __restrict__ out,
                              int ldin, int ldout, long inBS, long outBS) {
    __shared__ __bf16 tile[32][33];
    in  += (long)blockIdx.z * inBS;
    out += (long)blockIdx.z * outBS;
    int n0 = blockIdx.x * 32, m0 = blockIdx.y * 32;
    for (int i = threadIdx.y; i < 32; i += 8)
        tile[i][threadIdx.x] = (__bf16)in[(long)(m0 + i) * ldin + n0 + threadIdx.x];
    __syncthreads();
    for (int i = threadIdx.y; i < 32; i += 8)
        out[(long)(n0 + i) * ldout + m0 + threadIdx.x] = tile[threadIdx.x][i];
}

// bf16 transpose: in [rows][cols] -> out [cols][rows], batched over z
__global__ void transpose_bf16(const __bf16* __restrict__ in, __bf16* __restrict__ out,
                               int rows, int cols) {
    __shared__ __bf16 tile[32][33];
    in  += (long)blockIdx.z * rows * cols;
    out += (long)blockIdx.z * rows * cols;
    int c0 = blockIdx.x * 32, r0 = blockIdx.y * 32;
    for (int i = threadIdx.y; i < 32; i += 8)
        tile[i][threadIdx.x] = in[(long)(r0 + i) * cols + c0 + threadIdx.x];
    __syncthreads();
    for (int i = threadIdx.y; i < 32; i += 8)
        out[(long)(c0 + i) * rows + r0 + threadIdx.x] = tile[threadIdx.x][i];
}

// ---------------- GEMM (proven structure + 8x8 patch swizzle) ----------------
// C[M,N] = A[M,K] @ Bt[N,K]^T (+epilogue). 128^2 tile, BK=64, 4 waves.
// RES reads bf16 residual. OUT: 0 = f32, 1 = bf16
template<bool ROWB, bool COLB, bool GELUF, bool RES, int OUT>
__global__ __launch_bounds__(256, 2) void gemm_bf16(
    const __bf16* __restrict__ A, int lda, long aBS,
    const __bf16* __restrict__ Bt, int ldb, long bBS,
    void* __restrict__ outp, int ldc, long cBS,
    const float* __restrict__ rowBias,
    const float* __restrict__ colBias,
    const __bf16* __restrict__ res, int ldres,
    int K)
{
    __shared__ __bf16 Asm[128 * 64];
    __shared__ __bf16 Bsm[128 * 64];
    const int tid = threadIdx.x;
    const int lane = tid & 63, wave = tid >> 6;
    const int wm = wave >> 1, wn = wave & 1;
    const int l15 = lane & 15, l4 = lane >> 4;

    // 8x8 patch per XCD (L2-resident panels); fallback 1D swizzle
    int bx = blockIdx.x, by = blockIdx.y;
    {
        int gx = gridDim.x, gy = gridDim.y;
        int nb = gx * gy;
        if ((gx & 7) == 0 && (gy & 7) == 0 && (nb & 511) == 0) {
            int id = by * gx + bx;
            int xcd = id & 7, local = id >> 3;
            int t = local >> 6, within = local & 63;
            int ppx = gx >> 3;
            int ppc = nb >> 9;
            int pid = xcd * ppc + t;
            int pgy = pid / ppx, pgx = pid % ppx;
            bx = pgx * 8 + (within & 7);
            by = pgy * 8 + (within >> 3);
        } else if ((nb & 7) == 0) {
            int id = by * gx + bx;
            int cpx = nb >> 3;
            int swz = (id & 7) * cpx + (id >> 3);
            bx = swz % gx;
            by = swz / gx;
        }
    }
    const long m0 = (long)bx * 128, n0 = (long)by * 128;
    A  += (long)blockIdx.z * aBS;
    Bt += (long)blockIdx.z * bBS;

    const int srow8 = lane >> 3;
    const int gunit = ((lane & 7) ^ srow8) << 3;
    const __bf16* Abase = A  + (m0 + wave * 8 + srow8) * (long)lda + gunit;
    const __bf16* Bbase = Bt + (n0 + wave * 8 + srow8) * (long)ldb + gunit;
    __bf16* AsmW = Asm + wave * 8 * 64;
    __bf16* BsmW = Bsm + wave * 8 * 64;
    const int swz_r = l15 & 7;

    f32x4 acc[4][4];
#pragma unroll
    for (int mi = 0; mi < 4; mi++)
#pragma unroll
        for (int ni = 0; ni < 4; ni++) acc[mi][ni] = (f32x4){0.f, 0.f, 0.f, 0.f};

    for (int k0 = 0; k0 < K; k0 += 64) {
        __syncthreads();
#pragma unroll
        for (int p = 0; p < 4; p++) {
            __builtin_amdgcn_global_load_lds(
                (const __attribute__((address_space(1))) unsigned int*)(Abase + (long)p * 32 * lda + k0),
                (__attribute__((address_space(3))) unsigned int*)(AsmW + p * 32 * 64), 16, 0, 0);
            __builtin_amdgcn_global_load_lds(
                (const __attribute__((address_space(1))) unsigned int*)(Bbase + (long)p * 32 * ldb + k0),
                (__attribute__((address_space(3))) unsigned int*)(BsmW + p * 32 * 64), 16, 0, 0);
        }
        asm volatile("s_waitcnt vmcnt(0)" ::: "memory");
        __syncthreads();
#pragma unroll
        for (int ks = 0; ks < 2; ks++) {
            bf16x8 af[4], bfv[4];
#pragma unroll
            for (int mi = 0; mi < 4; mi++)
                af[mi] = *(const bf16x8*)(Asm + (wm * 64 + mi * 16 + l15) * 64 + (((ks * 4 + l4) ^ swz_r) << 3));
#pragma unroll
            for (int ni = 0; ni < 4; ni++)
                bfv[ni] = *(const bf16x8*)(Bsm + (wn * 64 + ni * 16 + l15) * 64 + (((ks * 4 + l4) ^ swz_r) << 3));
#pragma unroll
            for (int mi = 0; mi < 4; mi++)
#pragma unroll
                for (int ni = 0; ni < 4; ni++)
                    acc[mi][ni] = __builtin_amdgcn_mfma_f32_16x16x32_bf16(af[mi], bfv[ni], acc[mi][ni], 0, 0, 0);
        }
    }

    float* outf = (float*)outp;
    __bf16* outb = (__bf16*)outp;
    const long cOff = (long)blockIdx.z * cBS;
#pragma unroll
    for (int mi = 0; mi < 4; mi++)
#pragma unroll
        for (int ni = 0; ni < 4; ni++) {
            long gmb = m0 + wm * 64 + mi * 16 + l4 * 4;
            long gc  = n0 + wn * 64 + ni * 16 + l15;
#pragma unroll
            for (int i = 0; i < 4; i++) {
                long gm = gmb + i;
                float v = acc[mi][ni][i];
                if (ROWB)  v += rowBias[gm];
                if (COLB)  v += colBias[gc];
                if (GELUF) v = gelu_fast(v);
                if (RES)   v += (float)res[gm * (long)ldres + gc];
                if (OUT == 0) outf[cOff + gm * (long)ldc + gc] = v;
                else          outb[cOff + gm * (long)ldc + gc] = (__bf16)v;
            }
        }
}

// ========== gemm128_split: 128x128 tile split-K, writes f32 partials ==========
__global__ __launch_bounds__(256, 2) void gemm128_split(
    const __bf16* __restrict__ A, int lda, long aBS,
    const __bf16* __restrict__ Bt, int ldb, long bBS,
    float* __restrict__ P, long cBS, int ldc,
    int Ksplit, int S)
{
    __shared__ __bf16 Asm[128 * 64];
    __shared__ __bf16 Bsm[128 * 64];
    const int tid = threadIdx.x;
    const int lane = tid & 63, wave = tid >> 6;
    const int wm = wave >> 1, wn = wave & 1;
    const int l15 = lane & 15, l4 = lane >> 4;
    const long m0 = (long)blockIdx.x * 128, n0 = (long)blockIdx.y * 128;
    const long zb = blockIdx.z / S;
    const int  sp = blockIdx.z % S;
    A  += zb * aBS + (long)sp * Ksplit;
    Bt += zb * bBS + (long)sp * Ksplit;

    const int srow8 = lane >> 3;
    const int gunit = ((lane & 7) ^ srow8) << 3;
    const __bf16* Abase = A + (m0 + wave * 8 + srow8) * (long)lda + gunit;
    const __bf16* Bbase = Bt + (n0 + wave * 8 + srow8) * (long)ldb + gunit;
    __bf16* AsmW = Asm + wave * 8 * 64;
    __bf16* BsmW = Bsm + wave * 8 * 64;
    const int swz_r = l15 & 7;

    f32x4 acc[4][4];
#pragma unroll
    for (int mi = 0; mi < 4; mi++)
#pragma unroll
        for (int ni = 0; ni < 4; ni++) acc[mi][ni] = (f32x4){0.f, 0.f, 0.f, 0.f};

    for (int k0 = 0; k0 < Ksplit; k0 += 64) {
        __syncthreads();
#pragma unroll
        for (int p = 0; p < 4; p++) {
            __builtin_amdgcn_global_load_lds(
                (const __attribute__((address_space(1))) unsigned int*)(Abase + (long)p * 32 * lda + k0),
                (__attribute__((address_space(3))) unsigned int*)(AsmW + p * 32 * 64), 16, 0, 0);
            __builtin_amdgcn_global_load_lds(
                (const __attribute__((address_space(1))) unsigned int*)(Bbase + (long)p * 32 * ldb + k0),
                (__attribute__((address_space(3))) unsigned int*)(BsmW + p * 32 * 64), 16, 0, 0);
        }
        asm volatile("s_waitcnt vmcnt(0)" ::: "memory");
        __syncthreads();
#pragma unroll
        for (int ks = 0; ks < 2; ks++) {
            bf16x8 af[4], bfv[4];
#pragma unroll
            for (int mi = 0; mi < 4; mi++)
                af[mi] = *(const bf16x8*)(Asm + (wm * 64 + mi * 16 + l15) * 64 + (((ks * 4 + l4) ^ swz_r) << 3));
#pragma unroll
            for (int ni = 0; ni < 4; ni++)
                bfv[ni] = *(const bf16x8*)(Bsm + (wn * 64 + ni * 16 + l15) * 64 + (((ks * 4 + l4) ^ swz_r) << 3));
#pragma unroll
            for (int mi = 0; mi < 4; mi++)
#pragma unroll
                for (int ni = 0; ni < 4; ni++)
                    acc[mi][ni] = __builtin_amdgcn_mfma_f32_16x16x32_bf16(af[mi], bfv[ni], acc[mi][ni], 0, 0, 0);
        }
    }

    float* out = P + (long)blockIdx.z * cBS;
#pragma unroll
    for (int mi = 0; mi < 4; mi++)
#pragma unroll
        for (int ni = 0; ni < 4; ni++) {
            long gmb = m0 + wm * 64 + mi * 16 + l4 * 4;
            long gc  = n0 + wn * 64 + ni * 16 + l15;
#pragma unroll
            for (int i = 0; i < 4; i++)
                out[(gmb + i) * (long)ldc + gc] = acc[mi][ni][i];
        }
}

// ---------- reduce S f32 partials -> bf16 (xp path) ----------
__global__ __launch_bounds__(256) void reduce_partials(
    const float* __restrict__ P, __bf16* __restrict__ out, int S, long total, long pBS)
{
    int b = blockIdx.z;
    long idx = ((long)blockIdx.x * 256 + threadIdx.x) * 4;
    if (idx >= total) return;
    const float* Pb = P + (long)b * S * pBS + idx;
    float4 a = *(const float4*)Pb;
    for (int s = 1; s < S; s++) {
        float4 v = *(const float4*)(Pb + (long)s * pBS);
        a.x += v.x; a.y += v.y; a.z += v.z; a.w += v.w;
    }
    __bf16* o = out + (long)b * total + idx;
    o[0] = (__bf16)a.x; o[1] = (__bf16)a.y; o[2] = (__bf16)a.z; o[3] = (__bf16)a.w;
}

// ---------- merged KV reduce: partials [S][256][2048] -> KP bf16 + VPt bf16 ----------
__global__ __launch_bounds__(256) void reduce_kv(
    const float* __restrict__ P, __bf16* __restrict__ KP, __bf16* __restrict__ VPt,
    const float* __restrict__ Eb, int S)
{
    int b = blockIdx.z;
    long idx = ((long)blockIdx.x * 256 + threadIdx.x) * 4;   // over 256*2048
    const float* Pb = P + (long)b * S * 524288 + idx;
    float4 a = *(const float4*)Pb;
    for (int s = 1; s < S; s++) {
        float4 v = *(const float4*)(Pb + (long)s * 524288);
        a.x += v.x; a.y += v.y; a.z += v.z; a.w += v.w;
    }
    int m = (int)(idx >> 11), n = (int)(idx & 2047);
    float bv = Eb[m];
    float av[4] = {a.x + bv, a.y + bv, a.z + bv, a.w + bv};
    if (n < 1024) {
        __bf16* o = KP + (long)b * 262144 + (long)m * 1024 + n;
        o[0] = (__bf16)av[0]; o[1] = (__bf16)av[1]; o[2] = (__bf16)av[2]; o[3] = (__bf16)av[3];
    } else {
        int c = n - 1024;
#pragma unroll
        for (int j = 0; j < 4; j++)
            VPt[(long)b * 262144 + (long)(c + j) * 256 + m] = (__bf16)av[j];
    }
}

// ---------------- fused Linformer attention ----------------
__global__ __launch_bounds__(256, 2) void attn_fused(
    const __bf16* __restrict__ Q, const __bf16* __restrict__ KP,
    const __bf16* __restrict__ VPt, __bf16* __restrict__ O)
{
    __shared__ __bf16 plds[4][4096];
    const int tid = threadIdx.x, lane = tid & 63, wave = tid >> 6;
    const int l15 = lane & 15, l4 = lane >> 4;
    const int h = blockIdx.y, b = blockIdx.z;
    const long row0 = (long)b * 4096 + (long)blockIdx.x * 64 + wave * 16;

    bf16x8 aq[2];
#pragma unroll
    for (int ks = 0; ks < 2; ks++)
        aq[ks] = *(const bf16x8*)(Q + (row0 + l15) * 1024 + h * 64 + ks * 32 + l4 * 8);

    f32x4 s[16];
#pragma unroll
    for (int f = 0; f < 16; f++) {
        f32x4 a = (f32x4){0.f, 0.f, 0.f, 0.f};
#pragma unroll
        for (int ks = 0; ks < 2; ks++) {
            bf16x8 bk = *(const bf16x8*)(KP + ((long)b * 256 + f * 16 + l15) * 1024 + h * 64 + ks * 32 + l4 * 8);
            a = __builtin_amdgcn_mfma_f32_16x16x32_bf16(aq[ks], bk, a, 0, 0, 0);
        }
        s[f] = a;
    }

    const float scale = 0.125f;
#pragma unroll
    for (int i = 0; i < 4; i++) {
        float m_ = -3.4e38f;
#pragma unroll
        for (int f = 0; f < 16; f++) { float v = s[f][i] * scale; s[f][i] = v; m_ = fmaxf(m_, v); }
#pragma unroll
        for (int msk = 1; msk < 16; msk <<= 1) m_ = fmaxf(m_, __shfl_xor(m_, msk));
        float su = 0.f;
#pragma unroll
        for (int f = 0; f < 16; f++) { float e = __expf(s[f][i] - m_); s[f][i] = e; su += e; }
#pragma unroll
        for (int msk = 1; msk < 16; msk <<= 1) su += __shfl_xor(su, msk);
        float inv = 1.f / su;
#pragma unroll
        for (int f = 0; f < 16; f++) s[f][i] *= inv;
    }

    __bf16* pl = plds[wave];
#pragma unroll
    for (int f = 0; f < 16; f++)
#pragma unroll
        for (int i = 0; i < 4; i++) {
            int r = l4 * 4 + i, c = f * 16 + l15;
            int off = r * 256 + ((((c >> 3) ^ (r & 7)) << 3) | (c & 7));
            pl[off] = (__bf16)s[f][i];
        }

    f32x4 o[4];
#pragma unroll
    for (int f2 = 0; f2 < 4; f2++) o[f2] = (f32x4){0.f, 0.f, 0.f, 0.f};
#pragma unroll
    for (int ks = 0; ks < 8; ks++) {
        int kk = ks * 32 + l4 * 8;
        int off = l15 * 256 + (((kk >> 3) ^ (l15 & 7)) << 3);
        bf16x8 ap = *(const bf16x8*)(pl + off);
#pragma unroll
        for (int f2 = 0; f2 < 4; f2++) {
            bf16x8 bv = *(const bf16x8*)(VPt + ((long)b * 1024 + h * 64 + f2 * 16 + l15) * 256 + kk);
            o[f2] = __builtin_amdgcn_mfma_f32_16x16x32_bf16(ap, bv, o[f2], 0, 0, 0);
        }
    }
#pragma unroll
    for (int f2 = 0; f2 < 4; f2++)
#pragma unroll
        for (int i = 0; i < 4; i++)
            O[(row0 + l4 * 4 + i) * 1024 + h * 64 + f2 * 16 + l15] = (__bf16)o[f2][i];
}

// ---------------- LayerNorm (row=1024), bf16 in; writes xb (+xout if WF32) ----------------
template<bool WF32>
__global__ __launch_bounds__(256) void ln_kernel(const __bf16* __restrict__ y,
    const float* __restrict__ g, const float* __restrict__ b,
    float* __restrict__ xout, __bf16* __restrict__ xb)
{
    const int row = blockIdx.x;
    const int t = threadIdx.x;
    bf16x4 yv = *(const bf16x4*)(y + (long)row * 1024 + t * 4);
    float v0 = (float)yv[0], v1 = (float)yv[1], v2 = (float)yv[2], v3 = (float)yv[3];
    float s  = v0 + v1 + v2 + v3;
    float ss = v0 * v0 + v1 * v1 + v2 * v2 + v3 * v3;
#pragma unroll
    for (int m = 1; m < 64; m <<= 1) { s += __shfl_xor(s, m); ss += __shfl_xor(ss, m); }
    __shared__ float red[2][4];
    const int wave = t >> 6, lane = t & 63;
    if (lane == 0) { red[0][wave] = s; red[1][wave] = ss; }
    __syncthreads();
    s  = red[0][0] + red[0][1] + red[0][2] + red[0][3];
    ss = red[1][0] + red[1][1] + red[1][2] + red[1][3];
    const float mu = s * (1.f / 1024.f);
    const float var = ss * (1.f / 1024.f) - mu * mu;
    const float rs = rsqrtf(var + 1e-5f);
    const float4 gv = ((const float4*)g)[t];
    const float4 bv = ((const float4*)b)[t];
    float o0 = (v0 - mu) * rs * gv.x + bv.x;
    float o1 = (v1 - mu) * rs * gv.y + bv.y;
    float o2 = (v2 - mu) * rs * gv.z + bv.z;
    float o3 = (v3 - mu) * rs * gv.w + bv.w;
    if (WF32) {
        float4 ov; ov.x = o0; ov.y = o1; ov.z = o2; ov.w = o3;
        ((float4*)(xout + (long)row * 1024))[t] = ov;
    }
    __bf16* xr = xb + (long)row * 1024 + t * 4;
    xr[0] = (__bf16)o0; xr[1] = (__bf16)o1; xr[2] = (__bf16)o2; xr[3] = (__bf16)o3;
}

// ---------------- host launch ----------------
extern "C" void kernel_launch(void* const* d_in, const int* in_sizes, int n_in,
                              void* d_out, int out_size, void* d_ws, size_t ws_size,
                              hipStream_t stream) {
    const float* x   = (const float*)d_in[0];
    const float* Wq  = (const float*)d_in[1];
    const float* Wk  = (const float*)d_in[2];
    const float* Wv  = (const float*)d_in[3];
    const float* Wo  = (const float*)d_in[4];
    const float* bo  = (const float*)d_in[5];
    const float* Ew  = (const float*)d_in[6];
    const float* Eb  = (const float*)d_in[7];
    const float* W1  = (const float*)d_in[8];
    const float* b1  = (const float*)d_in[9];
    const float* W2  = (const float*)d_in[10];
    const float* b2  = (const float*)d_in[11];
    const float* lng = (const float*)d_in[12];
    const float* lnb = (const float*)d_in[13];
    float* xout = (float*)d_out;

    char* base = (char*)d_ws;
    size_t off = 0;
    auto alloc = [&](size_t bytes) { void* p = base + off; off += (bytes + 255) & ~(size_t)255; return p; };
    __bf16* Wqt  = (__bf16*)alloc(2ll * 1024 * 1024 * 2);
    __bf16* WkVt = (__bf16*)alloc(2ll * 2048 * 1024 * 2);
    __bf16* Wot  = (__bf16*)alloc(2ll * 1024 * 1024 * 2);
    __bf16* W1t  = (__bf16*)alloc(2ll * 1024 * 4096 * 2);
    __bf16* W2t  = (__bf16*)alloc(2ll * 1024 * 4096 * 2);
    __bf16* Ewb  = (__bf16*)alloc(256ll * 4096 * 2);
    __bf16* xb   = (__bf16*)alloc(8192ll * 1024 * 2);
    __bf16* xbT  = (__bf16*)alloc(2ll * 1024 * 4096 * 2);
    __bf16* ybf  = (__bf16*)alloc(8192ll * 1024 * 2);
    __bf16* xp   = (__bf16*)alloc(2ll * 256 * 1024 * 2);
    __bf16* KPb  = (__bf16*)alloc(2ll * 256 * 1024 * 2);
    __bf16* VPt  = (__bf16*)alloc(2ll * 1024 * 256 * 2);
    __bf16* big  = (__bf16*)alloc(8192ll * 4096 * 2);   // 64 MB scratch region
    float*  xpP  = (float*)big;                          // [16][256*1024] f32 = 16MB
    float*  kvP  = (float*)((char*)big + (16ll << 20));  // [8][256*2048]  f32 = 16MB
    __bf16* Qb   = big;                                  // [8192][1024] (over xpP, dead)
    __bf16* Ob   = big + (32ll << 20);                   // [8192][1024] at +32MB
    __bf16* hbuf = big;                                  // [8192][4096] (FF stage)

    cvt_f32_bf16<<<2048, 256, 0, stream>>>(x, xb, 8388608);
    cvt_f32_bf16<<<1024, 256, 0, stream>>>(Ew, Ewb, 1048576);
    transpose_cvt<<<dim3(2, 32, 32),  dim3(32, 8), 0, stream>>>(Wq, Wqt, 64, 1024, 65536, 65536);
    transpose_cvt<<<dim3(2, 32, 16),  dim3(32, 8), 0, stream>>>(Wk,           WkVt,                     64, 1024, 65536, 65536);
    transpose_cvt<<<dim3(2, 32, 16),  dim3(32, 8), 0, stream>>>(Wk + 1048576, WkVt + 2097152,           64, 1024, 65536, 65536);
    transpose_cvt<<<dim3(2, 32, 16),  dim3(32, 8), 0, stream>>>(Wv,           WkVt + 1048576,           64, 1024, 65536, 65536);
    transpose_cvt<<<dim3(2, 32, 16),  dim3(32, 8), 0, stream>>>(Wv + 1048576, WkVt + 2097152 + 1048576, 64, 1024, 65536, 65536);
    transpose_cvt<<<dim3(32, 32, 2),  dim3(32, 8), 0, stream>>>(Wo, Wot, 1024, 1024, 1048576, 1048576);
    transpose_cvt<<<dim3(128, 32, 2), dim3(32, 8), 0, stream>>>(W1, W1t, 4096, 1024, 4194304, 4194304);
    transpose_cvt<<<dim3(32, 128, 2), dim3(32, 8), 0, stream>>>(W2, W2t, 1024, 4096, 4194304, 4194304);

    for (int l = 0; l < 2; l++) {
        const __bf16* Wqt_l  = Wqt  + (long)l * 1048576;
        const __bf16* WkVt_l = WkVt + (long)l * 2097152;
        const __bf16* Wot_l  = Wot  + (long)l * 1048576;
        const __bf16* W1t_l  = W1t  + (long)l * 4194304;
        const __bf16* W2t_l  = W2t  + (long)l * 4194304;

        // xbT[b] = xb[b]^T  (xb currently holds the layer input)
        transpose_bf16<<<dim3(32, 128, 2), dim3(32, 8), 0, stream>>>(xb, xbT, 4096, 1024);
        // xp = Ew @ x  (split-K 8)
        gemm128_split<<<dim3(2, 8, 16), 256, 0, stream>>>(
            Ewb, 4096, 0, xbT, 4096, 4194304, xpP, 262144, 1024, 512, 8);
        reduce_partials<<<dim3(256, 1, 2), 256, 0, stream>>>(xpP, xp, 8, 262144, 262144);
        // [KP|VP] = xp @ [Wk|Wv]^T + Eb  (merged, split-K 4)
        gemm128_split<<<dim3(2, 16, 8), 256, 0, stream>>>(
            xp, 1024, 262144, WkVt_l, 1024, 0, kvP, 524288, 2048, 256, 4);
        reduce_kv<<<dim3(512, 1, 2), 256, 0, stream>>>(kvP, KPb, VPt, Eb, 4);
        // Q = xb @ Wq^T
        gemm_bf16<false, false, false, false, 1><<<dim3(64, 8, 1), 256, 0, stream>>>(
            xb, 1024, 0, Wqt_l, 1024, 0, (void*)Qb, 1024, 0, nullptr, nullptr, nullptr, 0, 1024);
        // attention
        attn_fused<<<dim3(64, 16, 2), 256, 0, stream>>>(Qb, KPb, VPt, Ob);
        // attn_out = O @ Wo^T + bo + residual(xb) -> ybf
        gemm_bf16<false, true, false, true, 1><<<dim3(64, 8, 1), 256, 0, stream>>>(
            Ob, 1024, 0, Wot_l, 1024, 0, (void*)ybf, 1024, 0,
            nullptr, bo + l * 1024, xb, 1024, 1024);
        ln_kernel<false><<<8192, 256, 0, stream>>>(ybf, lng + (2 * l + 0) * 1024, lnb + (2 * l + 0) * 1024, nullptr, xb);
        // h = gelu(x @ W1 + b1)
        gemm_bf16<false, true, true, false, 1><<<dim3(64, 32, 1), 256, 0, stream>>>(
            xb, 1024, 0, W1t_l, 1024, 0, (void*)hbuf, 4096, 0,
            nullptr, b1 + l * 4096, nullptr, 0, 1024);
        // ff = h @ W2 + b2 + residual(xb) -> ybf
        gemm_bf16<false, true, false, true, 1><<<dim3(64, 8, 1), 256, 0, stream>>>(
            hbuf, 4096, 0, W2t_l, 4096, 0, (void*)ybf, 1024, 0,
            nullptr, b2 + l * 1024, xb, 1024, 4096);
        if (l == 1)
            ln_kernel<true><<<8192, 256, 0, stream>>>(ybf, lng + 3 * 1024, lnb + 3 * 1024, xout, xb);
        else
            ln_kernel<false><<<8192, 256, 0, stream>>>(ybf, lng + 1 * 1024, lnb + 1 * 1024, nullptr, xb);
    }
}

// Round 11
// 767.989 us; speedup vs baseline: 1.8913x; 1.0077x over previous
//
#include <hip/hip_runtime.h>
#include <hip/hip_bf16.h>
#include <math.h>

// ---------------- types ----------------
typedef __bf16 bf16x8 __attribute__((ext_vector_type(8)));
typedef __bf16 bf16x4 __attribute__((ext_vector_type(4)));
typedef float f32x4 __attribute__((ext_vector_type(4)));

__device__ __forceinline__ float gelu_fast(float v) {
    float z = v * (1.f + 0.044715f * v * v);
    return v / (1.f + __expf(-1.5957691216f * z));
}

// ---------------- conversion kernels ----------------
__global__ void cvt_f32_bf16(const float* __restrict__ in, __bf16* __restrict__ out, long n) {
    long i = ((long)blockIdx.x * 256 + threadIdx.x) * 4;
    long stride = (long)gridDim.x * 1024;
    for (; i < n; i += stride) {
        float4 v = *(const float4*)(in + i);
        out[i + 0] = (__bf16)v.x;
        out[i + 1] = (__bf16)v.y;
        out[i + 2] = (__bf16)v.z;
        out[i + 3] = (__bf16)v.w;
    }
}

// fused: x f32 [Z][rows][cols] -> xb bf16 (same layout) + xbT bf16 [Z][cols][rows]
__global__ void cvt_transpose(const float* __restrict__ in, __bf16* __restrict__ out,
                              __bf16* __restrict__ outT, int rows, int cols) {
    __shared__ __bf16 tile[32][33];
    in   += (long)blockIdx.z * rows * cols;
    out  += (long)blockIdx.z * rows * cols;
    outT += (long)blockIdx.z * rows * cols;
    int c0 = blockIdx.x * 32, r0 = blockIdx.y * 32;
    for (int i = threadIdx.y; i < 32; i += 8) {
        __bf16 v = (__bf16)in[(long)(r0 + i) * cols + c0 + threadIdx.x];
        tile[i][threadIdx.x] = v;
        out[(long)(r0 + i) * cols + c0 + threadIdx.x] = v;
    }
    __syncthreads();
    for (int i = threadIdx.y; i < 32; i += 8)
        outT[(long)(c0 + i) * rows + r0 + threadIdx.x] = tile[threadIdx.x][i];
}

// transpose + convert: in f32 [M][N] (ldin) -> out bf16 [N][M] (ldout), batched over z
__global__ void transpose_cvt(const float* __restrict__ in, __bf16* __restrict__ out,
                              int ldin, int ldout, long inBS, long outBS) {
    __shared__ __bf16 tile[32][33];
    in  += (long)blockIdx.z * inBS;
    out += (long)blockIdx.z * outBS;
    int n0 = blockIdx.x * 32, m0 = blockIdx.y * 32;
    for (int i = threadIdx.y; i < 32; i += 8)
        tile[i][threadIdx.x] = (__bf16)in[(long)(m0 + i) * ldin + n0 + threadIdx.x];
    __syncthreads();
    for (int i = threadIdx.y; i < 32; i += 8)
        out[(long)(n0 + i) * ldout + m0 + threadIdx.x] = tile[threadIdx.x][i];
}

// bf16 transpose: in [rows][cols] -> out [cols][rows], batched over z
__global__ void transpose_bf16(const __bf16* __restrict__ in, __bf16* __restrict__ out,
                               int rows, int cols) {
    __shared__ __bf16 tile[32][33];
    in  += (long)blockIdx.z * rows * cols;
    out += (long)blockIdx.z * rows * cols;
    int c0 = blockIdx.x * 32, r0 = blockIdx.y * 32;
    for (int i = threadIdx.y; i < 32; i += 8)
        tile[i][threadIdx.x] = in[(long)(r0 + i) * cols + c0 + threadIdx.x];
    __syncthreads();
    for (int i = threadIdx.y; i < 32; i += 8)
        out[(long)(c0 + i) * rows + r0 + threadIdx.x] = tile[threadIdx.x][i];
}

// ---------------- GEMM (proven structure + 8x8 patch swizzle) ----------------
// C[M,N] = A[M,K] @ Bt[N,K]^T (+epilogue). 128^2 tile, BK=64, 4 waves.
// RES reads bf16 residual. OUT: 0 = f32, 1 = bf16
template<bool ROWB, bool COLB, bool GELUF, bool RES, int OUT>
__global__ __launch_bounds__(256, 2) void gemm_bf16(
    const __bf16* __restrict__ A, int lda, long aBS,
    const __bf16* __restrict__ Bt, int ldb, long bBS,
    void* __restrict__ outp, int ldc, long cBS,
    const float* __restrict__ rowBias,
    const float* __restrict__ colBias,
    const __bf16* __restrict__ res, int ldres,
    int K)
{
    __shared__ __bf16 Asm[128 * 64];
    __shared__ __bf16 Bsm[128 * 64];
    const int tid = threadIdx.x;
    const int lane = tid & 63, wave = tid >> 6;
    const int wm = wave >> 1, wn = wave & 1;
    const int l15 = lane & 15, l4 = lane >> 4;

    // 8x8 patch per XCD (L2-resident panels); fallback 1D swizzle
    int bx = blockIdx.x, by = blockIdx.y;
    {
        int gx = gridDim.x, gy = gridDim.y;
        int nb = gx * gy;
        if ((gx & 7) == 0 && (gy & 7) == 0 && (nb & 511) == 0) {
            int id = by * gx + bx;
            int xcd = id & 7, local = id >> 3;
            int t = local >> 6, within = local & 63;
            int ppx = gx >> 3;
            int ppc = nb >> 9;
            int pid = xcd * ppc + t;
            int pgy = pid / ppx, pgx = pid % ppx;
            bx = pgx * 8 + (within & 7);
            by = pgy * 8 + (within >> 3);
        } else if ((nb & 7) == 0) {
            int id = by * gx + bx;
            int cpx = nb >> 3;
            int swz = (id & 7) * cpx + (id >> 3);
            bx = swz % gx;
            by = swz / gx;
        }
    }
    const long m0 = (long)bx * 128, n0 = (long)by * 128;
    A  += (long)blockIdx.z * aBS;
    Bt += (long)blockIdx.z * bBS;

    const int srow8 = lane >> 3;
    const int gunit = ((lane & 7) ^ srow8) << 3;
    const __bf16* Abase = A  + (m0 + wave * 8 + srow8) * (long)lda + gunit;
    const __bf16* Bbase = Bt + (n0 + wave * 8 + srow8) * (long)ldb + gunit;
    __bf16* AsmW = Asm + wave * 8 * 64;
    __bf16* BsmW = Bsm + wave * 8 * 64;
    const int swz_r = l15 & 7;

    f32x4 acc[4][4];
#pragma unroll
    for (int mi = 0; mi < 4; mi++)
#pragma unroll
        for (int ni = 0; ni < 4; ni++) acc[mi][ni] = (f32x4){0.f, 0.f, 0.f, 0.f};

    for (int k0 = 0; k0 < K; k0 += 64) {
        __syncthreads();
#pragma unroll
        for (int p = 0; p < 4; p++) {
            __builtin_amdgcn_global_load_lds(
                (const __attribute__((address_space(1))) unsigned int*)(Abase + (long)p * 32 * lda + k0),
                (__attribute__((address_space(3))) unsigned int*)(AsmW + p * 32 * 64), 16, 0, 0);
            __builtin_amdgcn_global_load_lds(
                (const __attribute__((address_space(1))) unsigned int*)(Bbase + (long)p * 32 * ldb + k0),
                (__attribute__((address_space(3))) unsigned int*)(BsmW + p * 32 * 64), 16, 0, 0);
        }
        asm volatile("s_waitcnt vmcnt(0)" ::: "memory");
        __syncthreads();
#pragma unroll
        for (int ks = 0; ks < 2; ks++) {
            bf16x8 af[4], bfv[4];
#pragma unroll
            for (int mi = 0; mi < 4; mi++)
                af[mi] = *(const bf16x8*)(Asm + (wm * 64 + mi * 16 + l15) * 64 + (((ks * 4 + l4) ^ swz_r) << 3));
#pragma unroll
            for (int ni = 0; ni < 4; ni++)
                bfv[ni] = *(const bf16x8*)(Bsm + (wn * 64 + ni * 16 + l15) * 64 + (((ks * 4 + l4) ^ swz_r) << 3));
#pragma unroll
            for (int mi = 0; mi < 4; mi++)
#pragma unroll
                for (int ni = 0; ni < 4; ni++)
                    acc[mi][ni] = __builtin_amdgcn_mfma_f32_16x16x32_bf16(af[mi], bfv[ni], acc[mi][ni], 0, 0, 0);
        }
    }

    float* outf = (float*)outp;
    __bf16* outb = (__bf16*)outp;
    const long cOff = (long)blockIdx.z * cBS;
#pragma unroll
    for (int mi = 0; mi < 4; mi++)
#pragma unroll
        for (int ni = 0; ni < 4; ni++) {
            long gmb = m0 + wm * 64 + mi * 16 + l4 * 4;
            long gc  = n0 + wn * 64 + ni * 16 + l15;
#pragma unroll
            for (int i = 0; i < 4; i++) {
                long gm = gmb + i;
                float v = acc[mi][ni][i];
                if (ROWB)  v += rowBias[gm];
                if (COLB)  v += colBias[gc];
                if (GELUF) v = gelu_fast(v);
                if (RES)   v += (float)res[gm * (long)ldres + gc];
                if (OUT == 0) outf[cOff + gm * (long)ldc + gc] = v;
                else          outb[cOff + gm * (long)ldc + gc] = (__bf16)v;
            }
        }
}

// ========== gemm128_split: 128x128 tile split-K, writes f32 partials ==========
__global__ __launch_bounds__(256, 2) void gemm128_split(
    const __bf16* __restrict__ A, int lda, long aBS,
    const __bf16* __restrict__ Bt, int ldb, long bBS,
    float* __restrict__ P, long cBS, int ldc,
    int Ksplit, int S)
{
    __shared__ __bf16 Asm[128 * 64];
    __shared__ __bf16 Bsm[128 * 64];
    const int tid = threadIdx.x;
    const int lane = tid & 63, wave = tid >> 6;
    const int wm = wave >> 1, wn = wave & 1;
    const int l15 = lane & 15, l4 = lane >> 4;
    const long m0 = (long)blockIdx.x * 128, n0 = (long)blockIdx.y * 128;
    const long zb = blockIdx.z / S;
    const int  sp = blockIdx.z % S;
    A  += zb * aBS + (long)sp * Ksplit;
    Bt += zb * bBS + (long)sp * Ksplit;

    const int srow8 = lane >> 3;
    const int gunit = ((lane & 7) ^ srow8) << 3;
    const __bf16* Abase = A + (m0 + wave * 8 + srow8) * (long)lda + gunit;
    const __bf16* Bbase = Bt + (n0 + wave * 8 + srow8) * (long)ldb + gunit;
    __bf16* AsmW = Asm + wave * 8 * 64;
    __bf16* BsmW = Bsm + wave * 8 * 64;
    const int swz_r = l15 & 7;

    f32x4 acc[4][4];
#pragma unroll
    for (int mi = 0; mi < 4; mi++)
#pragma unroll
        for (int ni = 0; ni < 4; ni++) acc[mi][ni] = (f32x4){0.f, 0.f, 0.f, 0.f};

    for (int k0 = 0; k0 < Ksplit; k0 += 64) {
        __syncthreads();
#pragma unroll
        for (int p = 0; p < 4; p++) {
            __builtin_amdgcn_global_load_lds(
                (const __attribute__((address_space(1))) unsigned int*)(Abase + (long)p * 32 * lda + k0),
                (__attribute__((address_space(3))) unsigned int*)(AsmW + p * 32 * 64), 16, 0, 0);
            __builtin_amdgcn_global_load_lds(
                (const __attribute__((address_space(1))) unsigned int*)(Bbase + (long)p * 32 * ldb + k0),
                (__attribute__((address_space(3))) unsigned int*)(BsmW + p * 32 * 64), 16, 0, 0);
        }
        asm volatile("s_waitcnt vmcnt(0)" ::: "memory");
        __syncthreads();
#pragma unroll
        for (int ks = 0; ks < 2; ks++) {
            bf16x8 af[4], bfv[4];
#pragma unroll
            for (int mi = 0; mi < 4; mi++)
                af[mi] = *(const bf16x8*)(Asm + (wm * 64 + mi * 16 + l15) * 64 + (((ks * 4 + l4) ^ swz_r) << 3));
#pragma unroll
            for (int ni = 0; ni < 4; ni++)
                bfv[ni] = *(const bf16x8*)(Bsm + (wn * 64 + ni * 16 + l15) * 64 + (((ks * 4 + l4) ^ swz_r) << 3));
#pragma unroll
            for (int mi = 0; mi < 4; mi++)
#pragma unroll
                for (int ni = 0; ni < 4; ni++)
                    acc[mi][ni] = __builtin_amdgcn_mfma_f32_16x16x32_bf16(af[mi], bfv[ni], acc[mi][ni], 0, 0, 0);
        }
    }

    float* out = P + (long)blockIdx.z * cBS;
#pragma unroll
    for (int mi = 0; mi < 4; mi++)
#pragma unroll
        for (int ni = 0; ni < 4; ni++) {
            long gmb = m0 + wm * 64 + mi * 16 + l4 * 4;
            long gc  = n0 + wn * 64 + ni * 16 + l15;
#pragma unroll
            for (int i = 0; i < 4; i++)
                out[(gmb + i) * (long)ldc + gc] = acc[mi][ni][i];
        }
}

// ---------- reduce S f32 partials -> bf16 (xp path) ----------
__global__ __launch_bounds__(256) void reduce_partials(
    const float* __restrict__ P, __bf16* __restrict__ out, int S, long total, long pBS)
{
    int b = blockIdx.z;
    long idx = ((long)blockIdx.x * 256 + threadIdx.x) * 4;
    if (idx >= total) return;
    const float* Pb = P + (long)b * S * pBS + idx;
    float4 a = *(const float4*)Pb;
    for (int s = 1; s < S; s++) {
        float4 v = *(const float4*)(Pb + (long)s * pBS);
        a.x += v.x; a.y += v.y; a.z += v.z; a.w += v.w;
    }
    __bf16* o = out + (long)b * total + idx;
    o[0] = (__bf16)a.x; o[1] = (__bf16)a.y; o[2] = (__bf16)a.z; o[3] = (__bf16)a.w;
}

// ---------- merged KV reduce: partials [S][256][2048] -> KP bf16 + VPt bf16 ----------
__global__ __launch_bounds__(256) void reduce_kv(
    const float* __restrict__ P, __bf16* __restrict__ KP, __bf16* __restrict__ VPt,
    const float* __restrict__ Eb, int S)
{
    int b = blockIdx.z;
    long idx = ((long)blockIdx.x * 256 + threadIdx.x) * 4;   // over 256*2048
    const float* Pb = P + (long)b * S * 524288 + idx;
    float4 a = *(const float4*)Pb;
    for (int s = 1; s < S; s++) {
        float4 v = *(const float4*)(Pb + (long)s * 524288);
        a.x += v.x; a.y += v.y; a.z += v.z; a.w += v.w;
    }
    int m = (int)(idx >> 11), n = (int)(idx & 2047);
    float bv = Eb[m];
    float av[4] = {a.x + bv, a.y + bv, a.z + bv, a.w + bv};
    if (n < 1024) {
        __bf16* o = KP + (long)b * 262144 + (long)m * 1024 + n;
        o[0] = (__bf16)av[0]; o[1] = (__bf16)av[1]; o[2] = (__bf16)av[2]; o[3] = (__bf16)av[3];
    } else {
        int c = n - 1024;
#pragma unroll
        for (int j = 0; j < 4; j++)
            VPt[(long)b * 262144 + (long)(c + j) * 256 + m] = (__bf16)av[j];
    }
}

// ---------------- fused Linformer attention ----------------
__global__ __launch_bounds__(256, 2) void attn_fused(
    const __bf16* __restrict__ Q, const __bf16* __restrict__ KP,
    const __bf16* __restrict__ VPt, __bf16* __restrict__ O)
{
    __shared__ __bf16 plds[4][4096];
    const int tid = threadIdx.x, lane = tid & 63, wave = tid >> 6;
    const int l15 = lane & 15, l4 = lane >> 4;
    const int h = blockIdx.y, b = blockIdx.z;
    const long row0 = (long)b * 4096 + (long)blockIdx.x * 64 + wave * 16;

    bf16x8 aq[2];
#pragma unroll
    for (int ks = 0; ks < 2; ks++)
        aq[ks] = *(const bf16x8*)(Q + (row0 + l15) * 1024 + h * 64 + ks * 32 + l4 * 8);

    f32x4 s[16];
#pragma unroll
    for (int f = 0; f < 16; f++) {
        f32x4 a = (f32x4){0.f, 0.f, 0.f, 0.f};
#pragma unroll
        for (int ks = 0; ks < 2; ks++) {
            bf16x8 bk = *(const bf16x8*)(KP + ((long)b * 256 + f * 16 + l15) * 1024 + h * 64 + ks * 32 + l4 * 8);
            a = __builtin_amdgcn_mfma_f32_16x16x32_bf16(aq[ks], bk, a, 0, 0, 0);
        }
        s[f] = a;
    }

    const float scale = 0.125f;
#pragma unroll
    for (int i = 0; i < 4; i++) {
        float m_ = -3.4e38f;
#pragma unroll
        for (int f = 0; f < 16; f++) { float v = s[f][i] * scale; s[f][i] = v; m_ = fmaxf(m_, v); }
#pragma unroll
        for (int msk = 1; msk < 16; msk <<= 1) m_ = fmaxf(m_, __shfl_xor(m_, msk));
        float su = 0.f;
#pragma unroll
        for (int f = 0; f < 16; f++) { float e = __expf(s[f][i] - m_); s[f][i] = e; su += e; }
#pragma unroll
        for (int msk = 1; msk < 16; msk <<= 1) su += __shfl_xor(su, msk);
        float inv = 1.f / su;
#pragma unroll
        for (int f = 0; f < 16; f++) s[f][i] *= inv;
    }

    __bf16* pl = plds[wave];
#pragma unroll
    for (int f = 0; f < 16; f++)
#pragma unroll
        for (int i = 0; i < 4; i++) {
            int r = l4 * 4 + i, c = f * 16 + l15;
            int off = r * 256 + ((((c >> 3) ^ (r & 7)) << 3) | (c & 7));
            pl[off] = (__bf16)s[f][i];
        }

    f32x4 o[4];
#pragma unroll
    for (int f2 = 0; f2 < 4; f2++) o[f2] = (f32x4){0.f, 0.f, 0.f, 0.f};
#pragma unroll
    for (int ks = 0; ks < 8; ks++) {
        int kk = ks * 32 + l4 * 8;
        int off = l15 * 256 + (((kk >> 3) ^ (l15 & 7)) << 3);
        bf16x8 ap = *(const bf16x8*)(pl + off);
#pragma unroll
        for (int f2 = 0; f2 < 4; f2++) {
            bf16x8 bv = *(const bf16x8*)(VPt + ((long)b * 1024 + h * 64 + f2 * 16 + l15) * 256 + kk);
            o[f2] = __builtin_amdgcn_mfma_f32_16x16x32_bf16(ap, bv, o[f2], 0, 0, 0);
        }
    }
#pragma unroll
    for (int f2 = 0; f2 < 4; f2++)
#pragma unroll
        for (int i = 0; i < 4; i++)
            O[(row0 + l4 * 4 + i) * 1024 + h * 64 + f2 * 16 + l15] = (__bf16)o[f2][i];
}

// ---------------- LayerNorm (row=1024), bf16 in; writes xb (+xout if WF32) ----------------
template<bool WF32>
__global__ __launch_bounds__(256) void ln_kernel(const __bf16* __restrict__ y,
    const float* __restrict__ g, const float* __restrict__ b,
    float* __restrict__ xout, __bf16* __restrict__ xb)
{
    const int row = blockIdx.x;
    const int t = threadIdx.x;
    bf16x4 yv = *(const bf16x4*)(y + (long)row * 1024 + t * 4);
    float v0 = (float)yv[0], v1 = (float)yv[1], v2 = (float)yv[2], v3 = (float)yv[3];
    float s  = v0 + v1 + v2 + v3;
    float ss = v0 * v0 + v1 * v1 + v2 * v2 + v3 * v3;
#pragma unroll
    for (int m = 1; m < 64; m <<= 1) { s += __shfl_xor(s, m); ss += __shfl_xor(ss, m); }
    __shared__ float red[2][4];
    const int wave = t >> 6, lane = t & 63;
    if (lane == 0) { red[0][wave] = s; red[1][wave] = ss; }
    __syncthreads();
    s  = red[0][0] + red[0][1] + red[0][2] + red[0][3];
    ss = red[1][0] + red[1][1] + red[1][2] + red[1][3];
    const float mu = s * (1.f / 1024.f);
    const float var = ss * (1.f / 1024.f) - mu * mu;
    const float rs = rsqrtf(var + 1e-5f);
    const float4 gv = ((const float4*)g)[t];
    const float4 bv = ((const float4*)b)[t];
    float o0 = (v0 - mu) * rs * gv.x + bv.x;
    float o1 = (v1 - mu) * rs * gv.y + bv.y;
    float o2 = (v2 - mu) * rs * gv.z + bv.z;
    float o3 = (v3 - mu) * rs * gv.w + bv.w;
    if (WF32) {
        float4 ov; ov.x = o0; ov.y = o1; ov.z = o2; ov.w = o3;
        ((float4*)(xout + (long)row * 1024))[t] = ov;
    }
    __bf16* xr = xb + (long)row * 1024 + t * 4;
    xr[0] = (__bf16)o0; xr[1] = (__bf16)o1; xr[2] = (__bf16)o2; xr[3] = (__bf16)o3;
}

// ---------------- host launch ----------------
extern "C" void kernel_launch(void* const* d_in, const int* in_sizes, int n_in,
                              void* d_out, int out_size, void* d_ws, size_t ws_size,
                              hipStream_t stream) {
    const float* x   = (const float*)d_in[0];
    const float* Wq  = (const float*)d_in[1];
    const float* Wk  = (const float*)d_in[2];
    const float* Wv  = (const float*)d_in[3];
    const float* Wo  = (const float*)d_in[4];
    const float* bo  = (const float*)d_in[5];
    const float* Ew  = (const float*)d_in[6];
    const float* Eb  = (const float*)d_in[7];
    const float* W1  = (const float*)d_in[8];
    const float* b1  = (const float*)d_in[9];
    const float* W2  = (const float*)d_in[10];
    const float* b2  = (const float*)d_in[11];
    const float* lng = (const float*)d_in[12];
    const float* lnb = (const float*)d_in[13];
    float* xout = (float*)d_out;

    char* base = (char*)d_ws;
    size_t off = 0;
    auto alloc = [&](size_t bytes) { void* p = base + off; off += (bytes + 255) & ~(size_t)255; return p; };
    __bf16* Wqt  = (__bf16*)alloc(2ll * 1024 * 1024 * 2);
    __bf16* WkVt = (__bf16*)alloc(2ll * 2048 * 1024 * 2);
    __bf16* Wot  = (__bf16*)alloc(2ll * 1024 * 1024 * 2);
    __bf16* W1t  = (__bf16*)alloc(2ll * 1024 * 4096 * 2);
    __bf16* W2t  = (__bf16*)alloc(2ll * 1024 * 4096 * 2);
    __bf16* Ewb  = (__bf16*)alloc(256ll * 4096 * 2);
    __bf16* xb   = (__bf16*)alloc(8192ll * 1024 * 2);
    __bf16* xbT  = (__bf16*)alloc(2ll * 1024 * 4096 * 2);
    __bf16* ybf  = (__bf16*)alloc(8192ll * 1024 * 2);
    __bf16* xp   = (__bf16*)alloc(2ll * 256 * 1024 * 2);
    __bf16* KPb  = (__bf16*)alloc(2ll * 256 * 1024 * 2);
    __bf16* VPt  = (__bf16*)alloc(2ll * 1024 * 256 * 2);
    __bf16* big  = (__bf16*)alloc(8192ll * 4096 * 2);   // 64 MB scratch region
    float*  xpP  = (float*)big;                          // [16][256*1024] f32 = 16MB
    float*  kvP  = (float*)((char*)big + (16ll << 20));  // [8][256*2048]  f32 = 16MB
    __bf16* Qb   = big;                                  // [8192][1024] (over xpP, dead)
    __bf16* Ob   = big + (32ll << 20);                   // [8192][1024] at +32MB
    __bf16* hbuf = big;                                  // [8192][4096] (FF stage)

    // fused: xb + xbT (layer-0 input) in one pass over x
    cvt_transpose<<<dim3(32, 128, 2), dim3(32, 8), 0, stream>>>(x, xb, xbT, 4096, 1024);
    cvt_f32_bf16<<<1024, 256, 0, stream>>>(Ew, Ewb, 1048576);
    transpose_cvt<<<dim3(2, 32, 32),  dim3(32, 8), 0, stream>>>(Wq, Wqt, 64, 1024, 65536, 65536);
    transpose_cvt<<<dim3(2, 32, 16),  dim3(32, 8), 0, stream>>>(Wk,           WkVt,                     64, 1024, 65536, 65536);
    transpose_cvt<<<dim3(2, 32, 16),  dim3(32, 8), 0, stream>>>(Wk + 1048576, WkVt + 2097152,           64, 1024, 65536, 65536);
    transpose_cvt<<<dim3(2, 32, 16),  dim3(32, 8), 0, stream>>>(Wv,           WkVt + 1048576,           64, 1024, 65536, 65536);
    transpose_cvt<<<dim3(2, 32, 16),  dim3(32, 8), 0, stream>>>(Wv + 1048576, WkVt + 2097152 + 1048576, 64, 1024, 65536, 65536);
    transpose_cvt<<<dim3(32, 32, 2),  dim3(32, 8), 0, stream>>>(Wo, Wot, 1024, 1024, 1048576, 1048576);
    transpose_cvt<<<dim3(128, 32, 2), dim3(32, 8), 0, stream>>>(W1, W1t, 4096, 1024, 4194304, 4194304);
    transpose_cvt<<<dim3(32, 128, 2), dim3(32, 8), 0, stream>>>(W2, W2t, 1024, 4096, 4194304, 4194304);

    for (int l = 0; l < 2; l++) {
        const __bf16* Wqt_l  = Wqt  + (long)l * 1048576;
        const __bf16* WkVt_l = WkVt + (long)l * 2097152;
        const __bf16* Wot_l  = Wot  + (long)l * 1048576;
        const __bf16* W1t_l  = W1t  + (long)l * 4194304;
        const __bf16* W2t_l  = W2t  + (long)l * 4194304;

        // xbT = xb^T (layer 0 got it fused with the f32 conversion)
        if (l > 0)
            transpose_bf16<<<dim3(32, 128, 2), dim3(32, 8), 0, stream>>>(xb, xbT, 4096, 1024);
        // xp = Ew @ x  (split-K 8)
        gemm128_split<<<dim3(2, 8, 16), 256, 0, stream>>>(
            Ewb, 4096, 0, xbT, 4096, 4194304, xpP, 262144, 1024, 512, 8);
        reduce_partials<<<dim3(256, 1, 2), 256, 0, stream>>>(xpP, xp, 8, 262144, 262144);
        // [KP|VP] = xp @ [Wk|Wv]^T + Eb  (merged, split-K 4)
        gemm128_split<<<dim3(2, 16, 8), 256, 0, stream>>>(
            xp, 1024, 262144, WkVt_l, 1024, 0, kvP, 524288, 2048, 256, 4);
        reduce_kv<<<dim3(512, 1, 2), 256, 0, stream>>>(kvP, KPb, VPt, Eb, 4);
        // Q = xb @ Wq^T
        gemm_bf16<false, false, false, false, 1><<<dim3(64, 8, 1), 256, 0, stream>>>(
            xb, 1024, 0, Wqt_l, 1024, 0, (void*)Qb, 1024, 0, nullptr, nullptr, nullptr, 0, 1024);
        // attention
        attn_fused<<<dim3(64, 16, 2), 256, 0, stream>>>(Qb, KPb, VPt, Ob);
        // attn_out = O @ Wo^T + bo + residual(xb) -> ybf
        gemm_bf16<false, true, false, true, 1><<<dim3(64, 8, 1), 256, 0, stream>>>(
            Ob, 1024, 0, Wot_l, 1024, 0, (void*)ybf, 1024, 0,
            nullptr, bo + l * 1024, xb, 1024, 1024);
        ln_kernel<false><<<8192, 256, 0, stream>>>(ybf, lng + (2 * l + 0) * 1024, lnb + (2 * l + 0) * 1024, nullptr, xb);
        // h = gelu(x @ W1 + b1)
        gemm_bf16<false, true, true, false, 1><<<dim3(64, 32, 1), 256, 0, stream>>>(
            xb, 1024, 0, W1t_l, 1024, 0, (void*)hbuf, 4096, 0,
            nullptr, b1 + l * 4096, nullptr, 0, 1024);
        // ff = h @ W2 + b2 + residual(xb) -> ybf
        gemm_bf16<false, true, false, true, 1><<<dim3(64, 8, 1), 256, 0, stream>>>(
            hbuf, 4096, 0, W2t_l, 4096, 0, (void*)ybf, 1024, 0,
            nullptr, b2 + l * 1024, xb, 1024, 4096);
        if (l == 1)
            ln_kernel<true><<<8192, 256, 0, stream>>>(ybf, lng + 3 * 1024, lnb + 3 * 1024, xout, xb);
        else
            ln_kernel<false><<<8192, 256, 0, stream>>>(ybf, lng + 1 * 1024, lnb + 1 * 1024, nullptr, xb);
    }
}